// Round 5
// baseline (969.026 us; speedup 1.0000x reference)
//
#include <hip/hip_runtime.h>
#include <math.h>

// ---------------------------------------------------------------------------
// EfficientAttention (dual-stream) — round 5: transposed-domain pipeline.
//   in_tr: rgb/flow f32 [c][s] -> bf16 [s][c] (once per stream).
//   dw_t : depthwise 3x3x3 in [s][c] domain (lane=channel, t-sliding ring),
//          output [s][c] bf16 feeds MFMA pw GEMM directly (NO transposes).
//   att  : fused Q-softmax + LDS re-layout epilogue -> aggregated [n][s][c].
//   rp   : dw_t(512) -> pw GEMM with fused residual + LN partial sums.
// ---------------------------------------------------------------------------

constexpr int NN = 4;
constexpr int C1 = 256;
constexpr int C2 = 512;
constexpr int TT = 16;
constexpr int SP = TT * 28 * 28;                  // 12544
constexpr long long NB = (long long)NN * C2 * SP; // 25,690,112
constexpr int HEADS = 8;
constexpr int CTX_CHUNKS = 49;                    // SP / 256
constexpr int STATS_PARTS = 98 * 4 * 4;           // rp GEMM grid = 1568
constexpr double TOTAL_ELEMS = (double)NB;

typedef __attribute__((ext_vector_type(8))) short bf16x8;
typedef __attribute__((ext_vector_type(4))) float f32x4;

__device__ __forceinline__ short f2bf(float f)
{
    unsigned u = __float_as_uint(f);
    unsigned r = u + 0x7FFFu + ((u >> 16) & 1u);
    return (short)(r >> 16);
}
__device__ __forceinline__ float bf2f(short s)
{
    return __uint_as_float(((unsigned)(unsigned short)s) << 16);
}

__device__ __forceinline__ void gload16(const short* g, short* l)
{
    __builtin_amdgcn_global_load_lds(
        (const __attribute__((address_space(1))) unsigned int*)g,
        (__attribute__((address_space(3))) unsigned int*)l,
        16, 0, 0);
}

// ---------------- merged fp32 -> bf16 weight conversion --------------------
// out layout: 6 x 65536 (Krgb,Vrgb,Kflow,Vflow,Qrgb,Qflow) + 262144 (rp)
__global__ __launch_bounds__(256)
void wcvt_kernel(const float* __restrict__ w0, const float* __restrict__ w1,
                 const float* __restrict__ w2, const float* __restrict__ w3,
                 const float* __restrict__ w4, const float* __restrict__ w5,
                 const float* __restrict__ w6, short* __restrict__ out)
{
    int i = blockIdx.x * 256 + threadIdx.x;
    if (i >= 655360) return;
    const float* src; int off;
    if (i < 393216) {
        int seg = i >> 16; off = i & 65535;
        src = seg == 0 ? w0 : seg == 1 ? w1 : seg == 2 ? w2
            : seg == 3 ? w3 : seg == 4 ? w4 : w5;
    } else { src = w6; off = i - 393216; }
    out[i] = f2bf(src[off]);
}

// ---------------- input transpose: f32 [n][C][S] -> bf16 [n][S][C] ---------
// grid (SP/64, C/64, NN), block 256.
__global__ __launch_bounds__(256)
void in_tr_kernel(const float* __restrict__ in, short* __restrict__ outT, int C)
{
    __shared__ short t[64][66];
    const int s0 = blockIdx.x * 64, c0 = blockIdx.y * 64, n = blockIdx.z;
    const float* ip = in + ((size_t)n * C + c0) * SP + s0;
    short* op = outT + ((size_t)n * SP + s0) * C + c0;
    const int tid = threadIdx.x;
#pragma unroll
    for (int p = 0; p < 4; ++p) {
        int cc = (tid >> 4) + p * 16, s4 = (tid & 15) * 4;
        float4 v = *(const float4*)(ip + (size_t)cc * SP + s4);
        t[cc][s4] = f2bf(v.x); t[cc][s4 + 1] = f2bf(v.y);
        t[cc][s4 + 2] = f2bf(v.z); t[cc][s4 + 3] = f2bf(v.w);
    }
    __syncthreads();
#pragma unroll
    for (int p = 0; p < 2; ++p) {
        int s = (tid >> 3) + p * 32, chunk = tid & 7;
        bf16x8 v;
#pragma unroll
        for (int e = 0; e < 8; ++e) v[e] = t[chunk * 8 + e][s];
        *(bf16x8*)(op + (size_t)s * C + chunk * 8) = v;
    }
}

// ---------------- depthwise 3x3x3 in [s][c] domain -------------------------
// in/out: [n][S][C] bf16. wgt f32 [C][27], bias f32 [C].
// grid: (14 h-strips, C/64, NN*4 tq), block 256 (4 waves; lane = channel).
// Each wave: 14 positions of a 2h x 28w out-tile; t-sliding 2-slice ring.
__global__ __launch_bounds__(256)
void dw_t_kernel(const short* __restrict__ in, const float* __restrict__ wgt,
                 const float* __restrict__ bias, short* __restrict__ out, int C)
{
    const int h0 = blockIdx.x * 2;
    const int c0 = blockIdx.y * 64;
    const int n = blockIdx.z >> 2, q = blockIdx.z & 3;
    const int t0 = q * 4, t1 = t0 + 4;
    const int tid = threadIdx.x;
    const int lane = tid & 63, wv = tid >> 6;
    __shared__ short ring[2][4 * 30 * 64];
    const int c = c0 + lane;
    float w[27];
#pragma unroll
    for (int i = 0; i < 27; ++i) w[i] = wgt[c * 27 + i];
    const float bv = bias[c];
    float a0[14], a1[14], a2[14];
#pragma unroll
    for (int i = 0; i < 14; ++i) { a0[i] = bv; a1[i] = bv; a2[i] = bv; }
    const size_t base = (size_t)n * SP;
    const int zs = (t0 - 1 > 0) ? t0 - 1 : 0;
    const int ze = (t1 < TT - 1) ? t1 : TT - 1;

    for (int z = zs; z <= ze; ++z) {
        short* rb = ring[z & 1];
        // stage slice z: 4 halo rows (h0-1..h0+2) x 30 w x 64 c
#pragma unroll
        for (int r = 0; r < 4; ++r) {
            int item = tid + r * 256;               // 960 = 120 pos * 8 chunks
            if (item < 960) {
                int chunk = item & 7, pi = item >> 3;
                int hp = pi / 30, wp = pi - hp * 30;
                int h = h0 - 1 + hp, wq = wp - 1;
                bf16x8 v = {};
                if (h >= 0 && h < 28 && wq >= 0 && wq < 28)
                    v = *(const bf16x8*)(in +
                        (base + (size_t)z * 784 + h * 28 + wq) * C + c0 + chunk * 8);
                *(bf16x8*)&rb[pi * 64 + chunk * 8] = v;
            }
        }
        __syncthreads();
#pragma unroll
        for (int i = 0; i < 14; ++i) {
            const int pos = wv * 14 + i;
            const int hh = pos / 28, ww = pos - hh * 28;
            float x[9];
#pragma unroll
            for (int dh = 0; dh < 3; ++dh)
#pragma unroll
                for (int dw2 = 0; dw2 < 3; ++dw2)
                    x[dh * 3 + dw2] = bf2f(rb[((hh + dh) * 30 + ww + dw2) * 64 + lane]);
#pragma unroll
            for (int k = 0; k < 9; ++k) {
                a0[i] += x[k] * w[18 + k];
                a1[i] += x[k] * w[9 + k];
                a2[i] += x[k] * w[k];
            }
        }
        if (z - 1 >= t0) {
#pragma unroll
            for (int i = 0; i < 14; ++i) {
                const int pos = wv * 14 + i;
                const int hh = pos / 28, ww = pos - hh * 28;
                out[(base + (size_t)(z - 1) * 784 + (h0 + hh) * 28 + ww) * C + c] =
                    f2bf(a0[i]);
            }
        }
#pragma unroll
        for (int i = 0; i < 14; ++i) { a0[i] = a1[i]; a1[i] = a2[i]; a2[i] = bv; }
    }
    if (ze == TT - 1 && t1 == TT) {
#pragma unroll
        for (int i = 0; i < 14; ++i) {
            const int pos = wv * 14 + i;
            const int hh = pos / 28, ww = pos - hh * 28;
            out[(base + (size_t)15 * 784 + (h0 + hh) * 28 + ww) * C + c] = f2bf(a0[i]);
        }
    }
}

// ---------------- pointwise conv: bf16 MFMA GEMM ---------------------------
// actT: [N][S][Cin] bf16 (direct dw_t output).
// !RESID: bf16 out at outB + n*nStride + (chOff+m)*cStride + s.
// RESID:  f32 x = acc+bias+residual -> outF [N,C2,S] + LN double partials.
template<bool RESID>
__global__ __launch_bounds__(256)
void pw_mfma_kernel(const short* __restrict__ Wb, const float* __restrict__ bias,
                    const short* __restrict__ actT, short* __restrict__ outB,
                    float* __restrict__ outF, const float* __restrict__ rgb,
                    const float* __restrict__ flow, double* __restrict__ partials,
                    int Cin, size_t nStride, size_t cStride, int chOff)
{
    __shared__ short lA[128 * 64];
    __shared__ short lB[128 * 64];
    const int tid = threadIdx.x;
    const int w = tid >> 6, lane = tid & 63;
    const int s0 = blockIdx.x * 128;
    const int m0 = blockIdx.y * 128;
    const int n = blockIdx.z;
    const short* aSrc = Wb + (size_t)m0 * Cin;
    const short* bSrc = actT + ((size_t)n * SP + s0) * Cin;
    f32x4 acc[4][4];
#pragma unroll
    for (int i = 0; i < 4; ++i)
#pragma unroll
        for (int j = 0; j < 4; ++j)
            acc[i][j] = (f32x4){0.f, 0.f, 0.f, 0.f};
    const int lrow = lane >> 3, lslot = lane & 7;
    const int wr = w >> 1, wc = w & 1;

    for (int kt = 0; kt < Cin; kt += 64) {
#pragma unroll
        for (int cc = 0; cc < 4; ++cc) {
            const int chunk = w * 4 + cc;
            const int row = chunk * 8 + lrow;
            const int ss = lslot ^ (row & 7);
            gload16(aSrc + (size_t)row * Cin + kt + ss * 8, &lA[chunk * 512]);
            gload16(bSrc + (size_t)row * Cin + kt + ss * 8, &lB[chunk * 512]);
        }
        __syncthreads();
#pragma unroll
        for (int kf = 0; kf < 2; ++kf) {
            bf16x8 af[4], bfr[4];
            const int kb = kf * 4 + (lane >> 4);
#pragma unroll
            for (int i = 0; i < 4; ++i) {
                const int row = wr * 64 + i * 16 + (lane & 15);
                af[i] = *(const bf16x8*)&lA[row * 64 + ((kb ^ (row & 7)) << 3)];
            }
#pragma unroll
            for (int j = 0; j < 4; ++j) {
                const int row = wc * 64 + j * 16 + (lane & 15);
                bfr[j] = *(const bf16x8*)&lB[row * 64 + ((kb ^ (row & 7)) << 3)];
            }
#pragma unroll
            for (int i = 0; i < 4; ++i)
#pragma unroll
                for (int j = 0; j < 4; ++j)
                    acc[i][j] = __builtin_amdgcn_mfma_f32_16x16x32_bf16(
                        af[i], bfr[j], acc[i][j], 0, 0, 0);
        }
        __syncthreads();
    }

    if constexpr (!RESID) {
        short* op = outB + (size_t)n * nStride + (size_t)chOff * cStride;
#pragma unroll
        for (int i = 0; i < 4; ++i) {
            const int mBase = m0 + wr * 64 + i * 16 + (lane >> 4) * 4;
#pragma unroll
            for (int j = 0; j < 4; ++j) {
                const int s = s0 + wc * 64 + j * 16 + (lane & 15);
#pragma unroll
                for (int r = 0; r < 4; ++r) {
                    const int m = mBase + r;
                    op[(size_t)m * cStride + s] = f2bf(acc[i][j][r] + bias[m]);
                }
            }
        }
    } else {
        float* xp = outF + (size_t)n * C2 * SP;
        const float* rbase = (m0 < 256)
            ? rgb + ((size_t)n * 256 + m0) * SP
            : flow + ((size_t)n * 256 + (m0 - 256)) * SP;
        double ls = 0.0, lss = 0.0;
#pragma unroll
        for (int i = 0; i < 4; ++i) {
            const int mBase = m0 + wr * 64 + i * 16 + (lane >> 4) * 4;
#pragma unroll
            for (int j = 0; j < 4; ++j) {
                const int s = s0 + wc * 64 + j * 16 + (lane & 15);
#pragma unroll
                for (int r = 0; r < 4; ++r) {
                    const int m = mBase + r;
                    float x = acc[i][j][r] + bias[m] +
                              rbase[(size_t)(m - m0) * SP + s];
                    xp[(size_t)m * SP + s] = x;
                    ls += (double)x;
                    lss += (double)x * (double)x;
                }
            }
        }
        __shared__ double s1[256], s2[256];
        s1[tid] = ls; s2[tid] = lss;
        __syncthreads();
        for (int st = 128; st > 0; st >>= 1) {
            if (tid < st) { s1[tid] += s1[tid + st]; s2[tid] += s2[tid + st]; }
            __syncthreads();
        }
        if (tid == 0) {
            const size_t bid = ((size_t)blockIdx.z * gridDim.y + blockIdx.y) *
                               gridDim.x + blockIdx.x;
            partials[2 * bid] = s1[0];
            partials[2 * bid + 1] = s2[0];
        }
    }
}

// ---------------- per-row (max, 1/sum exp) of K [2048 rows x S] bf16 -------
__global__ __launch_bounds__(256)
void row_stats_kernel(const short* __restrict__ K, float2* __restrict__ st)
{
    const short* p = K + (size_t)blockIdx.x * SP;
    __shared__ float sm[4];
    __shared__ float bc;
    const int tid = threadIdx.x, wv = tid >> 6, ln = tid & 63;
    float m = -1e30f;
    for (int c = tid; c < SP / 8; c += 256) {
        bf16x8 v = *(const bf16x8*)(p + c * 8);
#pragma unroll
        for (int j = 0; j < 8; ++j) m = fmaxf(m, bf2f(v[j]));
    }
    for (int o = 32; o; o >>= 1) m = fmaxf(m, __shfl_down(m, o, 64));
    if (ln == 0) sm[wv] = m;
    __syncthreads();
    if (tid == 0) bc = fmaxf(fmaxf(sm[0], sm[1]), fmaxf(sm[2], sm[3]));
    __syncthreads();
    m = bc;
    float sum = 0.f;
    for (int c = tid; c < SP / 8; c += 256) {
        bf16x8 v = *(const bf16x8*)(p + c * 8);
#pragma unroll
        for (int j = 0; j < 8; ++j) sum += __expf(bf2f(v[j]) - m);
    }
    for (int o = 32; o; o >>= 1) sum += __shfl_down(sum, o, 64);
    __syncthreads();
    if (ln == 0) sm[wv] = sum;
    __syncthreads();
    if (tid == 0) {
        float tot = sm[0] + sm[1] + sm[2] + sm[3];
        st[blockIdx.x] = (float2){m, 1.f / tot};
    }
}

// ---------------- ctx = softmax(K) . V^T (bf16 in, exp on the fly) ---------
__global__ __launch_bounds__(256)
void ctx_partial_kernel(const short* __restrict__ Kbuf, const short* __restrict__ Vbuf,
                        const float2* __restrict__ stats, float* __restrict__ part)
{
    const int chunk = blockIdx.x, nh = blockIdx.y;
    const int sBeg = chunk * 256;
    const short* Kp = Kbuf + (size_t)nh * 64 * SP;
    const short* Vp = Vbuf + (size_t)nh * 64 * SP;
    __shared__ float Ks[64][33], Vs[64][33];
    __shared__ float km[64], kinv[64];
    const int tid = threadIdx.x;
    if (tid < 64) {
        float2 s = stats[nh * 64 + tid];
        km[tid] = s.x; kinv[tid] = s.y;
    }
    __syncthreads();
    const int kk = (tid >> 4) * 4, vv = (tid & 15) * 4;
    const int lr = tid >> 2, lc = (tid & 3) * 8;
    float acc[4][4] = {};
    for (int st = 0; st < 256; st += 32) {
        bf16x8 a = *(const bf16x8*)(Kp + (size_t)lr * SP + sBeg + st + lc);
        bf16x8 b = *(const bf16x8*)(Vp + (size_t)lr * SP + sBeg + st + lc);
        const float mk = km[lr], ik = kinv[lr];
#pragma unroll
        for (int j = 0; j < 8; ++j) {
            Ks[lr][lc + j] = __expf(bf2f(a[j]) - mk) * ik;
            Vs[lr][lc + j] = bf2f(b[j]);
        }
        __syncthreads();
#pragma unroll 8
        for (int s = 0; s < 32; ++s) {
            float av[4], bv[4];
#pragma unroll
            for (int i = 0; i < 4; ++i) av[i] = Ks[kk + i][s];
#pragma unroll
            for (int j = 0; j < 4; ++j) bv[j] = Vs[vv + j][s];
#pragma unroll
            for (int i = 0; i < 4; ++i)
#pragma unroll
                for (int j = 0; j < 4; ++j)
                    acc[i][j] += av[i] * bv[j];
        }
        __syncthreads();
    }
    float* op = part + ((size_t)nh * CTX_CHUNKS + chunk) * 4096;
#pragma unroll
    for (int i = 0; i < 4; ++i)
#pragma unroll
        for (int j = 0; j < 4; ++j)
            op[(kk + i) * 64 + vv + j] = acc[i][j];
}

__global__ __launch_bounds__(256)
void ctx_reduce_kernel(const float* __restrict__ part, float* __restrict__ ctx)
{
    const int nh = blockIdx.x;
    for (int e = threadIdx.x; e < 4096; e += 256) {
        float s = 0.f;
        for (int c = 0; c < CTX_CHUNKS; ++c)
            s += part[((size_t)nh * CTX_CHUNKS + c) * 4096 + e];
        ctx[(size_t)nh * 4096 + e] = s;
    }
}

// ---------------- att: out[n][s][h*64+v] = ctx^T . softmaxQ ----------------
// Q raw bf16 [c][n][s]; fused column softmax; agg out bf16 [n][S][512].
__global__ __launch_bounds__(256)
void att_kernel(const float* __restrict__ ctx, const short* __restrict__ Qraw,
                short* __restrict__ out)
{
    const int nh = blockIdx.y;
    const int n = nh >> 3, h = nh & 7;
    const int s0 = blockIdx.x * 64;
    const float* cp = ctx + (size_t)nh * 4096;
    const size_t qrs = (size_t)NN * SP;
    const short* Qp = Qraw + (size_t)(h * 64) * qrs + (size_t)n * SP;
    __shared__ float Cs[64][65];
    __shared__ float Bs[64][68];
    __shared__ float red[4][64];
    __shared__ float sinv[64];
    const int tx = threadIdx.x, ty = threadIdx.y;
    const int tid = ty * 16 + tx;
#pragma unroll
    for (int i = 0; i < 4; ++i) {
        int q = tid + i * 256;
        int k = q >> 4, v4 = (q & 15) * 4;
        float4 a = *(const float4*)&cp[k * 64 + v4];
        Cs[k][v4] = a.x; Cs[k][v4 + 1] = a.y; Cs[k][v4 + 2] = a.z; Cs[k][v4 + 3] = a.w;
    }
#pragma unroll
    for (int i = 0; i < 2; ++i) {
        int q = tid + i * 256;
        int k = q >> 3, g = (q & 7) * 8;
        bf16x8 b = *(const bf16x8*)(Qp + (size_t)k * qrs + s0 + g);
#pragma unroll
        for (int j = 0; j < 8; ++j) Bs[k][g + j] = bf2f(b[j]);
    }
    __syncthreads();
    const int sc = tid & 63, qr = tid >> 6;
    float m = -1e30f;
#pragma unroll
    for (int k = 0; k < 16; ++k) m = fmaxf(m, Bs[qr * 16 + k][sc]);
    red[qr][sc] = m;
    __syncthreads();
    m = fmaxf(fmaxf(red[0][sc], red[1][sc]), fmaxf(red[2][sc], red[3][sc]));
    __syncthreads();
    float sum = 0.f;
#pragma unroll
    for (int k = 0; k < 16; ++k) {
        float e = __expf(Bs[qr * 16 + k][sc] - m);
        Bs[qr * 16 + k][sc] = e;
        sum += e;
    }
    red[qr][sc] = sum;
    __syncthreads();
    if (qr == 0)
        sinv[sc] = 1.f / (red[0][sc] + red[1][sc] + red[2][sc] + red[3][sc]);
    __syncthreads();

    float acc[4][4] = {};
    const int v0 = ty * 4, j0 = tx * 4;
#pragma unroll 8
    for (int k = 0; k < 64; ++k) {
        float a[4], b[4];
#pragma unroll
        for (int i = 0; i < 4; ++i) a[i] = Cs[k][v0 + i];
#pragma unroll
        for (int j = 0; j < 4; ++j) b[j] = Bs[k][j0 + j];
#pragma unroll
        for (int i = 0; i < 4; ++i)
#pragma unroll
            for (int j = 0; j < 4; ++j)
                acc[i][j] += a[i] * b[j];
    }
    __syncthreads();                       // Bs reads done; re-use as [s][v]
#pragma unroll
    for (int i = 0; i < 4; ++i)
#pragma unroll
        for (int j = 0; j < 4; ++j)
            Bs[j0 + j][v0 + i] = acc[i][j] * sinv[j0 + j];
    __syncthreads();
#pragma unroll
    for (int p = 0; p < 2; ++p) {
        int item = tid + p * 256;          // 512 = 64 s * 8 chunks
        int s = item >> 3, chunk = item & 7;
        bf16x8 v;
#pragma unroll
        for (int e = 0; e < 8; ++e) v[e] = f2bf(Bs[s][chunk * 8 + e]);
        *(bf16x8*)(out + ((size_t)n * SP + s0 + s) * C2 + h * 64 + chunk * 8) = v;
    }
}

// ---------------- LN finalize ----------------------------------------------
__global__ __launch_bounds__(256)
void stats_final_kernel(const double* __restrict__ partials, float* __restrict__ mv)
{
    double ls = 0.0, lss = 0.0;
    for (int i = threadIdx.x; i < STATS_PARTS; i += 256) {
        ls += partials[2 * i];
        lss += partials[2 * i + 1];
    }
    __shared__ double s1[256], s2[256];
    const int tid = threadIdx.x;
    s1[tid] = ls; s2[tid] = lss;
    __syncthreads();
    for (int s = 128; s > 0; s >>= 1) {
        if (tid < s) { s1[tid] += s1[tid + s]; s2[tid] += s2[tid + s]; }
        __syncthreads();
    }
    if (tid == 0) {
        double mean = s1[0] / TOTAL_ELEMS;
        double var = s2[0] / TOTAL_ELEMS - mean * mean;
        mv[0] = (float)mean;
        mv[1] = (float)(1.0 / sqrt(var + 1e-5));
    }
}

__global__ __launch_bounds__(256)
void normalize_kernel(float* __restrict__ x, const float* __restrict__ mv)
{
    const float mean = mv[0], inv = mv[1];
    size_t i = ((size_t)blockIdx.x * 256 + threadIdx.x) * 4;
    const size_t tot = (size_t)NB;
    const size_t step = (size_t)gridDim.x * 1024;
    for (; i < tot; i += step) {
        float4 v = *(float4*)&x[i];
        v.x = (v.x - mean) * inv; v.y = (v.y - mean) * inv;
        v.z = (v.z - mean) * inv; v.w = (v.w - mean) * inv;
        *(float4*)&x[i] = v;
    }
}

// ---------------------------------------------------------------------------
extern "C" void kernel_launch(void* const* d_in, const int* in_sizes, int n_in,
                              void* d_out, int out_size, void* d_ws, size_t ws_size,
                              hipStream_t stream)
{
    (void)in_sizes; (void)n_in; (void)out_size; (void)ws_size;
    const float* rgb = (const float*)d_in[0];
    const float* flow = (const float*)d_in[1];
    float* ws = (float*)d_ws;

    // ws layout (f32 units); NB/2 f32 == NB bf16.
    short* bufK   = (short*)ws;                      // [N,512,S] bf16
    short* bufQ   = (short*)(ws + NB / 2);           // [512,N,S] bf16
    short* bufV   = (short*)(ws + NB);               // V [N,512,S] / agg [N,S,512]
    short* xT_rgb = (short*)(ws + 3 * NB / 2);       // [N,S,256] bf16
    short* xT_flw = (short*)(ws + 7 * NB / 4);       // [N,S,256] bf16
    short* dwOut  = (short*)(ws + 2 * NB);           // [N,S,256/512] bf16
    float2* rowStats = (float2*)(ws + 5 * NB / 2);   // 2048
    float* ctxBuf = (float*)(rowStats + 2048);       // 32*4096
    double* partials = (double*)(ctxBuf + 32 * 4096);
    float* mv = (float*)(partials + 2 * STATS_PARTS);
    float* ctxPart = ws + 3 * NB / 2;                // alias xT (dead after proj)

    const size_t nsA = (size_t)C2 * SP, csA = SP;          // K/V [n][c][s]
    const size_t nsB = (size_t)SP, csB = (size_t)NN * SP;  // Q   [c][n][s]

    // ---- weights -> bf16 (one dispatch) ----
    short* wB = dwOut + (size_t)NN * SP * C2;  // tail of dwOut region unused by
    // C1 outputs... NOT safe for rp; place weights in smalls region instead:
    wB = (short*)(mv + 8);
    wcvt_kernel<<<2560, 256, 0, stream>>>(
        (const float*)d_in[4], (const float*)d_in[12], (const float*)d_in[16],
        (const float*)d_in[24], (const float*)d_in[8], (const float*)d_in[20],
        (const float*)d_in[28], wB);

    // ---- input transposes ----
    in_tr_kernel<<<dim3(SP / 64, 4, NN), 256, 0, stream>>>(rgb, xT_rgb, C1);
    in_tr_kernel<<<dim3(SP / 64, 4, NN), 256, 0, stream>>>(flow, xT_flw, C1);

    // ---- projections: K-rgb, V-rgb, K-flow, V-flow, Q-rgb, Q-flow ----
    const int wIdx[6] = {2, 10, 14, 22, 6, 18};
    const short* src[6] = {xT_rgb, xT_rgb, xT_flw, xT_flw, xT_rgb, xT_flw};
    short* dst[6] = {bufK, bufV, bufK, bufV, bufQ, bufQ};
    const int choff[6] = {0, 0, 256, 256, 0, 256};
    for (int p = 0; p < 6; ++p) {
        const int wi = wIdx[p];
        const bool layB = (p >= 4);
        dw_t_kernel<<<dim3(14, 4, NN * 4), 256, 0, stream>>>(
            src[p], (const float*)d_in[wi], (const float*)d_in[wi + 1], dwOut, C1);
        pw_mfma_kernel<false><<<dim3(SP / 128, 2, NN), 256, 0, stream>>>(
            wB + (size_t)p * 65536, (const float*)d_in[wi + 3], dwOut, dst[p],
            nullptr, nullptr, nullptr, nullptr,
            C1, layB ? nsB : nsA, layB ? csB : csA, choff[p]);
    }

    // ---- attention ----
    row_stats_kernel<<<NN * C2, 256, 0, stream>>>(bufK, rowStats);
    ctx_partial_kernel<<<dim3(CTX_CHUNKS, NN * HEADS), 256, 0, stream>>>(
        bufK, bufV, rowStats, ctxPart);
    ctx_reduce_kernel<<<NN * HEADS, 256, 0, stream>>>(ctxPart, ctxBuf);
    att_kernel<<<dim3(SP / 64, NN * HEADS), dim3(16, 16), 0, stream>>>(
        ctxBuf, bufQ, bufV);   // bufV becomes aggregated [N,S,512]

    // ---- reprojection: dw_t(512) -> pw GEMM (+residual +LN stats) ----
    dw_t_kernel<<<dim3(14, 8, NN * 4), 256, 0, stream>>>(
        bufV, (const float*)d_in[26], (const float*)d_in[27], dwOut, C2);
    pw_mfma_kernel<true><<<dim3(SP / 128, 4, NN), 256, 0, stream>>>(
        wB + 6 * 65536, (const float*)d_in[29], dwOut, nullptr,
        (float*)d_out, rgb, flow, partials, C2, 0, 0, 0);

    // ---- LN finalize ----
    stats_final_kernel<<<1, 256, 0, stream>>>(partials, mv);
    normalize_kernel<<<2048, 256, 0, stream>>>((float*)d_out, mv);
}

// Round 6
// 774.296 us; speedup vs baseline: 1.2515x; 1.2515x over previous
//
#include <hip/hip_runtime.h>
#include <math.h>

// ---------------------------------------------------------------------------
// EfficientAttention (dual-stream) — round 6: round-4 skeleton, transpose
// fused into pw GEMM B-staging (no separate transpose kernels).
//   dw conv in [c][s] (low-VGPR sliding-t, hoisted staging index math).
//   pw MFMA GEMM: A (weights) via global_load_lds + XOR swizzle; B (act[c][s])
//     reg-staged and written transposed into LDS Bs[s][k^ (s&56)] (stride 72).
//   softmax_K folded (row_stats + exp-on-the-fly in ctx), softmax_Q in att,
//   residual + LN stats in rp GEMM epilogue.
// ---------------------------------------------------------------------------

constexpr int NN = 4;
constexpr int C1 = 256;
constexpr int C2 = 512;
constexpr int TT = 16;
constexpr int SP = TT * 28 * 28;                  // 12544
constexpr long long NB = (long long)NN * C2 * SP; // 25,690,112
constexpr int HEADS = 8;
constexpr int CTX_CHUNKS = 49;                    // SP / 256
constexpr int STATS_PARTS = 98 * 4 * 4;           // rp GEMM grid = 1568
constexpr double TOTAL_ELEMS = (double)NB;

typedef __attribute__((ext_vector_type(8))) short bf16x8;
typedef __attribute__((ext_vector_type(4))) short bf16x4;
typedef __attribute__((ext_vector_type(4))) float f32x4;

__device__ __forceinline__ short f2bf(float f)
{
    unsigned u = __float_as_uint(f);
    unsigned r = u + 0x7FFFu + ((u >> 16) & 1u);
    return (short)(r >> 16);
}
__device__ __forceinline__ float bf2f(short s)
{
    return __uint_as_float(((unsigned)(unsigned short)s) << 16);
}
__device__ __forceinline__ float toF(float x) { return x; }
__device__ __forceinline__ float toF(short x) { return bf2f(x); }

__device__ __forceinline__ void gload16(const short* g, short* l)
{
    __builtin_amdgcn_global_load_lds(
        (const __attribute__((address_space(1))) unsigned int*)g,
        (__attribute__((address_space(3))) unsigned int*)l,
        16, 0, 0);
}

// ---------------- merged fp32 -> bf16 weight conversion --------------------
__global__ __launch_bounds__(256)
void wcvt_kernel(const float* __restrict__ w0, const float* __restrict__ w1,
                 const float* __restrict__ w2, const float* __restrict__ w3,
                 const float* __restrict__ w4, const float* __restrict__ w5,
                 const float* __restrict__ w6, short* __restrict__ out)
{
    int i = blockIdx.x * 256 + threadIdx.x;
    if (i >= 655360) return;
    const float* src; int off;
    if (i < 393216) {
        int seg = i >> 16; off = i & 65535;
        src = seg == 0 ? w0 : seg == 1 ? w1 : seg == 2 ? w2
            : seg == 3 ? w3 : seg == 4 ? w4 : w5;
    } else { src = w6; off = i - 393216; }
    out[i] = f2bf(src[off]);
}

// ---------------- depthwise 3x3x3 conv + bias -> bf16 (sliding-t) ----------
// grid: (2, Cin, NN), block: 256. in: [N,Cin,T,784] (f32|bf16); out bf16 same.
template<typename IT>
__global__ __launch_bounds__(256)
void dw_conv_kernel(const IT* __restrict__ in, const float* __restrict__ wgt,
                    const float* __restrict__ bias, short* __restrict__ out, int Cin)
{
    const int split = blockIdx.x;
    const int c = blockIdx.y, n = blockIdx.z;
    const int t0 = split * 8, t1 = t0 + 8;
    const int zs = (t0 - 1 > 0) ? t0 - 1 : 0;
    const int ze = (t1 < 15) ? t1 : 15;
    __shared__ float tile[2][900];
    const IT* inp = in + ((size_t)(n * Cin + c)) * TT * 784;
    short* op = out + ((size_t)(n * Cin + c)) * TT * 784;
    float wr[27];
#pragma unroll
    for (int i = 0; i < 27; ++i) wr[i] = wgt[c * 27 + i];
    const float bv = bias[c];
    const int tid = threadIdx.x;

    // hoisted staging indices (4 items of 900)
    int li[4], goff[4]; bool inr[4], val[4];
#pragma unroll
    for (int p = 0; p < 4; ++p) {
        int i = tid + p * 256;
        li[p] = i;
        inr[p] = i < 900;
        int y = i / 30, x = i - y * 30;
        val[p] = inr[p] && y >= 1 && y <= 28 && x >= 1 && x <= 28;
        goff[p] = (y - 1) * 28 + (x - 1);
    }
    // hoisted output indices (4 positions of 784)
    int hw[4];
#pragma unroll
    for (int p = 0; p < 4; ++p) {
        int idx = tid + p * 256;
        int hh = idx / 28, ww = idx - hh * 28;
        hw[p] = hh * 30 + ww;
    }
    float a0[4], a1[4], a2[4];
#pragma unroll
    for (int p = 0; p < 4; ++p) { a0[p] = bv; a1[p] = bv; a2[p] = bv; }

    for (int z = zs; z <= ze; ++z) {
        float* tb = tile[z & 1];
        const IT* gsrc = inp + (size_t)z * 784;
#pragma unroll
        for (int p = 0; p < 4; ++p)
            if (inr[p]) tb[li[p]] = val[p] ? toF(gsrc[goff[p]]) : 0.f;
        __syncthreads();
#pragma unroll
        for (int p = 0; p < 4; ++p) {
            const bool act = (p < 3) || (tid < 16);
            if (!act) continue;
            float v[9];
#pragma unroll
            for (int dh = 0; dh < 3; ++dh)
#pragma unroll
                for (int dw2 = 0; dw2 < 3; ++dw2)
                    v[dh * 3 + dw2] = tb[hw[p] + dh * 30 + dw2];
#pragma unroll
            for (int i = 0; i < 9; ++i) {
                a0[p] += v[i] * wr[18 + i];
                a1[p] += v[i] * wr[9 + i];
                a2[p] += v[i] * wr[i];
            }
        }
        if (z - 1 >= t0 && z - 1 < t1) {
#pragma unroll
            for (int p = 0; p < 4; ++p)
                if ((p < 3) || (tid < 16))
                    op[(size_t)(z - 1) * 784 + tid + p * 256] = f2bf(a0[p]);
        }
#pragma unroll
        for (int p = 0; p < 4; ++p) { a0[p] = a1[p]; a1[p] = a2[p]; a2[p] = bv; }
        // ring parity separates same-buffer reuse by the next sync
    }
    if (ze >= t0 && ze < t1) {
#pragma unroll
        for (int p = 0; p < 4; ++p)
            if ((p < 3) || (tid < 16))
                op[(size_t)ze * 784 + tid + p * 256] = f2bf(a0[p]);
    }
}

// ---------------- pointwise conv: bf16 MFMA GEMM, fused B-transpose --------
// act: [N][Cin][S] bf16 (dw output, channels-major). D[m][s]=W[m][k]*act[k][s].
// A (W[m][k], k-contig) -> global_load_lds + XOR swizzle.
// B (act rows) -> reg-stage coalesced, transposed scatter into Bs[s][72]
//   with column swizzle col = k ^ (s&56); fragment reads 16B aligned.
// !RESID: bf16 out at outB + n*nStride + (chOff+m)*cStride + s.
// RESID : f32 x = acc+bias+residual -> outF [N,C2,S] + LN double partials.
template<bool RESID>
__global__ __launch_bounds__(256)
void pw_mfma_kernel(const short* __restrict__ Wb, const float* __restrict__ bias,
                    const short* __restrict__ act, short* __restrict__ outB,
                    float* __restrict__ outF, const float* __restrict__ rgb,
                    const float* __restrict__ flow, double* __restrict__ partials,
                    int Cin, size_t nStride, size_t cStride, int chOff)
{
    __shared__ short lA[128 * 64];
    __shared__ short Bs[128 * 72];
    const int tid = threadIdx.x;
    const int w = tid >> 6, lane = tid & 63;
    const int s0 = blockIdx.x * 128;
    const int m0 = blockIdx.y * 128;
    const int n = blockIdx.z;
    const short* aSrc = Wb + (size_t)m0 * Cin;
    const short* bSrc = act + (size_t)n * Cin * SP;
    f32x4 acc[4][4];
#pragma unroll
    for (int i = 0; i < 4; ++i)
#pragma unroll
        for (int j = 0; j < 4; ++j)
            acc[i][j] = (f32x4){0.f, 0.f, 0.f, 0.f};
    const int lrow = lane >> 3, lslot = lane & 7;
    const int wr = w >> 1, wc = w & 1;

    for (int kt = 0; kt < Cin; kt += 64) {
        // A: async global->LDS (linear dest, source pre-swizzled)
#pragma unroll
        for (int cc = 0; cc < 4; ++cc) {
            const int chunk = w * 4 + cc;
            const int row = chunk * 8 + lrow;
            const int ss = lslot ^ (row & 7);
            gload16(aSrc + (size_t)row * Cin + kt + ss * 8, &lA[chunk * 512]);
        }
        // B: coalesced reg loads of act rows [kt+krow][s0..s0+127]
        bf16x8 breg[4];
#pragma unroll
        for (int k = 0; k < 4; ++k) {
            const int cid = tid + k * 256;
            const int krow = cid >> 4, sc = (cid & 15) * 8;
            breg[k] = *(const bf16x8*)(bSrc + (size_t)(kt + krow) * SP + s0 + sc);
        }
        // transposed scatter into Bs (swizzled column)
#pragma unroll
        for (int k = 0; k < 4; ++k) {
            const int cid = tid + k * 256;
            const int krow = cid >> 4, sc = (cid & 15) * 8;
            const int col = krow ^ (sc & 56);
#pragma unroll
            for (int j = 0; j < 8; ++j)
                Bs[(sc + j) * 72 + col] = breg[k][j];
        }
        __syncthreads();
#pragma unroll
        for (int kf = 0; kf < 2; ++kf) {
            bf16x8 af[4], bfr[4];
            const int kb = kf * 4 + (lane >> 4);
#pragma unroll
            for (int i = 0; i < 4; ++i) {
                const int row = wr * 64 + i * 16 + (lane & 15);
                af[i] = *(const bf16x8*)&lA[row * 64 + ((kb ^ (row & 7)) << 3)];
            }
#pragma unroll
            for (int j = 0; j < 4; ++j) {
                const int srow = wc * 64 + j * 16 + (lane & 15);
                bfr[j] = *(const bf16x8*)&Bs[srow * 72 + ((kb ^ ((srow >> 3) & 7)) << 3)];
            }
#pragma unroll
            for (int i = 0; i < 4; ++i)
#pragma unroll
                for (int j = 0; j < 4; ++j)
                    acc[i][j] = __builtin_amdgcn_mfma_f32_16x16x32_bf16(
                        af[i], bfr[j], acc[i][j], 0, 0, 0);
        }
        __syncthreads();
    }

    if constexpr (!RESID) {
        short* op = outB + (size_t)n * nStride + (size_t)chOff * cStride;
#pragma unroll
        for (int i = 0; i < 4; ++i) {
            const int mBase = m0 + wr * 64 + i * 16 + (lane >> 4) * 4;
#pragma unroll
            for (int j = 0; j < 4; ++j) {
                const int s = s0 + wc * 64 + j * 16 + (lane & 15);
#pragma unroll
                for (int r = 0; r < 4; ++r) {
                    const int m = mBase + r;
                    op[(size_t)m * cStride + s] = f2bf(acc[i][j][r] + bias[m]);
                }
            }
        }
    } else {
        float* xp = outF + (size_t)n * C2 * SP;
        const float* rbase = (m0 < 256)
            ? rgb + ((size_t)n * 256 + m0) * SP
            : flow + ((size_t)n * 256 + (m0 - 256)) * SP;
        double ls = 0.0, lss = 0.0;
#pragma unroll
        for (int i = 0; i < 4; ++i) {
            const int mBase = m0 + wr * 64 + i * 16 + (lane >> 4) * 4;
#pragma unroll
            for (int j = 0; j < 4; ++j) {
                const int s = s0 + wc * 64 + j * 16 + (lane & 15);
#pragma unroll
                for (int r = 0; r < 4; ++r) {
                    const int m = mBase + r;
                    float x = acc[i][j][r] + bias[m] +
                              rbase[(size_t)(m - m0) * SP + s];
                    xp[(size_t)m * SP + s] = x;
                    ls += (double)x;
                    lss += (double)x * (double)x;
                }
            }
        }
        __shared__ double s1[256], s2[256];
        s1[tid] = ls; s2[tid] = lss;
        __syncthreads();
        for (int st = 128; st > 0; st >>= 1) {
            if (tid < st) { s1[tid] += s1[tid + st]; s2[tid] += s2[tid + st]; }
            __syncthreads();
        }
        if (tid == 0) {
            const size_t bid = ((size_t)blockIdx.z * gridDim.y + blockIdx.y) *
                               gridDim.x + blockIdx.x;
            partials[2 * bid] = s1[0];
            partials[2 * bid + 1] = s2[0];
        }
    }
}

// ---------------- per-row (max, 1/sum exp) of K [2048 rows x S] bf16 -------
__global__ __launch_bounds__(256)
void row_stats_kernel(const short* __restrict__ K, float2* __restrict__ st)
{
    const short* p = K + (size_t)blockIdx.x * SP;
    __shared__ float sm[4];
    __shared__ float bc;
    const int tid = threadIdx.x, wv = tid >> 6, ln = tid & 63;
    float m = -1e30f;
    for (int c = tid; c < SP / 8; c += 256) {
        bf16x8 v = *(const bf16x8*)(p + c * 8);
#pragma unroll
        for (int j = 0; j < 8; ++j) m = fmaxf(m, bf2f(v[j]));
    }
    for (int o = 32; o; o >>= 1) m = fmaxf(m, __shfl_down(m, o, 64));
    if (ln == 0) sm[wv] = m;
    __syncthreads();
    if (tid == 0) bc = fmaxf(fmaxf(sm[0], sm[1]), fmaxf(sm[2], sm[3]));
    __syncthreads();
    m = bc;
    float sum = 0.f;
    for (int c = tid; c < SP / 8; c += 256) {
        bf16x8 v = *(const bf16x8*)(p + c * 8);
#pragma unroll
        for (int j = 0; j < 8; ++j) sum += __expf(bf2f(v[j]) - m);
    }
    for (int o = 32; o; o >>= 1) sum += __shfl_down(sum, o, 64);
    __syncthreads();
    if (ln == 0) sm[wv] = sum;
    __syncthreads();
    if (tid == 0) {
        float tot = sm[0] + sm[1] + sm[2] + sm[3];
        st[blockIdx.x] = (float2){m, 1.f / tot};
    }
}

// ---------------- ctx = softmax(K) . V^T (bf16 in, exp on the fly) ---------
__global__ __launch_bounds__(256)
void ctx_partial_kernel(const short* __restrict__ Kbuf, const short* __restrict__ Vbuf,
                        const float2* __restrict__ stats, float* __restrict__ part)
{
    const int chunk = blockIdx.x, nh = blockIdx.y;
    const int sBeg = chunk * 256;
    const short* Kp = Kbuf + (size_t)nh * 64 * SP;
    const short* Vp = Vbuf + (size_t)nh * 64 * SP;
    __shared__ float Ks[64][33], Vs[64][33];
    __shared__ float km[64], kinv[64];
    const int tid = threadIdx.x;
    if (tid < 64) {
        float2 s = stats[nh * 64 + tid];
        km[tid] = s.x; kinv[tid] = s.y;
    }
    __syncthreads();
    const int kk = (tid >> 4) * 4, vv = (tid & 15) * 4;
    const int lr = tid >> 2, lc = (tid & 3) * 8;
    float acc[4][4] = {};
    for (int st = 0; st < 256; st += 32) {
        bf16x8 a = *(const bf16x8*)(Kp + (size_t)lr * SP + sBeg + st + lc);
        bf16x8 b = *(const bf16x8*)(Vp + (size_t)lr * SP + sBeg + st + lc);
        const float mk = km[lr], ik = kinv[lr];
#pragma unroll
        for (int j = 0; j < 8; ++j) {
            Ks[lr][lc + j] = __expf(bf2f(a[j]) - mk) * ik;
            Vs[lr][lc + j] = bf2f(b[j]);
        }
        __syncthreads();
#pragma unroll 8
        for (int s = 0; s < 32; ++s) {
            float av[4], bv[4];
#pragma unroll
            for (int i = 0; i < 4; ++i) av[i] = Ks[kk + i][s];
#pragma unroll
            for (int j = 0; j < 4; ++j) bv[j] = Vs[vv + j][s];
#pragma unroll
            for (int i = 0; i < 4; ++i)
#pragma unroll
                for (int j = 0; j < 4; ++j)
                    acc[i][j] += av[i] * bv[j];
        }
        __syncthreads();
    }
    float* op = part + ((size_t)nh * CTX_CHUNKS + chunk) * 4096;
#pragma unroll
    for (int i = 0; i < 4; ++i)
#pragma unroll
        for (int j = 0; j < 4; ++j)
            op[(kk + i) * 64 + vv + j] = acc[i][j];
}

__global__ __launch_bounds__(256)
void ctx_reduce_kernel(const float* __restrict__ part, float* __restrict__ ctx)
{
    const int nh = blockIdx.x;
    for (int e = threadIdx.x; e < 4096; e += 256) {
        float s = 0.f;
        for (int c = 0; c < CTX_CHUNKS; ++c)
            s += part[((size_t)nh * CTX_CHUNKS + c) * 4096 + e];
        ctx[(size_t)nh * 4096 + e] = s;
    }
}

// ---------------- att[v,s] = sum_k ctx[k,v] * softmaxQ[k,s] ----------------
// Q raw bf16 [c][n][s]; fused column softmax; agg out bf16 [N,512,S].
__global__ __launch_bounds__(256)
void att_kernel(const float* __restrict__ ctx, const short* __restrict__ Qraw,
                short* __restrict__ out)
{
    const int nh = blockIdx.y;
    const int n = nh >> 3, h = nh & 7;
    const int s0 = blockIdx.x * 64;
    const float* cp = ctx + (size_t)nh * 4096;
    const size_t qrs = (size_t)NN * SP;
    const short* Qp = Qraw + (size_t)(h * 64) * qrs + (size_t)n * SP;
    short* op = out + (size_t)nh * 64 * SP;
    __shared__ float Cs[64][65];
    __shared__ float Bs[64][68];
    __shared__ float red[4][64];
    __shared__ float sinv[64];
    const int tx = threadIdx.x, ty = threadIdx.y;
    const int tid = ty * 16 + tx;
#pragma unroll
    for (int i = 0; i < 4; ++i) {
        int q = tid + i * 256;
        int k = q >> 4, v4 = (q & 15) * 4;
        float4 a = *(const float4*)&cp[k * 64 + v4];
        Cs[k][v4] = a.x; Cs[k][v4 + 1] = a.y; Cs[k][v4 + 2] = a.z; Cs[k][v4 + 3] = a.w;
    }
#pragma unroll
    for (int i = 0; i < 2; ++i) {
        int q = tid + i * 256;
        int k = q >> 3, g = (q & 7) * 8;
        bf16x8 b = *(const bf16x8*)(Qp + (size_t)k * qrs + s0 + g);
#pragma unroll
        for (int j = 0; j < 8; ++j) Bs[k][g + j] = bf2f(b[j]);
    }
    __syncthreads();
    const int sc = tid & 63, qr = tid >> 6;
    float m = -1e30f;
#pragma unroll
    for (int k = 0; k < 16; ++k) m = fmaxf(m, Bs[qr * 16 + k][sc]);
    red[qr][sc] = m;
    __syncthreads();
    m = fmaxf(fmaxf(red[0][sc], red[1][sc]), fmaxf(red[2][sc], red[3][sc]));
    __syncthreads();
    float sum = 0.f;
#pragma unroll
    for (int k = 0; k < 16; ++k) {
        float e = __expf(Bs[qr * 16 + k][sc] - m);
        Bs[qr * 16 + k][sc] = e;
        sum += e;
    }
    red[qr][sc] = sum;
    __syncthreads();
    if (qr == 0)
        sinv[sc] = 1.f / (red[0][sc] + red[1][sc] + red[2][sc] + red[3][sc]);
    __syncthreads();

    float acc[4][4] = {};
    const int v0 = ty * 4, j0 = tx * 4;
#pragma unroll 8
    for (int k = 0; k < 64; ++k) {
        float a[4], b[4];
#pragma unroll
        for (int i = 0; i < 4; ++i) a[i] = Cs[k][v0 + i];
#pragma unroll
        for (int j = 0; j < 4; ++j) b[j] = Bs[k][j0 + j];
#pragma unroll
        for (int i = 0; i < 4; ++i)
#pragma unroll
            for (int j = 0; j < 4; ++j)
                acc[i][j] += a[i] * b[j];
    }
#pragma unroll
    for (int i = 0; i < 4; ++i) {
        bf16x4 v;
#pragma unroll
        for (int j = 0; j < 4; ++j) v[j] = f2bf(acc[i][j] * sinv[j0 + j]);
        *(bf16x4*)&op[(size_t)(v0 + i) * SP + s0 + j0] = v;
    }
}

// ---------------- LN finalize ----------------------------------------------
__global__ __launch_bounds__(256)
void stats_final_kernel(const double* __restrict__ partials, float* __restrict__ mv)
{
    double ls = 0.0, lss = 0.0;
    for (int i = threadIdx.x; i < STATS_PARTS; i += 256) {
        ls += partials[2 * i];
        lss += partials[2 * i + 1];
    }
    __shared__ double s1[256], s2[256];
    const int tid = threadIdx.x;
    s1[tid] = ls; s2[tid] = lss;
    __syncthreads();
    for (int s = 128; s > 0; s >>= 1) {
        if (tid < s) { s1[tid] += s1[tid + s]; s2[tid] += s2[tid + s]; }
        __syncthreads();
    }
    if (tid == 0) {
        double mean = s1[0] / TOTAL_ELEMS;
        double var = s2[0] / TOTAL_ELEMS - mean * mean;
        mv[0] = (float)mean;
        mv[1] = (float)(1.0 / sqrt(var + 1e-5));
    }
}

__global__ __launch_bounds__(256)
void normalize_kernel(float* __restrict__ x, const float* __restrict__ mv)
{
    const float mean = mv[0], inv = mv[1];
    size_t i = ((size_t)blockIdx.x * 256 + threadIdx.x) * 4;
    const size_t tot = (size_t)NB;
    const size_t step = (size_t)gridDim.x * 1024;
    for (; i < tot; i += step) {
        float4 v = *(float4*)&x[i];
        v.x = (v.x - mean) * inv; v.y = (v.y - mean) * inv;
        v.z = (v.z - mean) * inv; v.w = (v.w - mean) * inv;
        *(float4*)&x[i] = v;
    }
}

// ---------------------------------------------------------------------------
extern "C" void kernel_launch(void* const* d_in, const int* in_sizes, int n_in,
                              void* d_out, int out_size, void* d_ws, size_t ws_size,
                              hipStream_t stream)
{
    (void)in_sizes; (void)n_in; (void)out_size; (void)ws_size;
    const float* rgb = (const float*)d_in[0];
    const float* flow = (const float*)d_in[1];
    float* ws = (float*)d_ws;

    // ws layout (f32 units); NB bf16 == NB/2 f32 units.
    short* bufK  = (short*)ws;                       // [N,512,S] bf16
    short* bufQ  = (short*)(ws + NB / 2);            // [512,N,S] bf16
    short* bufV  = (short*)(ws + NB);                // V/agg [N,512,S] bf16
    short* dwOut = (short*)(ws + 3 * NB / 2);        // [N,<=512,S] bf16 temp
    short* wB    = (short*)(ws + 2 * NB);            // 655360 bf16
    float2* rowStats = (float2*)(wB + 655360);       // 2048
    float* ctxBuf = (float*)(rowStats + 2048);       // 32*4096
    double* partials = (double*)(ctxBuf + 32 * 4096);
    float* mv = (float*)(partials + 2 * STATS_PARTS);
    float* ctxPart = (float*)dwOut;                  // alias (dead between proj & rp)

    const size_t nsA = (size_t)C2 * SP, csA = SP;          // K/V [n][c][s]
    const size_t nsB = (size_t)SP, csB = (size_t)NN * SP;  // Q   [c][n][s]

    // ---- weights -> bf16 (one dispatch) ----
    wcvt_kernel<<<2560, 256, 0, stream>>>(
        (const float*)d_in[4], (const float*)d_in[12], (const float*)d_in[16],
        (const float*)d_in[24], (const float*)d_in[8], (const float*)d_in[20],
        (const float*)d_in[28], wB);

    // ---- projections: K-rgb, V-rgb, K-flow, V-flow, Q-rgb, Q-flow ----
    const int wIdx[6] = {2, 10, 14, 22, 6, 18};
    const float* src[6] = {rgb, rgb, flow, flow, rgb, flow};
    short* dst[6] = {bufK, bufV, bufK, bufV, bufQ, bufQ};
    const int choff[6] = {0, 0, 256, 256, 0, 256};
    for (int p = 0; p < 6; ++p) {
        const int wi = wIdx[p];
        const bool layB = (p >= 4);
        dw_conv_kernel<float><<<dim3(2, C1, NN), 256, 0, stream>>>(
            src[p], (const float*)d_in[wi], (const float*)d_in[wi + 1], dwOut, C1);
        pw_mfma_kernel<false><<<dim3(SP / 128, 2, NN), 256, 0, stream>>>(
            wB + (size_t)p * 65536, (const float*)d_in[wi + 3], dwOut, dst[p],
            nullptr, nullptr, nullptr, nullptr,
            C1, layB ? nsB : nsA, layB ? csB : csA, choff[p]);
    }

    // ---- attention ----
    row_stats_kernel<<<NN * C2, 256, 0, stream>>>(bufK, rowStats);
    ctx_partial_kernel<<<dim3(CTX_CHUNKS, NN * HEADS), 256, 0, stream>>>(
        bufK, bufV, rowStats, ctxPart);
    ctx_reduce_kernel<<<NN * HEADS, 256, 0, stream>>>(ctxPart, ctxBuf);
    att_kernel<<<dim3(SP / 64, NN * HEADS), dim3(16, 16), 0, stream>>>(
        ctxBuf, bufQ, bufV);   // bufV becomes aggregated [N,512,S]

    // ---- reprojection: dw(512) -> pw GEMM (+residual +LN stats) ----
    dw_conv_kernel<short><<<dim3(2, C2, NN), 256, 0, stream>>>(
        bufV, (const float*)d_in[26], (const float*)d_in[27], dwOut, C2);
    pw_mfma_kernel<true><<<dim3(SP / 128, 4, NN), 256, 0, stream>>>(
        wB + 6 * 65536, (const float*)d_in[29], dwOut, nullptr,
        (float*)d_out, rgb, flow, partials, C2, 0, 0, 0);

    // ---- LN finalize ----
    stats_final_kernel<<<1, 256, 0, stream>>>(partials, mv);
    normalize_kernel<<<2048, 256, 0, stream>>>((float*)d_out, mv);
}

// Round 7
// 657.913 us; speedup vs baseline: 1.4729x; 1.1769x over previous
//
#include <hip/hip_runtime.h>
#include <math.h>

// ---------------------------------------------------------------------------
// EfficientAttention (dual-stream) — round 7: MFMA attention + coalesced
// LDS-transposed epilogues.
//   dw conv [c][s] (round-4 proven). pw GEMM: A gload_lds+XOR, B fused
//   transpose; epilogues route acc through LDS for coalesced stores:
//     MODE 0 (K/V):  bf16 [n][c][s]
//     MODE 1 (Q):    bf16 [n][s][512]  (rgb cols 0-255, flow 256-511)
//     MODE 2 (rp):   f32 x=acc+bias+resid -> d_out + LN double partials
//   ctx = softmax(K)·V^T via MFMA (exp folded into K staging, bf16).
//   att = ctx^T·softmaxQ via MFMA (softmax+1/sum folded into Q staging).
// ---------------------------------------------------------------------------

constexpr int NN = 4;
constexpr int C1 = 256;
constexpr int C2 = 512;
constexpr int TT = 16;
constexpr int SP = TT * 28 * 28;                  // 12544
constexpr long long NB = (long long)NN * C2 * SP; // 25,690,112
constexpr int HEADS = 8;
constexpr int CTX_CHUNKS = 7;                     // 7 chunks x 7 subtiles x 256
constexpr int STATS_PARTS = 98 * 4 * 4;           // rp GEMM grid = 1568
constexpr double TOTAL_ELEMS = (double)NB;

typedef __attribute__((ext_vector_type(8))) short bf16x8;
typedef __attribute__((ext_vector_type(4))) short bf16x4;
typedef __attribute__((ext_vector_type(4))) float f32x4;

__device__ __forceinline__ short f2bf(float f)
{
    unsigned u = __float_as_uint(f);
    unsigned r = u + 0x7FFFu + ((u >> 16) & 1u);
    return (short)(r >> 16);
}
__device__ __forceinline__ float bf2f(short s)
{
    return __uint_as_float(((unsigned)(unsigned short)s) << 16);
}
__device__ __forceinline__ float toF(float x) { return x; }
__device__ __forceinline__ float toF(short x) { return bf2f(x); }

__device__ __forceinline__ void gload16(const short* g, short* l)
{
    __builtin_amdgcn_global_load_lds(
        (const __attribute__((address_space(1))) unsigned int*)g,
        (__attribute__((address_space(3))) unsigned int*)l,
        16, 0, 0);
}

// ---------------- merged fp32 -> bf16 weight conversion --------------------
__global__ __launch_bounds__(256)
void wcvt_kernel(const float* __restrict__ w0, const float* __restrict__ w1,
                 const float* __restrict__ w2, const float* __restrict__ w3,
                 const float* __restrict__ w4, const float* __restrict__ w5,
                 const float* __restrict__ w6, short* __restrict__ out)
{
    int i = blockIdx.x * 256 + threadIdx.x;
    if (i >= 655360) return;
    const float* src; int off;
    if (i < 393216) {
        int seg = i >> 16; off = i & 65535;
        src = seg == 0 ? w0 : seg == 1 ? w1 : seg == 2 ? w2
            : seg == 3 ? w3 : seg == 4 ? w4 : w5;
    } else { src = w6; off = i - 393216; }
    out[i] = f2bf(src[off]);
}

// ---------------- depthwise 3x3x3 conv + bias -> bf16 (sliding-t) ----------
template<typename IT>
__global__ __launch_bounds__(256)
void dw_conv_kernel(const IT* __restrict__ in, const float* __restrict__ wgt,
                    const float* __restrict__ bias, short* __restrict__ out, int Cin)
{
    const int split = blockIdx.x;
    const int c = blockIdx.y, n = blockIdx.z;
    const int t0 = split * 8, t1 = t0 + 8;
    const int zs = (t0 - 1 > 0) ? t0 - 1 : 0;
    const int ze = (t1 < 15) ? t1 : 15;
    __shared__ float tile[2][900];
    const IT* inp = in + ((size_t)(n * Cin + c)) * TT * 784;
    short* op = out + ((size_t)(n * Cin + c)) * TT * 784;
    float wr[27];
#pragma unroll
    for (int i = 0; i < 27; ++i) wr[i] = wgt[c * 27 + i];
    const float bv = bias[c];
    const int tid = threadIdx.x;

    int li[4], goff[4]; bool inr[4], val[4];
#pragma unroll
    for (int p = 0; p < 4; ++p) {
        int i = tid + p * 256;
        li[p] = i;
        inr[p] = i < 900;
        int y = i / 30, x = i - y * 30;
        val[p] = inr[p] && y >= 1 && y <= 28 && x >= 1 && x <= 28;
        goff[p] = (y - 1) * 28 + (x - 1);
    }
    int hw[4];
#pragma unroll
    for (int p = 0; p < 4; ++p) {
        int idx = tid + p * 256;
        int hh = idx / 28, ww = idx - hh * 28;
        hw[p] = hh * 30 + ww;
    }
    float a0[4], a1[4], a2[4];
#pragma unroll
    for (int p = 0; p < 4; ++p) { a0[p] = bv; a1[p] = bv; a2[p] = bv; }

    for (int z = zs; z <= ze; ++z) {
        float* tb = tile[z & 1];
        const IT* gsrc = inp + (size_t)z * 784;
#pragma unroll
        for (int p = 0; p < 4; ++p)
            if (inr[p]) tb[li[p]] = val[p] ? toF(gsrc[goff[p]]) : 0.f;
        __syncthreads();
#pragma unroll
        for (int p = 0; p < 4; ++p) {
            const bool act = (p < 3) || (tid < 16);
            if (!act) continue;
            float v[9];
#pragma unroll
            for (int dh = 0; dh < 3; ++dh)
#pragma unroll
                for (int dw2 = 0; dw2 < 3; ++dw2)
                    v[dh * 3 + dw2] = tb[hw[p] + dh * 30 + dw2];
#pragma unroll
            for (int i = 0; i < 9; ++i) {
                a0[p] += v[i] * wr[18 + i];
                a1[p] += v[i] * wr[9 + i];
                a2[p] += v[i] * wr[i];
            }
        }
        if (z - 1 >= t0 && z - 1 < t1) {
#pragma unroll
            for (int p = 0; p < 4; ++p)
                if ((p < 3) || (tid < 16))
                    op[(size_t)(z - 1) * 784 + tid + p * 256] = f2bf(a0[p]);
        }
#pragma unroll
        for (int p = 0; p < 4; ++p) { a0[p] = a1[p]; a1[p] = a2[p]; a2[p] = bv; }
    }
    if (ze >= t0 && ze < t1) {
#pragma unroll
        for (int p = 0; p < 4; ++p)
            if ((p < 3) || (tid < 16))
                op[(size_t)ze * 784 + tid + p * 256] = f2bf(a0[p]);
    }
}

// ---------------- pointwise conv: bf16 MFMA GEMM ---------------------------
// MODE 0: K/V -> bf16 [n][c][s] ; MODE 1: Q -> bf16 [n][s][512] ;
// MODE 2: rp -> f32 x=acc+bias+resid [N,C2,S] + LN partials.
template<int MODE>
__global__ __launch_bounds__(256)
void pw_mfma_kernel(const short* __restrict__ Wb, const float* __restrict__ bias,
                    const short* __restrict__ act, short* __restrict__ outB,
                    float* __restrict__ outF, const float* __restrict__ rgb,
                    const float* __restrict__ flow, double* __restrict__ partials,
                    int Cin, size_t nStride, size_t cStride, int chOff)
{
    __shared__ short smem[17408];
    short* lA = smem;                 // [128][64]
    short* Bs = smem + 8192;          // [128][72]
    const int tid = threadIdx.x;
    const int w = tid >> 6, lane = tid & 63;
    const int s0 = blockIdx.x * 128;
    const int m0 = blockIdx.y * 128;
    const int n = blockIdx.z;
    const short* aSrc = Wb + (size_t)m0 * Cin;
    const short* bSrc = act + (size_t)n * Cin * SP;
    f32x4 acc[4][4];
#pragma unroll
    for (int i = 0; i < 4; ++i)
#pragma unroll
        for (int j = 0; j < 4; ++j)
            acc[i][j] = (f32x4){0.f, 0.f, 0.f, 0.f};
    const int lrow = lane >> 3, lslot = lane & 7;
    const int wr = w >> 1, wc = w & 1;

    for (int kt = 0; kt < Cin; kt += 64) {
#pragma unroll
        for (int cc = 0; cc < 4; ++cc) {
            const int chunk = w * 4 + cc;
            const int row = chunk * 8 + lrow;
            const int ss = lslot ^ (row & 7);
            gload16(aSrc + (size_t)row * Cin + kt + ss * 8, &lA[chunk * 512]);
        }
        bf16x8 breg[4];
#pragma unroll
        for (int k = 0; k < 4; ++k) {
            const int cid = tid + k * 256;
            const int krow = cid >> 4, sc = (cid & 15) * 8;
            breg[k] = *(const bf16x8*)(bSrc + (size_t)(kt + krow) * SP + s0 + sc);
        }
#pragma unroll
        for (int k = 0; k < 4; ++k) {
            const int cid = tid + k * 256;
            const int krow = cid >> 4, sc = (cid & 15) * 8;
            const int col = krow ^ (sc & 56);
#pragma unroll
            for (int j = 0; j < 8; ++j)
                Bs[(sc + j) * 72 + col] = breg[k][j];
        }
        __syncthreads();
#pragma unroll
        for (int kf = 0; kf < 2; ++kf) {
            bf16x8 af[4], bfr[4];
            const int kb = kf * 4 + (lane >> 4);
#pragma unroll
            for (int i = 0; i < 4; ++i) {
                const int row = wr * 64 + i * 16 + (lane & 15);
                af[i] = *(const bf16x8*)&lA[row * 64 + ((kb ^ (row & 7)) << 3)];
            }
#pragma unroll
            for (int j = 0; j < 4; ++j) {
                const int srow = wc * 64 + j * 16 + (lane & 15);
                bfr[j] = *(const bf16x8*)&Bs[srow * 72 + ((kb ^ ((srow >> 3) & 7)) << 3)];
            }
#pragma unroll
            for (int i = 0; i < 4; ++i)
#pragma unroll
                for (int j = 0; j < 4; ++j)
                    acc[i][j] = __builtin_amdgcn_mfma_f32_16x16x32_bf16(
                        af[i], bfr[j], acc[i][j], 0, 0, 0);
        }
        __syncthreads();
    }

    if constexpr (MODE == 0) {
        // LDS transpose: ep[m][s] bf16 [128][136], then coalesced row stores.
        short* ep = smem;
#pragma unroll
        for (int i = 0; i < 4; ++i) {
            const int mloc = wr * 64 + i * 16 + (lane >> 4) * 4;
#pragma unroll
            for (int j = 0; j < 4; ++j) {
                const int sloc = wc * 64 + j * 16 + (lane & 15);
#pragma unroll
                for (int r = 0; r < 4; ++r)
                    ep[(mloc + r) * 136 + sloc] =
                        f2bf(acc[i][j][r] + bias[m0 + mloc + r]);
            }
        }
        __syncthreads();
        short* op = outB + (size_t)n * nStride;
#pragma unroll
        for (int cc = 0; cc < 8; ++cc) {
            const int idx = tid + cc * 256;
            const int mloc = idx >> 4, ch = idx & 15;
            bf16x8 v = *(const bf16x8*)&ep[mloc * 136 + ch * 8];
            *(bf16x8*)&op[(size_t)(chOff + m0 + mloc) * cStride + s0 + ch * 8] = v;
        }
    } else if constexpr (MODE == 1) {
        // ep[s][m] bf16 [128][136] (b64-packed writes), out [n][s][512].
        short* ep = smem;
#pragma unroll
        for (int i = 0; i < 4; ++i) {
            const int mb = wr * 64 + i * 16 + (lane >> 4) * 4;
#pragma unroll
            for (int j = 0; j < 4; ++j) {
                const int sloc = wc * 64 + j * 16 + (lane & 15);
                bf16x4 pk;
#pragma unroll
                for (int r = 0; r < 4; ++r)
                    pk[r] = f2bf(acc[i][j][r] + bias[m0 + mb + r]);
                *(bf16x4*)&ep[sloc * 136 + mb] = pk;
            }
        }
        __syncthreads();
#pragma unroll
        for (int cc = 0; cc < 8; ++cc) {
            const int idx = tid + cc * 256;
            const int sloc = idx >> 4, ch = idx & 15;
            bf16x8 v = *(const bf16x8*)&ep[sloc * 136 + ch * 8];
            *(bf16x8*)&outB[((size_t)n * SP + s0 + sloc) * 512 + chOff + m0 + ch * 8] = v;
        }
    } else {
        // f32 halves via LDS [64][132]; coalesced resid read + x write + LN.
        float* ep = (float*)smem;
        float* xp = outF + (size_t)n * C2 * SP;
        const float* rbase = (m0 < 256)
            ? rgb + ((size_t)n * 256 + m0) * SP
            : flow + ((size_t)n * 256 + (m0 - 256)) * SP;
        double ls = 0.0, lss = 0.0;
#pragma unroll
        for (int p = 0; p < 2; ++p) {
            if (p) __syncthreads();
            if (wr == p) {
#pragma unroll
                for (int i = 0; i < 4; ++i) {
                    const int mloc = i * 16 + (lane >> 4) * 4;
#pragma unroll
                    for (int j = 0; j < 4; ++j) {
                        const int sloc = wc * 64 + j * 16 + (lane & 15);
#pragma unroll
                        for (int r = 0; r < 4; ++r)
                            ep[(mloc + r) * 132 + sloc] =
                                acc[i][j][r] + bias[m0 + p * 64 + mloc + r];
                    }
                }
            }
            __syncthreads();
#pragma unroll
            for (int cc = 0; cc < 8; ++cc) {
                const int idx = tid + cc * 256;
                const int row = idx >> 5, ch = idx & 31;
                const int m = m0 + p * 64 + row;
                float4 a = *(const float4*)&ep[row * 132 + ch * 4];
                float4 rs = *(const float4*)&rbase[(size_t)(p * 64 + row) * SP + s0 + ch * 4];
                float4 x;
                x.x = a.x + rs.x; x.y = a.y + rs.y;
                x.z = a.z + rs.z; x.w = a.w + rs.w;
                *(float4*)&xp[(size_t)m * SP + s0 + ch * 4] = x;
                ls += (double)x.x + (double)x.y + (double)x.z + (double)x.w;
                lss += (double)x.x * x.x + (double)x.y * x.y +
                       (double)x.z * x.z + (double)x.w * x.w;
            }
        }
        __shared__ double s1[256], s2[256];
        s1[tid] = ls; s2[tid] = lss;
        __syncthreads();
        for (int st = 128; st > 0; st >>= 1) {
            if (tid < st) { s1[tid] += s1[tid + st]; s2[tid] += s2[tid + st]; }
            __syncthreads();
        }
        if (tid == 0) {
            const size_t bid = ((size_t)blockIdx.z * gridDim.y + blockIdx.y) *
                               gridDim.x + blockIdx.x;
            partials[2 * bid] = s1[0];
            partials[2 * bid + 1] = s2[0];
        }
    }
}

// ---------------- per-row (max, 1/sum exp) of K [2048 rows x S] bf16 -------
__global__ __launch_bounds__(256)
void row_stats_kernel(const short* __restrict__ K, float2* __restrict__ st)
{
    const short* p = K + (size_t)blockIdx.x * SP;
    __shared__ float sm[4];
    __shared__ float bc;
    const int tid = threadIdx.x, wv = tid >> 6, ln = tid & 63;
    float m = -1e30f;
    for (int c = tid; c < SP / 8; c += 256) {
        bf16x8 v = *(const bf16x8*)(p + c * 8);
#pragma unroll
        for (int j = 0; j < 8; ++j) m = fmaxf(m, bf2f(v[j]));
    }
    for (int o = 32; o; o >>= 1) m = fmaxf(m, __shfl_down(m, o, 64));
    if (ln == 0) sm[wv] = m;
    __syncthreads();
    if (tid == 0) bc = fmaxf(fmaxf(sm[0], sm[1]), fmaxf(sm[2], sm[3]));
    __syncthreads();
    m = bc;
    float sum = 0.f;
    for (int c = tid; c < SP / 8; c += 256) {
        bf16x8 v = *(const bf16x8*)(p + c * 8);
#pragma unroll
        for (int j = 0; j < 8; ++j) sum += __expf(bf2f(v[j]) - m);
    }
    for (int o = 32; o; o >>= 1) sum += __shfl_down(sum, o, 64);
    __syncthreads();
    if (ln == 0) sm[wv] = sum;
    __syncthreads();
    if (tid == 0) {
        float tot = sm[0] + sm[1] + sm[2] + sm[3];
        st[blockIdx.x] = (float2){m, 1.f / tot};
    }
}

// ---------------- ctx = softmax(K) . V^T via MFMA --------------------------
// grid (7, 32): block = 64k x 64v over 7 subtiles of 256 s. exp folded into
// K staging (bf16); V via gload_lds w/ pre-swizzled source.
__global__ __launch_bounds__(256)
void ctx_mfma_kernel(const short* __restrict__ Kb, const short* __restrict__ Vb,
                     const float2* __restrict__ stats, float* __restrict__ part)
{
    const int chunk = blockIdx.x, nh = blockIdx.y;
    const short* Kp = Kb + (size_t)nh * 64 * SP;
    const short* Vp = Vb + (size_t)nh * 64 * SP;
    __shared__ short lK[64 * 256];
    __shared__ short lV[64 * 256];
    const int tid = threadIdx.x;
    const int w = tid >> 6, lane = tid & 63;
    const int wr = w >> 1, wc = w & 1;
    f32x4 acc[2][2];
#pragma unroll
    for (int i = 0; i < 2; ++i)
#pragma unroll
        for (int j = 0; j < 2; ++j)
            acc[i][j] = (f32x4){0.f, 0.f, 0.f, 0.f};

    // hoist per-thread K row stats (rows = (tid>>5) + ps*8)
    float km8[8], ki8[8];
#pragma unroll
    for (int ps = 0; ps < 8; ++ps) {
        float2 s = stats[nh * 64 + (tid >> 5) + ps * 8];
        km8[ps] = s.x; ki8[ps] = s.y;
    }

    for (int sub = 0; sub < 7; ++sub) {
        const int sOff = chunk * 1792 + sub * 256;
        // V: async, source pre-swizzled (slot' = slot ^ (row&7))
#pragma unroll
        for (int cc = 0; cc < 8; ++cc) {
            const int ch = w * 8 + cc;
            const int row = ch * 2 + (lane >> 5);
            const int sc = lane & 31;
            gload16(Vp + (size_t)row * SP + sOff + ((sc ^ (row & 7)) << 3),
                    &lV[ch * 512]);
        }
        // K: reg-stage + exp -> bf16, swizzled b128 writes
#pragma unroll
        for (int ps = 0; ps < 8; ++ps) {
            const int row = (tid >> 5) + ps * 8;
            const int sc = tid & 31;
            bf16x8 kv = *(const bf16x8*)(Kp + (size_t)row * SP + sOff + sc * 8);
            bf16x8 ev;
#pragma unroll
            for (int j = 0; j < 8; ++j)
                ev[j] = f2bf(__expf(bf2f(kv[j]) - km8[ps]) * ki8[ps]);
            *(bf16x8*)&lK[row * 256 + ((sc ^ (row & 7)) << 3)] = ev;
        }
        __syncthreads();
#pragma unroll
        for (int ks = 0; ks < 8; ++ks) {
            const int kb = ks * 4 + (lane >> 4);
            bf16x8 ak[2], bv[2];
#pragma unroll
            for (int i = 0; i < 2; ++i) {
                const int rk = wr * 32 + i * 16 + (lane & 15);
                ak[i] = *(const bf16x8*)&lK[rk * 256 + ((kb ^ (rk & 7)) << 3)];
            }
#pragma unroll
            for (int j = 0; j < 2; ++j) {
                const int rv = wc * 32 + j * 16 + (lane & 15);
                bv[j] = *(const bf16x8*)&lV[rv * 256 + ((kb ^ (rv & 7)) << 3)];
            }
#pragma unroll
            for (int i = 0; i < 2; ++i)
#pragma unroll
                for (int j = 0; j < 2; ++j)
                    acc[i][j] = __builtin_amdgcn_mfma_f32_16x16x32_bf16(
                        ak[i], bv[j], acc[i][j], 0, 0, 0);
        }
        __syncthreads();
    }
    float* op = part + ((size_t)nh * CTX_CHUNKS + chunk) * 4096;
#pragma unroll
    for (int i = 0; i < 2; ++i)
#pragma unroll
        for (int j = 0; j < 2; ++j)
#pragma unroll
            for (int r = 0; r < 4; ++r) {
                const int k = wr * 32 + i * 16 + (lane >> 4) * 4 + r;
                const int v = wc * 32 + j * 16 + (lane & 15);
                op[k * 64 + v] = acc[i][j][r];
            }
}

__global__ __launch_bounds__(256)
void ctx_reduce_kernel(const float* __restrict__ part, float* __restrict__ ctx)
{
    const int nh = blockIdx.x;
    for (int e = threadIdx.x; e < 4096; e += 256) {
        float s = 0.f;
        for (int c = 0; c < CTX_CHUNKS; ++c)
            s += part[((size_t)nh * CTX_CHUNKS + c) * 4096 + e];
        ctx[(size_t)nh * 4096 + e] = s;
    }
}

// ---------------- att = ctx^T . softmaxQ via MFMA --------------------------
// Q bf16 [n][s][512]; per-thread row softmax (1/sum folded into P);
// agg out bf16 [n][c][s] via LDS transpose.
__global__ __launch_bounds__(256)
void att_kernel(const float* __restrict__ ctx, const short* __restrict__ Qb,
                short* __restrict__ out)
{
    const int nh = blockIdx.y;
    const int n = nh >> 3, h = nh & 7;
    const int s0 = blockIdx.x * 64;
    const float* cp = ctx + (size_t)nh * 4096;
    __shared__ short lC[64 * 64];     // ctxT [v][k] swizzled
    __shared__ short lQ[64 * 64];     // P^T  [s][k] swizzled, pre-scaled
    __shared__ float red[64][4];
    __shared__ short lO[64 * 72];
    const int tid = threadIdx.x;
    const int w = tid >> 6, lane = tid & 63;

    // stage ctxT (bf16, slot = si ^ (v&7))
#pragma unroll
    for (int u = 0; u < 2; ++u) {
        const int si = (tid >> 6) + u * 4;
        const int v = tid & 63;
        bf16x8 pk;
#pragma unroll
        for (int j = 0; j < 8; ++j) pk[j] = f2bf(cp[(si * 8 + j) * 64 + v]);
        *(bf16x8*)&lC[v * 64 + ((si ^ (v & 7)) << 3)] = pk;
    }
    // Q row softmax: thread owns 16 k of row sq
    const int sq = tid >> 2, part = tid & 3;
    const short* Qrow = Qb + ((size_t)n * SP + s0 + sq) * 512 + h * 64 + part * 16;
    bf16x8 q0 = *(const bf16x8*)(Qrow);
    bf16x8 q1 = *(const bf16x8*)(Qrow + 8);
    float e[16];
    float mx = -1e30f;
#pragma unroll
    for (int j = 0; j < 8; ++j) {
        e[j] = bf2f(q0[j]); e[8 + j] = bf2f(q1[j]);
        mx = fmaxf(mx, fmaxf(e[j], e[8 + j]));
    }
    red[sq][part] = mx;
    __syncthreads();
    mx = fmaxf(fmaxf(red[sq][0], red[sq][1]), fmaxf(red[sq][2], red[sq][3]));
    float sum = 0.f;
#pragma unroll
    for (int j = 0; j < 16; ++j) { e[j] = __expf(e[j] - mx); sum += e[j]; }
    __syncthreads();
    red[sq][part] = sum;
    __syncthreads();
    const float sinv = 1.f / (red[sq][0] + red[sq][1] + red[sq][2] + red[sq][3]);
    bf16x8 p0, p1;
#pragma unroll
    for (int j = 0; j < 8; ++j) {
        p0[j] = f2bf(e[j] * sinv);
        p1[j] = f2bf(e[8 + j] * sinv);
    }
    *(bf16x8*)&lQ[sq * 64 + (((part * 2) ^ (sq & 7)) << 3)] = p0;
    *(bf16x8*)&lQ[sq * 64 + (((part * 2 + 1) ^ (sq & 7)) << 3)] = p1;
    __syncthreads();

    // MFMA: wave w -> s-cols w*16..+15, all 64 v
    f32x4 acc[4];
#pragma unroll
    for (int i = 0; i < 4; ++i) acc[i] = (f32x4){0.f, 0.f, 0.f, 0.f};
    const int srow = w * 16 + (lane & 15);
#pragma unroll
    for (int ks = 0; ks < 2; ++ks) {
        const int kb = ks * 4 + (lane >> 4);
        bf16x8 bq = *(const bf16x8*)&lQ[srow * 64 + ((kb ^ (srow & 7)) << 3)];
#pragma unroll
        for (int i = 0; i < 4; ++i) {
            const int vr = i * 16 + (lane & 15);
            bf16x8 av = *(const bf16x8*)&lC[vr * 64 + ((kb ^ (vr & 7)) << 3)];
            acc[i] = __builtin_amdgcn_mfma_f32_16x16x32_bf16(av, bq, acc[i], 0, 0, 0);
        }
    }
    // lO [v][s], then coalesced [c][s] stores
#pragma unroll
    for (int i = 0; i < 4; ++i)
#pragma unroll
        for (int r = 0; r < 4; ++r)
            lO[(i * 16 + (lane >> 4) * 4 + r) * 72 + w * 16 + (lane & 15)] =
                f2bf(acc[i][r]);
    __syncthreads();
    short* op = out + (size_t)nh * 64 * SP;
#pragma unroll
    for (int cc = 0; cc < 2; ++cc) {
        const int idx = tid + cc * 256;
        const int v = idx >> 3, ch = idx & 7;
        bf16x8 t = *(const bf16x8*)&lO[v * 72 + ch * 8];
        *(bf16x8*)&op[(size_t)v * SP + s0 + ch * 8] = t;
    }
}

// ---------------- LN finalize ----------------------------------------------
__global__ __launch_bounds__(256)
void stats_final_kernel(const double* __restrict__ partials, float* __restrict__ mv)
{
    double ls = 0.0, lss = 0.0;
    for (int i = threadIdx.x; i < STATS_PARTS; i += 256) {
        ls += partials[2 * i];
        lss += partials[2 * i + 1];
    }
    __shared__ double s1[256], s2[256];
    const int tid = threadIdx.x;
    s1[tid] = ls; s2[tid] = lss;
    __syncthreads();
    for (int s = 128; s > 0; s >>= 1) {
        if (tid < s) { s1[tid] += s1[tid + s]; s2[tid] += s2[tid + s]; }
        __syncthreads();
    }
    if (tid == 0) {
        double mean = s1[0] / TOTAL_ELEMS;
        double var = s2[0] / TOTAL_ELEMS - mean * mean;
        mv[0] = (float)mean;
        mv[1] = (float)(1.0 / sqrt(var + 1e-5));
    }
}

__global__ __launch_bounds__(256)
void normalize_kernel(float* __restrict__ x, const float* __restrict__ mv)
{
    const float mean = mv[0], inv = mv[1];
    size_t i = ((size_t)blockIdx.x * 256 + threadIdx.x) * 4;
    const size_t tot = (size_t)NB;
    const size_t step = (size_t)gridDim.x * 1024;
    for (; i < tot; i += step) {
        float4 v = *(float4*)&x[i];
        v.x = (v.x - mean) * inv; v.y = (v.y - mean) * inv;
        v.z = (v.z - mean) * inv; v.w = (v.w - mean) * inv;
        *(float4*)&x[i] = v;
    }
}

// ---------------------------------------------------------------------------
extern "C" void kernel_launch(void* const* d_in, const int* in_sizes, int n_in,
                              void* d_out, int out_size, void* d_ws, size_t ws_size,
                              hipStream_t stream)
{
    (void)in_sizes; (void)n_in; (void)out_size; (void)ws_size;
    const float* rgb = (const float*)d_in[0];
    const float* flow = (const float*)d_in[1];
    float* ws = (float*)d_ws;

    short* bufK  = (short*)ws;                       // [N,512,S] bf16
    short* bufQ  = (short*)(ws + NB / 2);            // [N,S,512] bf16
    short* bufV  = (short*)(ws + NB);                // V/agg [N,512,S] bf16
    short* dwOut = (short*)(ws + 3 * NB / 2);        // [N,<=512,S] bf16 temp
    short* wB    = (short*)(ws + 2 * NB);            // 655360 bf16
    float2* rowStats = (float2*)(wB + 655360);       // 2048
    float* ctxBuf = (float*)(rowStats + 2048);       // 32*4096
    double* partials = (double*)(ctxBuf + 32 * 4096);
    float* mv = (float*)(partials + 2 * STATS_PARTS);
    float* ctxPart = (float*)dwOut;                  // alias (dead between phases)

    const size_t nsA = (size_t)C2 * SP, csA = SP;    // K/V [n][c][s]

    wcvt_kernel<<<2560, 256, 0, stream>>>(
        (const float*)d_in[4], (const float*)d_in[12], (const float*)d_in[16],
        (const float*)d_in[24], (const float*)d_in[8], (const float*)d_in[20],
        (const float*)d_in[28], wB);

    // ---- projections: K-rgb, V-rgb, K-flow, V-flow, Q-rgb, Q-flow ----
    const int wIdx[6] = {2, 10, 14, 22, 6, 18};
    const float* src[6] = {rgb, rgb, flow, flow, rgb, flow};
    short* dst[6] = {bufK, bufV, bufK, bufV, bufQ, bufQ};
    const int choff[6] = {0, 0, 256, 256, 0, 256};
    for (int p = 0; p < 6; ++p) {
        const int wi = wIdx[p];
        dw_conv_kernel<float><<<dim3(2, C1, NN), 256, 0, stream>>>(
            src[p], (const float*)d_in[wi], (const float*)d_in[wi + 1], dwOut, C1);
        if (p < 4)
            pw_mfma_kernel<0><<<dim3(SP / 128, 2, NN), 256, 0, stream>>>(
                wB + (size_t)p * 65536, (const float*)d_in[wi + 3], dwOut, dst[p],
                nullptr, nullptr, nullptr, nullptr, C1, nsA, csA, choff[p]);
        else
            pw_mfma_kernel<1><<<dim3(SP / 128, 2, NN), 256, 0, stream>>>(
                wB + (size_t)p * 65536, (const float*)d_in[wi + 3], dwOut, dst[p],
                nullptr, nullptr, nullptr, nullptr, C1, 0, 0, choff[p]);
    }

    // ---- attention ----
    row_stats_kernel<<<NN * C2, 256, 0, stream>>>(bufK, rowStats);
    ctx_mfma_kernel<<<dim3(CTX_CHUNKS, NN * HEADS), 256, 0, stream>>>(
        bufK, bufV, rowStats, ctxPart);
    ctx_reduce_kernel<<<NN * HEADS, 256, 0, stream>>>(ctxPart, ctxBuf);
    att_kernel<<<dim3(SP / 64, NN * HEADS), 256, 0, stream>>>(
        ctxBuf, bufQ, bufV);   // bufV becomes aggregated [N,512,S]

    // ---- reprojection: dw(512) -> pw GEMM (+residual +LN stats) ----
    dw_conv_kernel<short><<<dim3(2, C2, NN), 256, 0, stream>>>(
        bufV, (const float*)d_in[26], (const float*)d_in[27], dwOut, C2);
    pw_mfma_kernel<2><<<dim3(SP / 128, 4, NN), 256, 0, stream>>>(
        wB + 6 * 65536, (const float*)d_in[29], dwOut, nullptr,
        (float*)d_out, rgb, flow, partials, C2, 0, 0, 0);

    // ---- LN finalize ----
    stats_final_kernel<<<1, 256, 0, stream>>>(partials, mv);
    normalize_kernel<<<2048, 256, 0, stream>>>((float*)d_out, mv);
}

// Round 8
// 552.999 us; speedup vs baseline: 1.7523x; 1.1897x over previous
//
#include <hip/hip_runtime.h>
#include <math.h>

// ---------------------------------------------------------------------------
// EfficientAttention (dual-stream) — round 8:
//   * pw GEMM B-staging: b64-packed swizzled scatter (8 ds_write_b64/thread
//     per K-step instead of 32 ds_write_b16); fragment-read path unchanged.
//   * dw3: fused K/Q/V depthwise conv per stream (input staged once).
//   Rest identical to round 7 (MFMA attention, LDS-transposed epilogues,
//   fused residual+LN in rp epilogue).
// ---------------------------------------------------------------------------

constexpr int NN = 4;
constexpr int C1 = 256;
constexpr int C2 = 512;
constexpr int TT = 16;
constexpr int SP = TT * 28 * 28;                  // 12544
constexpr long long NB = (long long)NN * C2 * SP; // 25,690,112
constexpr int HEADS = 8;
constexpr int CTX_CHUNKS = 7;
constexpr int STATS_PARTS = 98 * 4 * 4;           // rp GEMM grid = 1568
constexpr double TOTAL_ELEMS = (double)NB;

typedef __attribute__((ext_vector_type(8))) short bf16x8;
typedef __attribute__((ext_vector_type(4))) short bf16x4;
typedef __attribute__((ext_vector_type(4))) float f32x4;

__device__ __forceinline__ short f2bf(float f)
{
    unsigned u = __float_as_uint(f);
    unsigned r = u + 0x7FFFu + ((u >> 16) & 1u);
    return (short)(r >> 16);
}
__device__ __forceinline__ float bf2f(short s)
{
    return __uint_as_float(((unsigned)(unsigned short)s) << 16);
}
__device__ __forceinline__ float toF(float x) { return x; }
__device__ __forceinline__ float toF(short x) { return bf2f(x); }

__device__ __forceinline__ void gload16(const short* g, short* l)
{
    __builtin_amdgcn_global_load_lds(
        (const __attribute__((address_space(1))) unsigned int*)g,
        (__attribute__((address_space(3))) unsigned int*)l,
        16, 0, 0);
}

// ---------------- merged fp32 -> bf16 weight conversion --------------------
__global__ __launch_bounds__(256)
void wcvt_kernel(const float* __restrict__ w0, const float* __restrict__ w1,
                 const float* __restrict__ w2, const float* __restrict__ w3,
                 const float* __restrict__ w4, const float* __restrict__ w5,
                 const float* __restrict__ w6, short* __restrict__ out)
{
    int i = blockIdx.x * 256 + threadIdx.x;
    if (i >= 655360) return;
    const float* src; int off;
    if (i < 393216) {
        int seg = i >> 16; off = i & 65535;
        src = seg == 0 ? w0 : seg == 1 ? w1 : seg == 2 ? w2
            : seg == 3 ? w3 : seg == 4 ? w4 : w5;
    } else { src = w6; off = i - 393216; }
    out[i] = f2bf(src[off]);
}

// ---------------- fused K/Q/V depthwise 3x3x3 + bias -> bf16 ---------------
// grid: (2, 256, NN), block 256. Input staged once; 3 weight sets.
__global__ __launch_bounds__(256)
void dw3_conv_kernel(const float* __restrict__ in,
                     const float* __restrict__ wK, const float* __restrict__ bK,
                     const float* __restrict__ wQ, const float* __restrict__ bQ,
                     const float* __restrict__ wV, const float* __restrict__ bV,
                     short* __restrict__ outK, short* __restrict__ outQ,
                     short* __restrict__ outV)
{
    const int split = blockIdx.x;
    const int c = blockIdx.y, n = blockIdx.z;
    const int t0 = split * 8, t1 = t0 + 8;
    const int zs = (t0 - 1 > 0) ? t0 - 1 : 0;
    const int ze = (t1 < 15) ? t1 : 15;
    __shared__ float tile[2][900];
    const float* inp = in + ((size_t)(n * C1 + c)) * TT * 784;
    const size_t obase = ((size_t)(n * C1 + c)) * TT * 784;
    float w[3][27], bv[3];
#pragma unroll
    for (int i = 0; i < 27; ++i) {
        w[0][i] = wK[c * 27 + i];
        w[1][i] = wQ[c * 27 + i];
        w[2][i] = wV[c * 27 + i];
    }
    bv[0] = bK[c]; bv[1] = bQ[c]; bv[2] = bV[c];
    const int tid = threadIdx.x;

    int li[4], goff[4]; bool inr[4], val[4];
#pragma unroll
    for (int p = 0; p < 4; ++p) {
        int i = tid + p * 256;
        li[p] = i;
        inr[p] = i < 900;
        int y = i / 30, x = i - y * 30;
        val[p] = inr[p] && y >= 1 && y <= 28 && x >= 1 && x <= 28;
        goff[p] = (y - 1) * 28 + (x - 1);
    }
    int hw[4];
#pragma unroll
    for (int p = 0; p < 4; ++p) {
        int idx = tid + p * 256;
        int hh = idx / 28, ww = idx - hh * 28;
        hw[p] = hh * 30 + ww;
    }
    float a0[3][4], a1[3][4], a2[3][4];
#pragma unroll
    for (int g = 0; g < 3; ++g)
#pragma unroll
        for (int p = 0; p < 4; ++p) { a0[g][p] = bv[g]; a1[g][p] = bv[g]; a2[g][p] = bv[g]; }

    for (int z = zs; z <= ze; ++z) {
        float* tb = tile[z & 1];
        const float* gsrc = inp + (size_t)z * 784;
#pragma unroll
        for (int p = 0; p < 4; ++p)
            if (inr[p]) tb[li[p]] = val[p] ? gsrc[goff[p]] : 0.f;
        __syncthreads();
#pragma unroll
        for (int p = 0; p < 4; ++p) {
            const bool act = (p < 3) || (tid < 16);
            if (!act) continue;
            float v[9];
#pragma unroll
            for (int dh = 0; dh < 3; ++dh)
#pragma unroll
                for (int dw2 = 0; dw2 < 3; ++dw2)
                    v[dh * 3 + dw2] = tb[hw[p] + dh * 30 + dw2];
#pragma unroll
            for (int g = 0; g < 3; ++g)
#pragma unroll
                for (int i = 0; i < 9; ++i) {
                    a0[g][p] += v[i] * w[g][18 + i];
                    a1[g][p] += v[i] * w[g][9 + i];
                    a2[g][p] += v[i] * w[g][i];
                }
        }
        if (z - 1 >= t0 && z - 1 < t1) {
            const size_t ob = obase + (size_t)(z - 1) * 784;
#pragma unroll
            for (int p = 0; p < 4; ++p)
                if ((p < 3) || (tid < 16)) {
                    outK[ob + tid + p * 256] = f2bf(a0[0][p]);
                    outQ[ob + tid + p * 256] = f2bf(a0[1][p]);
                    outV[ob + tid + p * 256] = f2bf(a0[2][p]);
                }
        }
#pragma unroll
        for (int g = 0; g < 3; ++g)
#pragma unroll
            for (int p = 0; p < 4; ++p) {
                a0[g][p] = a1[g][p]; a1[g][p] = a2[g][p]; a2[g][p] = bv[g];
            }
    }
    if (ze >= t0 && ze < t1) {
        const size_t ob = obase + (size_t)ze * 784;
#pragma unroll
        for (int p = 0; p < 4; ++p)
            if ((p < 3) || (tid < 16)) {
                outK[ob + tid + p * 256] = f2bf(a0[0][p]);
                outQ[ob + tid + p * 256] = f2bf(a0[1][p]);
                outV[ob + tid + p * 256] = f2bf(a0[2][p]);
            }
    }
}

// ---------------- single depthwise (rp, bf16 in) ---------------------------
__global__ __launch_bounds__(256)
void dw_conv_kernel(const short* __restrict__ in, const float* __restrict__ wgt,
                    const float* __restrict__ bias, short* __restrict__ out, int Cin)
{
    const int split = blockIdx.x;
    const int c = blockIdx.y, n = blockIdx.z;
    const int t0 = split * 8, t1 = t0 + 8;
    const int zs = (t0 - 1 > 0) ? t0 - 1 : 0;
    const int ze = (t1 < 15) ? t1 : 15;
    __shared__ float tile[2][900];
    const short* inp = in + ((size_t)(n * Cin + c)) * TT * 784;
    short* op = out + ((size_t)(n * Cin + c)) * TT * 784;
    float wr[27];
#pragma unroll
    for (int i = 0; i < 27; ++i) wr[i] = wgt[c * 27 + i];
    const float bv = bias[c];
    const int tid = threadIdx.x;

    int li[4], goff[4]; bool inr[4], val[4];
#pragma unroll
    for (int p = 0; p < 4; ++p) {
        int i = tid + p * 256;
        li[p] = i;
        inr[p] = i < 900;
        int y = i / 30, x = i - y * 30;
        val[p] = inr[p] && y >= 1 && y <= 28 && x >= 1 && x <= 28;
        goff[p] = (y - 1) * 28 + (x - 1);
    }
    int hw[4];
#pragma unroll
    for (int p = 0; p < 4; ++p) {
        int idx = tid + p * 256;
        int hh = idx / 28, ww = idx - hh * 28;
        hw[p] = hh * 30 + ww;
    }
    float a0[4], a1[4], a2[4];
#pragma unroll
    for (int p = 0; p < 4; ++p) { a0[p] = bv; a1[p] = bv; a2[p] = bv; }

    for (int z = zs; z <= ze; ++z) {
        float* tb = tile[z & 1];
        const short* gsrc = inp + (size_t)z * 784;
#pragma unroll
        for (int p = 0; p < 4; ++p)
            if (inr[p]) tb[li[p]] = val[p] ? bf2f(gsrc[goff[p]]) : 0.f;
        __syncthreads();
#pragma unroll
        for (int p = 0; p < 4; ++p) {
            const bool act = (p < 3) || (tid < 16);
            if (!act) continue;
            float v[9];
#pragma unroll
            for (int dh = 0; dh < 3; ++dh)
#pragma unroll
                for (int dw2 = 0; dw2 < 3; ++dw2)
                    v[dh * 3 + dw2] = tb[hw[p] + dh * 30 + dw2];
#pragma unroll
            for (int i = 0; i < 9; ++i) {
                a0[p] += v[i] * wr[18 + i];
                a1[p] += v[i] * wr[9 + i];
                a2[p] += v[i] * wr[i];
            }
        }
        if (z - 1 >= t0 && z - 1 < t1) {
#pragma unroll
            for (int p = 0; p < 4; ++p)
                if ((p < 3) || (tid < 16))
                    op[(size_t)(z - 1) * 784 + tid + p * 256] = f2bf(a0[p]);
        }
#pragma unroll
        for (int p = 0; p < 4; ++p) { a0[p] = a1[p]; a1[p] = a2[p]; a2[p] = bv; }
    }
    if (ze >= t0 && ze < t1) {
#pragma unroll
        for (int p = 0; p < 4; ++p)
            if ((p < 3) || (tid < 16))
                op[(size_t)ze * 784 + tid + p * 256] = f2bf(a0[p]);
    }
}

// ---------------- pointwise conv: bf16 MFMA GEMM ---------------------------
// MODE 0: K/V -> bf16 [n][c][s] ; MODE 1: Q -> bf16 [n][s][512] ;
// MODE 2: rp -> f32 x=acc+bias+resid [N,C2,S] + LN partials.
template<int MODE>
__global__ __launch_bounds__(256)
void pw_mfma_kernel(const short* __restrict__ Wb, const float* __restrict__ bias,
                    const short* __restrict__ act, short* __restrict__ outB,
                    float* __restrict__ outF, const float* __restrict__ rgb,
                    const float* __restrict__ flow, double* __restrict__ partials,
                    int Cin, size_t nStride, size_t cStride, int chOff)
{
    __shared__ short smem[17408];
    short* lA = smem;                 // [128][64]
    short* Bs = smem + 8192;          // [128][72]
    const int tid = threadIdx.x;
    const int w = tid >> 6, lane = tid & 63;
    const int s0 = blockIdx.x * 128;
    const int m0 = blockIdx.y * 128;
    const int n = blockIdx.z;
    const short* aSrc = Wb + (size_t)m0 * Cin;
    const short* bSrc = act + (size_t)n * Cin * SP;
    f32x4 acc[4][4];
#pragma unroll
    for (int i = 0; i < 4; ++i)
#pragma unroll
        for (int j = 0; j < 4; ++j)
            acc[i][j] = (f32x4){0.f, 0.f, 0.f, 0.f};
    const int lrow = lane >> 3, lslot = lane & 7;
    const int wr = w >> 1, wc = w & 1;
    const int kg = tid >> 4, scb = tid & 15;   // B staging: 4 k-rows x 8 s

    for (int kt = 0; kt < Cin; kt += 64) {
        // A: async global->LDS (linear dest, source pre-swizzled)
#pragma unroll
        for (int cc = 0; cc < 4; ++cc) {
            const int chunk = w * 4 + cc;
            const int row = chunk * 8 + lrow;
            const int ss = lslot ^ (row & 7);
            gload16(aSrc + (size_t)row * Cin + kt + ss * 8, &lA[chunk * 512]);
        }
        // B: 4 coalesced k-row loads, b64-packed swizzled transpose scatter
        bf16x8 breg[4];
#pragma unroll
        for (int r = 0; r < 4; ++r)
            breg[r] = *(const bf16x8*)(bSrc + (size_t)(kt + kg * 4 + r) * SP + s0 + scb * 8);
#pragma unroll
        for (int j = 0; j < 8; ++j) {
            bf16x4 pk;
#pragma unroll
            for (int r = 0; r < 4; ++r) pk[r] = breg[r][j];
            const int srow = scb * 8 + j;
            const int slot = (kg >> 1) ^ (scb & 7);
            *(bf16x4*)&Bs[srow * 72 + slot * 8 + (kg & 1) * 4] = pk;
        }
        __syncthreads();
#pragma unroll
        for (int kf = 0; kf < 2; ++kf) {
            bf16x8 af[4], bfr[4];
            const int kb = kf * 4 + (lane >> 4);
#pragma unroll
            for (int i = 0; i < 4; ++i) {
                const int row = wr * 64 + i * 16 + (lane & 15);
                af[i] = *(const bf16x8*)&lA[row * 64 + ((kb ^ (row & 7)) << 3)];
            }
#pragma unroll
            for (int j = 0; j < 4; ++j) {
                const int srow = wc * 64 + j * 16 + (lane & 15);
                bfr[j] = *(const bf16x8*)&Bs[srow * 72 + ((kb ^ ((srow >> 3) & 7)) << 3)];
            }
#pragma unroll
            for (int i = 0; i < 4; ++i)
#pragma unroll
                for (int j = 0; j < 4; ++j)
                    acc[i][j] = __builtin_amdgcn_mfma_f32_16x16x32_bf16(
                        af[i], bfr[j], acc[i][j], 0, 0, 0);
        }
        __syncthreads();
    }

    if constexpr (MODE == 0) {
        short* ep = smem;
#pragma unroll
        for (int i = 0; i < 4; ++i) {
            const int mloc = wr * 64 + i * 16 + (lane >> 4) * 4;
#pragma unroll
            for (int j = 0; j < 4; ++j) {
                const int sloc = wc * 64 + j * 16 + (lane & 15);
#pragma unroll
                for (int r = 0; r < 4; ++r)
                    ep[(mloc + r) * 136 + sloc] =
                        f2bf(acc[i][j][r] + bias[m0 + mloc + r]);
            }
        }
        __syncthreads();
        short* op = outB + (size_t)n * nStride;
#pragma unroll
        for (int cc = 0; cc < 8; ++cc) {
            const int idx = tid + cc * 256;
            const int mloc = idx >> 4, ch = idx & 15;
            bf16x8 v = *(const bf16x8*)&ep[mloc * 136 + ch * 8];
            *(bf16x8*)&op[(size_t)(chOff + m0 + mloc) * cStride + s0 + ch * 8] = v;
        }
    } else if constexpr (MODE == 1) {
        short* ep = smem;
#pragma unroll
        for (int i = 0; i < 4; ++i) {
            const int mb = wr * 64 + i * 16 + (lane >> 4) * 4;
#pragma unroll
            for (int j = 0; j < 4; ++j) {
                const int sloc = wc * 64 + j * 16 + (lane & 15);
                bf16x4 pk;
#pragma unroll
                for (int r = 0; r < 4; ++r)
                    pk[r] = f2bf(acc[i][j][r] + bias[m0 + mb + r]);
                *(bf16x4*)&ep[sloc * 136 + mb] = pk;
            }
        }
        __syncthreads();
#pragma unroll
        for (int cc = 0; cc < 8; ++cc) {
            const int idx = tid + cc * 256;
            const int sloc = idx >> 4, ch = idx & 15;
            bf16x8 v = *(const bf16x8*)&ep[sloc * 136 + ch * 8];
            *(bf16x8*)&outB[((size_t)n * SP + s0 + sloc) * 512 + chOff + m0 + ch * 8] = v;
        }
    } else {
        float* ep = (float*)smem;
        float* xp = outF + (size_t)n * C2 * SP;
        const float* rbase = (m0 < 256)
            ? rgb + ((size_t)n * 256 + m0) * SP
            : flow + ((size_t)n * 256 + (m0 - 256)) * SP;
        double ls = 0.0, lss = 0.0;
#pragma unroll
        for (int p = 0; p < 2; ++p) {
            if (p) __syncthreads();
            if (wr == p) {
#pragma unroll
                for (int i = 0; i < 4; ++i) {
                    const int mloc = i * 16 + (lane >> 4) * 4;
#pragma unroll
                    for (int j = 0; j < 4; ++j) {
                        const int sloc = wc * 64 + j * 16 + (lane & 15);
#pragma unroll
                        for (int r = 0; r < 4; ++r)
                            ep[(mloc + r) * 132 + sloc] =
                                acc[i][j][r] + bias[m0 + p * 64 + mloc + r];
                    }
                }
            }
            __syncthreads();
#pragma unroll
            for (int cc = 0; cc < 8; ++cc) {
                const int idx = tid + cc * 256;
                const int row = idx >> 5, ch = idx & 31;
                const int m = m0 + p * 64 + row;
                float4 a = *(const float4*)&ep[row * 132 + ch * 4];
                float4 rs = *(const float4*)&rbase[(size_t)(p * 64 + row) * SP + s0 + ch * 4];
                float4 x;
                x.x = a.x + rs.x; x.y = a.y + rs.y;
                x.z = a.z + rs.z; x.w = a.w + rs.w;
                *(float4*)&xp[(size_t)m * SP + s0 + ch * 4] = x;
                ls += (double)x.x + (double)x.y + (double)x.z + (double)x.w;
                lss += (double)x.x * x.x + (double)x.y * x.y +
                       (double)x.z * x.z + (double)x.w * x.w;
            }
        }
        __shared__ double s1[256], s2[256];
        s1[tid] = ls; s2[tid] = lss;
        __syncthreads();
        for (int st = 128; st > 0; st >>= 1) {
            if (tid < st) { s1[tid] += s1[tid + st]; s2[tid] += s2[tid + st]; }
            __syncthreads();
        }
        if (tid == 0) {
            const size_t bid = ((size_t)blockIdx.z * gridDim.y + blockIdx.y) *
                               gridDim.x + blockIdx.x;
            partials[2 * bid] = s1[0];
            partials[2 * bid + 1] = s2[0];
        }
    }
}

// ---------------- per-row (max, 1/sum exp) of K [2048 rows x S] bf16 -------
__global__ __launch_bounds__(256)
void row_stats_kernel(const short* __restrict__ K, float2* __restrict__ st)
{
    const short* p = K + (size_t)blockIdx.x * SP;
    __shared__ float sm[4];
    __shared__ float bc;
    const int tid = threadIdx.x, wv = tid >> 6, ln = tid & 63;
    float m = -1e30f;
    for (int c = tid; c < SP / 8; c += 256) {
        bf16x8 v = *(const bf16x8*)(p + c * 8);
#pragma unroll
        for (int j = 0; j < 8; ++j) m = fmaxf(m, bf2f(v[j]));
    }
    for (int o = 32; o; o >>= 1) m = fmaxf(m, __shfl_down(m, o, 64));
    if (ln == 0) sm[wv] = m;
    __syncthreads();
    if (tid == 0) bc = fmaxf(fmaxf(sm[0], sm[1]), fmaxf(sm[2], sm[3]));
    __syncthreads();
    m = bc;
    float sum = 0.f;
    for (int c = tid; c < SP / 8; c += 256) {
        bf16x8 v = *(const bf16x8*)(p + c * 8);
#pragma unroll
        for (int j = 0; j < 8; ++j) sum += __expf(bf2f(v[j]) - m);
    }
    for (int o = 32; o; o >>= 1) sum += __shfl_down(sum, o, 64);
    __syncthreads();
    if (ln == 0) sm[wv] = sum;
    __syncthreads();
    if (tid == 0) {
        float tot = sm[0] + sm[1] + sm[2] + sm[3];
        st[blockIdx.x] = (float2){m, 1.f / tot};
    }
}

// ---------------- ctx = softmax(K) . V^T via MFMA --------------------------
__global__ __launch_bounds__(256)
void ctx_mfma_kernel(const short* __restrict__ Kb, const short* __restrict__ Vb,
                     const float2* __restrict__ stats, float* __restrict__ part)
{
    const int chunk = blockIdx.x, nh = blockIdx.y;
    const short* Kp = Kb + (size_t)nh * 64 * SP;
    const short* Vp = Vb + (size_t)nh * 64 * SP;
    __shared__ short lK[64 * 256];
    __shared__ short lV[64 * 256];
    const int tid = threadIdx.x;
    const int w = tid >> 6, lane = tid & 63;
    const int wr = w >> 1, wc = w & 1;
    f32x4 acc[2][2];
#pragma unroll
    for (int i = 0; i < 2; ++i)
#pragma unroll
        for (int j = 0; j < 2; ++j)
            acc[i][j] = (f32x4){0.f, 0.f, 0.f, 0.f};

    float km8[8], ki8[8];
#pragma unroll
    for (int ps = 0; ps < 8; ++ps) {
        float2 s = stats[nh * 64 + (tid >> 5) + ps * 8];
        km8[ps] = s.x; ki8[ps] = s.y;
    }

    for (int sub = 0; sub < 7; ++sub) {
        const int sOff = chunk * 1792 + sub * 256;
#pragma unroll
        for (int cc = 0; cc < 8; ++cc) {
            const int ch = w * 8 + cc;
            const int row = ch * 2 + (lane >> 5);
            const int sc = lane & 31;
            gload16(Vp + (size_t)row * SP + sOff + ((sc ^ (row & 7)) << 3),
                    &lV[ch * 512]);
        }
#pragma unroll
        for (int ps = 0; ps < 8; ++ps) {
            const int row = (tid >> 5) + ps * 8;
            const int sc = tid & 31;
            bf16x8 kv = *(const bf16x8*)(Kp + (size_t)row * SP + sOff + sc * 8);
            bf16x8 ev;
#pragma unroll
            for (int j = 0; j < 8; ++j)
                ev[j] = f2bf(__expf(bf2f(kv[j]) - km8[ps]) * ki8[ps]);
            *(bf16x8*)&lK[row * 256 + ((sc ^ (row & 7)) << 3)] = ev;
        }
        __syncthreads();
#pragma unroll
        for (int ks = 0; ks < 8; ++ks) {
            const int kb = ks * 4 + (lane >> 4);
            bf16x8 ak[2], bv[2];
#pragma unroll
            for (int i = 0; i < 2; ++i) {
                const int rk = wr * 32 + i * 16 + (lane & 15);
                ak[i] = *(const bf16x8*)&lK[rk * 256 + ((kb ^ (rk & 7)) << 3)];
            }
#pragma unroll
            for (int j = 0; j < 2; ++j) {
                const int rv = wc * 32 + j * 16 + (lane & 15);
                bv[j] = *(const bf16x8*)&lV[rv * 256 + ((kb ^ (rv & 7)) << 3)];
            }
#pragma unroll
            for (int i = 0; i < 2; ++i)
#pragma unroll
                for (int j = 0; j < 2; ++j)
                    acc[i][j] = __builtin_amdgcn_mfma_f32_16x16x32_bf16(
                        ak[i], bv[j], acc[i][j], 0, 0, 0);
        }
        __syncthreads();
    }
    float* op = part + ((size_t)nh * CTX_CHUNKS + chunk) * 4096;
#pragma unroll
    for (int i = 0; i < 2; ++i)
#pragma unroll
        for (int j = 0; j < 2; ++j)
#pragma unroll
            for (int r = 0; r < 4; ++r) {
                const int k = wr * 32 + i * 16 + (lane >> 4) * 4 + r;
                const int v = wc * 32 + j * 16 + (lane & 15);
                op[k * 64 + v] = acc[i][j][r];
            }
}

__global__ __launch_bounds__(256)
void ctx_reduce_kernel(const float* __restrict__ part, float* __restrict__ ctx)
{
    const int nh = blockIdx.x;
    for (int e = threadIdx.x; e < 4096; e += 256) {
        float s = 0.f;
        for (int c = 0; c < CTX_CHUNKS; ++c)
            s += part[((size_t)nh * CTX_CHUNKS + c) * 4096 + e];
        ctx[(size_t)nh * 4096 + e] = s;
    }
}

// ---------------- att = ctx^T . softmaxQ via MFMA --------------------------
__global__ __launch_bounds__(256)
void att_kernel(const float* __restrict__ ctx, const short* __restrict__ Qb,
                short* __restrict__ out)
{
    const int nh = blockIdx.y;
    const int n = nh >> 3, h = nh & 7;
    const int s0 = blockIdx.x * 64;
    const float* cp = ctx + (size_t)nh * 4096;
    __shared__ short lC[64 * 64];
    __shared__ short lQ[64 * 64];
    __shared__ float red[64][4];
    __shared__ short lO[64 * 72];
    const int tid = threadIdx.x;
    const int w = tid >> 6, lane = tid & 63;

#pragma unroll
    for (int u = 0; u < 2; ++u) {
        const int si = (tid >> 6) + u * 4;
        const int v = tid & 63;
        bf16x8 pk;
#pragma unroll
        for (int j = 0; j < 8; ++j) pk[j] = f2bf(cp[(si * 8 + j) * 64 + v]);
        *(bf16x8*)&lC[v * 64 + ((si ^ (v & 7)) << 3)] = pk;
    }
    const int sq = tid >> 2, qpart = tid & 3;
    const short* Qrow = Qb + ((size_t)n * SP + s0 + sq) * 512 + h * 64 + qpart * 16;
    bf16x8 q0 = *(const bf16x8*)(Qrow);
    bf16x8 q1 = *(const bf16x8*)(Qrow + 8);
    float e[16];
    float mx = -1e30f;
#pragma unroll
    for (int j = 0; j < 8; ++j) {
        e[j] = bf2f(q0[j]); e[8 + j] = bf2f(q1[j]);
        mx = fmaxf(mx, fmaxf(e[j], e[8 + j]));
    }
    red[sq][qpart] = mx;
    __syncthreads();
    mx = fmaxf(fmaxf(red[sq][0], red[sq][1]), fmaxf(red[sq][2], red[sq][3]));
    float sum = 0.f;
#pragma unroll
    for (int j = 0; j < 16; ++j) { e[j] = __expf(e[j] - mx); sum += e[j]; }
    __syncthreads();
    red[sq][qpart] = sum;
    __syncthreads();
    const float sinv = 1.f / (red[sq][0] + red[sq][1] + red[sq][2] + red[sq][3]);
    bf16x8 p0, p1;
#pragma unroll
    for (int j = 0; j < 8; ++j) {
        p0[j] = f2bf(e[j] * sinv);
        p1[j] = f2bf(e[8 + j] * sinv);
    }
    *(bf16x8*)&lQ[sq * 64 + (((qpart * 2) ^ (sq & 7)) << 3)] = p0;
    *(bf16x8*)&lQ[sq * 64 + (((qpart * 2 + 1) ^ (sq & 7)) << 3)] = p1;
    __syncthreads();

    f32x4 acc[4];
#pragma unroll
    for (int i = 0; i < 4; ++i) acc[i] = (f32x4){0.f, 0.f, 0.f, 0.f};
    const int srow = w * 16 + (lane & 15);
#pragma unroll
    for (int ks = 0; ks < 2; ++ks) {
        const int kb = ks * 4 + (lane >> 4);
        bf16x8 bq = *(const bf16x8*)&lQ[srow * 64 + ((kb ^ (srow & 7)) << 3)];
#pragma unroll
        for (int i = 0; i < 4; ++i) {
            const int vr = i * 16 + (lane & 15);
            bf16x8 av = *(const bf16x8*)&lC[vr * 64 + ((kb ^ (vr & 7)) << 3)];
            acc[i] = __builtin_amdgcn_mfma_f32_16x16x32_bf16(av, bq, acc[i], 0, 0, 0);
        }
    }
#pragma unroll
    for (int i = 0; i < 4; ++i)
#pragma unroll
        for (int r = 0; r < 4; ++r)
            lO[(i * 16 + (lane >> 4) * 4 + r) * 72 + w * 16 + (lane & 15)] =
                f2bf(acc[i][r]);
    __syncthreads();
    short* op = out + (size_t)nh * 64 * SP;
#pragma unroll
    for (int cc = 0; cc < 2; ++cc) {
        const int idx = tid + cc * 256;
        const int v = idx >> 3, ch = idx & 7;
        bf16x8 t = *(const bf16x8*)&lO[v * 72 + ch * 8];
        *(bf16x8*)&op[(size_t)v * SP + s0 + ch * 8] = t;
    }
}

// ---------------- LN finalize ----------------------------------------------
__global__ __launch_bounds__(256)
void stats_final_kernel(const double* __restrict__ partials, float* __restrict__ mv)
{
    double ls = 0.0, lss = 0.0;
    for (int i = threadIdx.x; i < STATS_PARTS; i += 256) {
        ls += partials[2 * i];
        lss += partials[2 * i + 1];
    }
    __shared__ double s1[256], s2[256];
    const int tid = threadIdx.x;
    s1[tid] = ls; s2[tid] = lss;
    __syncthreads();
    for (int s = 128; s > 0; s >>= 1) {
        if (tid < s) { s1[tid] += s1[tid + s]; s2[tid] += s2[tid + s]; }
        __syncthreads();
    }
    if (tid == 0) {
        double mean = s1[0] / TOTAL_ELEMS;
        double var = s2[0] / TOTAL_ELEMS - mean * mean;
        mv[0] = (float)mean;
        mv[1] = (float)(1.0 / sqrt(var + 1e-5));
    }
}

__global__ __launch_bounds__(256)
void normalize_kernel(float* __restrict__ x, const float* __restrict__ mv)
{
    const float mean = mv[0], inv = mv[1];
    size_t i = ((size_t)blockIdx.x * 256 + threadIdx.x) * 4;
    const size_t tot = (size_t)NB;
    const size_t step = (size_t)gridDim.x * 1024;
    for (; i < tot; i += step) {
        float4 v = *(float4*)&x[i];
        v.x = (v.x - mean) * inv; v.y = (v.y - mean) * inv;
        v.z = (v.z - mean) * inv; v.w = (v.w - mean) * inv;
        *(float4*)&x[i] = v;
    }
}

// ---------------------------------------------------------------------------
extern "C" void kernel_launch(void* const* d_in, const int* in_sizes, int n_in,
                              void* d_out, int out_size, void* d_ws, size_t ws_size,
                              hipStream_t stream)
{
    (void)in_sizes; (void)n_in; (void)out_size; (void)ws_size;
    const float* rgb = (const float*)d_in[0];
    const float* flow = (const float*)d_in[1];
    float* ws = (float*)d_ws;

    // ws layout (f32 units); [N,256,S] bf16 = NB/4 f32 units.
    short* bufK = (short*)ws;                        // [N,512,S] bf16
    short* bufQ = (short*)(ws + NB / 2);             // [N,S,512] bf16
    short* bufV = (short*)(ws + NB);                 // V/agg [N,512,S] bf16
    short* actK = (short*)(ws + 3 * NB / 2);         // [N,256,S] bf16
    short* actQ = (short*)(ws + 7 * NB / 4);         // [N,256,S] bf16
    short* actV = (short*)(ws + 2 * NB);             // [N,256,S] bf16
    short* wB   = (short*)(ws + 9 * NB / 4);         // 655360 bf16
    float2* rowStats = (float2*)(wB + 655360);       // 2048
    float* ctxBuf = (float*)(rowStats + 2048);       // 32*4096
    double* partials = (double*)(ctxBuf + 32 * 4096);
    float* mv = (float*)(partials + 2 * STATS_PARTS);
    float* ctxPart = ws + 3 * NB / 2;                // alias act region
    short* rpDw = actK;                              // rp dw out [N,512,S] bf16

    const size_t nsA = (size_t)C2 * SP, csA = SP;    // K/V [n][c][s]

    wcvt_kernel<<<2560, 256, 0, stream>>>(
        (const float*)d_in[4], (const float*)d_in[12], (const float*)d_in[16],
        (const float*)d_in[24], (const float*)d_in[8], (const float*)d_in[20],
        (const float*)d_in[28], wB);

    // ---- projections per stream: fused dw3 then 3 pw GEMMs ----
    for (int st = 0; st < 2; ++st) {
        const float* src = st ? flow : rgb;
        const int kI = st ? 14 : 2, qI = st ? 18 : 6, vI = st ? 22 : 10;
        const int choff = st ? 256 : 0;
        dw3_conv_kernel<<<dim3(2, C1, NN), 256, 0, stream>>>(
            src,
            (const float*)d_in[kI], (const float*)d_in[kI + 1],
            (const float*)d_in[qI], (const float*)d_in[qI + 1],
            (const float*)d_in[vI], (const float*)d_in[vI + 1],
            actK, actQ, actV);
        pw_mfma_kernel<0><<<dim3(SP / 128, 2, NN), 256, 0, stream>>>(
            wB + (size_t)(st ? 2 : 0) * 65536, (const float*)d_in[kI + 3], actK,
            bufK, nullptr, nullptr, nullptr, nullptr, C1, nsA, csA, choff);
        pw_mfma_kernel<0><<<dim3(SP / 128, 2, NN), 256, 0, stream>>>(
            wB + (size_t)(st ? 3 : 1) * 65536, (const float*)d_in[vI + 3], actV,
            bufV, nullptr, nullptr, nullptr, nullptr, C1, nsA, csA, choff);
        pw_mfma_kernel<1><<<dim3(SP / 128, 2, NN), 256, 0, stream>>>(
            wB + (size_t)(st ? 5 : 4) * 65536, (const float*)d_in[qI + 3], actQ,
            bufQ, nullptr, nullptr, nullptr, nullptr, C1, 0, 0, choff);
    }

    // ---- attention ----
    row_stats_kernel<<<NN * C2, 256, 0, stream>>>(bufK, rowStats);
    ctx_mfma_kernel<<<dim3(CTX_CHUNKS, NN * HEADS), 256, 0, stream>>>(
        bufK, bufV, rowStats, ctxPart);
    ctx_reduce_kernel<<<NN * HEADS, 256, 0, stream>>>(ctxPart, ctxBuf);
    att_kernel<<<dim3(SP / 64, NN * HEADS), 256, 0, stream>>>(
        ctxBuf, bufQ, bufV);   // bufV becomes aggregated [N,512,S]

    // ---- reprojection: dw(512) -> pw GEMM (+residual +LN stats) ----
    dw_conv_kernel<<<dim3(2, C2, NN), 256, 0, stream>>>(
        bufV, (const float*)d_in[26], (const float*)d_in[27], rpDw, C2);
    pw_mfma_kernel<2><<<dim3(SP / 128, 4, NN), 256, 0, stream>>>(
        wB + 6 * 65536, (const float*)d_in[29], rpDw, nullptr,
        (float*)d_out, rgb, flow, partials, C2, 0, 0, 0);

    // ---- LN finalize ----
    stats_final_kernel<<<1, 256, 0, stream>>>(partials, mv);
    normalize_kernel<<<2048, 256, 0, stream>>>((float*)d_out, mv);
}

// Round 9
// 460.444 us; speedup vs baseline: 2.1045x; 1.2010x over previous
//
#include <hip/hip_runtime.h>
#include <math.h>

// ---------------------------------------------------------------------------
// EfficientAttention (dual-stream) — round 9: prefetched vectorized depthwise.
//   dwv<IT,NSET>: 196 threads x 4 consecutive positions; register prefetch of
//   slice z+1 overlaps compute of slice z (T14); float4 staging; shared
//   window reads (18 LDS reads / 4 positions); NSET weight sets per pass.
//   Rest identical to round 8 (MFMA pw GEMMs + b64 B-scatter, MFMA attention,
//   LDS-transposed epilogues, fused residual+LN in rp epilogue).
// ---------------------------------------------------------------------------

constexpr int NN = 4;
constexpr int C1 = 256;
constexpr int C2 = 512;
constexpr int TT = 16;
constexpr int SP = TT * 28 * 28;                  // 12544
constexpr long long NB = (long long)NN * C2 * SP; // 25,690,112
constexpr int HEADS = 8;
constexpr int CTX_CHUNKS = 7;
constexpr int STATS_PARTS = 98 * 4 * 4;           // rp GEMM grid = 1568
constexpr double TOTAL_ELEMS = (double)NB;

typedef __attribute__((ext_vector_type(8))) short bf16x8;
typedef __attribute__((ext_vector_type(4))) short bf16x4;
typedef __attribute__((ext_vector_type(4))) float f32x4;

__device__ __forceinline__ short f2bf(float f)
{
    unsigned u = __float_as_uint(f);
    unsigned r = u + 0x7FFFu + ((u >> 16) & 1u);
    return (short)(r >> 16);
}
__device__ __forceinline__ float bf2f(short s)
{
    return __uint_as_float(((unsigned)(unsigned short)s) << 16);
}

__device__ __forceinline__ float4 loadvec4(const float* p)
{
    return *(const float4*)p;
}
__device__ __forceinline__ float4 loadvec4(const short* p)
{
    bf16x4 v = *(const bf16x4*)p;
    return (float4){bf2f(v[0]), bf2f(v[1]), bf2f(v[2]), bf2f(v[3])};
}

__device__ __forceinline__ void gload16(const short* g, short* l)
{
    __builtin_amdgcn_global_load_lds(
        (const __attribute__((address_space(1))) unsigned int*)g,
        (__attribute__((address_space(3))) unsigned int*)l,
        16, 0, 0);
}

// ---------------- merged fp32 -> bf16 weight conversion --------------------
__global__ __launch_bounds__(256)
void wcvt_kernel(const float* __restrict__ w0, const float* __restrict__ w1,
                 const float* __restrict__ w2, const float* __restrict__ w3,
                 const float* __restrict__ w4, const float* __restrict__ w5,
                 const float* __restrict__ w6, short* __restrict__ out)
{
    int i = blockIdx.x * 256 + threadIdx.x;
    if (i >= 655360) return;
    const float* src; int off;
    if (i < 393216) {
        int seg = i >> 16; off = i & 65535;
        src = seg == 0 ? w0 : seg == 1 ? w1 : seg == 2 ? w2
            : seg == 3 ? w3 : seg == 4 ? w4 : w5;
    } else { src = w6; off = i - 393216; }
    out[i] = f2bf(src[off]);
}

// ---------------- depthwise 3x3x3 (prefetched, vectorized) -----------------
// grid: (2, Cin, NN), block 256 (196 active in compute).
// Thread t<196 owns 4 consecutive spatial positions (one row segment).
// Register prefetch of slice z+1 overlaps the 27*NSET*4-FMA compute of z.
template<typename IT, int NSET>
__global__ __launch_bounds__(256)
void dwv_kernel(const IT* __restrict__ in,
                const float* __restrict__ w0c, const float* __restrict__ b0c,
                short* __restrict__ o0,
                const float* __restrict__ w1c, const float* __restrict__ b1c,
                short* __restrict__ o1,
                const float* __restrict__ w2c, const float* __restrict__ b2c,
                short* __restrict__ o2, int Cin)
{
    const int split = blockIdx.x, c = blockIdx.y, n = blockIdx.z;
    const int t0 = split * 8, t1 = t0 + 8;
    const int zs = (t0 - 1 > 0) ? t0 - 1 : 0;
    const int ze = (t1 < 15) ? t1 : 15;
    __shared__ float tile[2][900];
    const int tid = threadIdx.x;
    const size_t ibase = ((size_t)(n * Cin + c)) * TT * 784;
    const IT* inp = in + ibase;

    const float* wp[3] = {w0c, w1c, w2c};
    const float* bp[3] = {b0c, b1c, b2c};
    short* op[3] = {o0, o1, o2};
    float w[NSET][27], bv[NSET];
#pragma unroll
    for (int g = 0; g < NSET; ++g) {
#pragma unroll
        for (int i = 0; i < 27; ++i) w[g][i] = wp[g][c * 27 + i];
        bv[g] = bp[g][c];
    }

    // zero both ring buffers once (halo stays 0; interior rewritten per slice)
    for (int i = tid; i < 1800; i += 256) ((float*)tile)[i] = 0.f;

    const bool act = tid < 196;
    const int pos = tid * 4;
    const int hh = pos / 28, ww = pos - hh * 28;
    const int ladr = (hh + 1) * 30 + ww + 1;  // staging write base (padded)
    const int rbase = hh * 30 + ww;           // window read base (padded)

    float4 preg = {0.f, 0.f, 0.f, 0.f};
    if (act) preg = loadvec4(inp + (size_t)zs * 784 + pos);

    float a0[NSET][4], a1[NSET][4], a2[NSET][4];
#pragma unroll
    for (int g = 0; g < NSET; ++g)
#pragma unroll
        for (int k = 0; k < 4; ++k) { a0[g][k] = bv[g]; a1[g][k] = bv[g]; a2[g][k] = bv[g]; }

    for (int z = zs; z <= ze; ++z) {
        float* tb = tile[z & 1];
        __syncthreads();                      // prior reads of this buffer done
        if (act) {
            tb[ladr] = preg.x; tb[ladr + 1] = preg.y;
            tb[ladr + 2] = preg.z; tb[ladr + 3] = preg.w;
            if (z < ze) preg = loadvec4(inp + (size_t)(z + 1) * 784 + pos);
        }
        __syncthreads();
        if (act) {
            float v[3][6];
#pragma unroll
            for (int r = 0; r < 3; ++r)
#pragma unroll
                for (int j = 0; j < 6; ++j)
                    v[r][j] = tb[rbase + r * 30 + j];
#pragma unroll
            for (int g = 0; g < NSET; ++g)
#pragma unroll
                for (int dh = 0; dh < 3; ++dh)
#pragma unroll
                    for (int dw = 0; dw < 3; ++dw) {
                        const float wa = w[g][18 + dh * 3 + dw];
                        const float wb = w[g][9 + dh * 3 + dw];
                        const float wc2 = w[g][dh * 3 + dw];
#pragma unroll
                        for (int k = 0; k < 4; ++k) {
                            const float val = v[dh][k + dw];
                            a0[g][k] += val * wa;
                            a1[g][k] += val * wb;
                            a2[g][k] += val * wc2;
                        }
                    }
            if (z - 1 >= t0) {
#pragma unroll
                for (int g = 0; g < NSET; ++g) {
                    bf16x4 pk;
#pragma unroll
                    for (int k = 0; k < 4; ++k) pk[k] = f2bf(a0[g][k]);
                    *(bf16x4*)&op[g][ibase + (size_t)(z - 1) * 784 + pos] = pk;
                }
            }
#pragma unroll
            for (int g = 0; g < NSET; ++g)
#pragma unroll
                for (int k = 0; k < 4; ++k) {
                    a0[g][k] = a1[g][k]; a1[g][k] = a2[g][k]; a2[g][k] = bv[g];
                }
        }
    }
    if (act && ze >= t0 && ze < t1) {
#pragma unroll
        for (int g = 0; g < NSET; ++g) {
            bf16x4 pk;
#pragma unroll
            for (int k = 0; k < 4; ++k) pk[k] = f2bf(a0[g][k]);
            *(bf16x4*)&op[g][ibase + (size_t)ze * 784 + pos] = pk;
        }
    }
}

// ---------------- pointwise conv: bf16 MFMA GEMM ---------------------------
// MODE 0: K/V -> bf16 [n][c][s] ; MODE 1: Q -> bf16 [n][s][512] ;
// MODE 2: rp -> f32 x=acc+bias+resid [N,C2,S] + LN partials.
template<int MODE>
__global__ __launch_bounds__(256)
void pw_mfma_kernel(const short* __restrict__ Wb, const float* __restrict__ bias,
                    const short* __restrict__ act, short* __restrict__ outB,
                    float* __restrict__ outF, const float* __restrict__ rgb,
                    const float* __restrict__ flow, double* __restrict__ partials,
                    int Cin, size_t nStride, size_t cStride, int chOff)
{
    __shared__ short smem[17408];
    short* lA = smem;                 // [128][64]
    short* Bs = smem + 8192;          // [128][72]
    const int tid = threadIdx.x;
    const int w = tid >> 6, lane = tid & 63;
    const int s0 = blockIdx.x * 128;
    const int m0 = blockIdx.y * 128;
    const int n = blockIdx.z;
    const short* aSrc = Wb + (size_t)m0 * Cin;
    const short* bSrc = act + (size_t)n * Cin * SP;
    f32x4 acc[4][4];
#pragma unroll
    for (int i = 0; i < 4; ++i)
#pragma unroll
        for (int j = 0; j < 4; ++j)
            acc[i][j] = (f32x4){0.f, 0.f, 0.f, 0.f};
    const int lrow = lane >> 3, lslot = lane & 7;
    const int wr = w >> 1, wc = w & 1;
    const int kg = tid >> 4, scb = tid & 15;   // B staging: 4 k-rows x 8 s

    for (int kt = 0; kt < Cin; kt += 64) {
#pragma unroll
        for (int cc = 0; cc < 4; ++cc) {
            const int chunk = w * 4 + cc;
            const int row = chunk * 8 + lrow;
            const int ss = lslot ^ (row & 7);
            gload16(aSrc + (size_t)row * Cin + kt + ss * 8, &lA[chunk * 512]);
        }
        bf16x8 breg[4];
#pragma unroll
        for (int r = 0; r < 4; ++r)
            breg[r] = *(const bf16x8*)(bSrc + (size_t)(kt + kg * 4 + r) * SP + s0 + scb * 8);
#pragma unroll
        for (int j = 0; j < 8; ++j) {
            bf16x4 pk;
#pragma unroll
            for (int r = 0; r < 4; ++r) pk[r] = breg[r][j];
            const int srow = scb * 8 + j;
            const int slot = (kg >> 1) ^ (scb & 7);
            *(bf16x4*)&Bs[srow * 72 + slot * 8 + (kg & 1) * 4] = pk;
        }
        __syncthreads();
#pragma unroll
        for (int kf = 0; kf < 2; ++kf) {
            bf16x8 af[4], bfr[4];
            const int kb = kf * 4 + (lane >> 4);
#pragma unroll
            for (int i = 0; i < 4; ++i) {
                const int row = wr * 64 + i * 16 + (lane & 15);
                af[i] = *(const bf16x8*)&lA[row * 64 + ((kb ^ (row & 7)) << 3)];
            }
#pragma unroll
            for (int j = 0; j < 4; ++j) {
                const int srow = wc * 64 + j * 16 + (lane & 15);
                bfr[j] = *(const bf16x8*)&Bs[srow * 72 + ((kb ^ ((srow >> 3) & 7)) << 3)];
            }
#pragma unroll
            for (int i = 0; i < 4; ++i)
#pragma unroll
                for (int j = 0; j < 4; ++j)
                    acc[i][j] = __builtin_amdgcn_mfma_f32_16x16x32_bf16(
                        af[i], bfr[j], acc[i][j], 0, 0, 0);
        }
        __syncthreads();
    }

    if constexpr (MODE == 0) {
        short* ep = smem;
#pragma unroll
        for (int i = 0; i < 4; ++i) {
            const int mloc = wr * 64 + i * 16 + (lane >> 4) * 4;
#pragma unroll
            for (int j = 0; j < 4; ++j) {
                const int sloc = wc * 64 + j * 16 + (lane & 15);
#pragma unroll
                for (int r = 0; r < 4; ++r)
                    ep[(mloc + r) * 136 + sloc] =
                        f2bf(acc[i][j][r] + bias[m0 + mloc + r]);
            }
        }
        __syncthreads();
        short* op = outB + (size_t)n * nStride;
#pragma unroll
        for (int cc = 0; cc < 8; ++cc) {
            const int idx = tid + cc * 256;
            const int mloc = idx >> 4, ch = idx & 15;
            bf16x8 v = *(const bf16x8*)&ep[mloc * 136 + ch * 8];
            *(bf16x8*)&op[(size_t)(chOff + m0 + mloc) * cStride + s0 + ch * 8] = v;
        }
    } else if constexpr (MODE == 1) {
        short* ep = smem;
#pragma unroll
        for (int i = 0; i < 4; ++i) {
            const int mb = wr * 64 + i * 16 + (lane >> 4) * 4;
#pragma unroll
            for (int j = 0; j < 4; ++j) {
                const int sloc = wc * 64 + j * 16 + (lane & 15);
                bf16x4 pk;
#pragma unroll
                for (int r = 0; r < 4; ++r)
                    pk[r] = f2bf(acc[i][j][r] + bias[m0 + mb + r]);
                *(bf16x4*)&ep[sloc * 136 + mb] = pk;
            }
        }
        __syncthreads();
#pragma unroll
        for (int cc = 0; cc < 8; ++cc) {
            const int idx = tid + cc * 256;
            const int sloc = idx >> 4, ch = idx & 15;
            bf16x8 v = *(const bf16x8*)&ep[sloc * 136 + ch * 8];
            *(bf16x8*)&outB[((size_t)n * SP + s0 + sloc) * 512 + chOff + m0 + ch * 8] = v;
        }
    } else {
        float* ep = (float*)smem;
        float* xp = outF + (size_t)n * C2 * SP;
        const float* rbase = (m0 < 256)
            ? rgb + ((size_t)n * 256 + m0) * SP
            : flow + ((size_t)n * 256 + (m0 - 256)) * SP;
        double ls = 0.0, lss = 0.0;
#pragma unroll
        for (int p = 0; p < 2; ++p) {
            if (p) __syncthreads();
            if (wr == p) {
#pragma unroll
                for (int i = 0; i < 4; ++i) {
                    const int mloc = i * 16 + (lane >> 4) * 4;
#pragma unroll
                    for (int j = 0; j < 4; ++j) {
                        const int sloc = wc * 64 + j * 16 + (lane & 15);
#pragma unroll
                        for (int r = 0; r < 4; ++r)
                            ep[(mloc + r) * 132 + sloc] =
                                acc[i][j][r] + bias[m0 + p * 64 + mloc + r];
                    }
                }
            }
            __syncthreads();
#pragma unroll
            for (int cc = 0; cc < 8; ++cc) {
                const int idx = tid + cc * 256;
                const int row = idx >> 5, ch = idx & 31;
                const int m = m0 + p * 64 + row;
                float4 a = *(const float4*)&ep[row * 132 + ch * 4];
                float4 rs = *(const float4*)&rbase[(size_t)(p * 64 + row) * SP + s0 + ch * 4];
                float4 x;
                x.x = a.x + rs.x; x.y = a.y + rs.y;
                x.z = a.z + rs.z; x.w = a.w + rs.w;
                *(float4*)&xp[(size_t)m * SP + s0 + ch * 4] = x;
                ls += (double)x.x + (double)x.y + (double)x.z + (double)x.w;
                lss += (double)x.x * x.x + (double)x.y * x.y +
                       (double)x.z * x.z + (double)x.w * x.w;
            }
        }
        __shared__ double s1[256], s2[256];
        s1[tid] = ls; s2[tid] = lss;
        __syncthreads();
        for (int st = 128; st > 0; st >>= 1) {
            if (tid < st) { s1[tid] += s1[tid + st]; s2[tid] += s2[tid + st]; }
            __syncthreads();
        }
        if (tid == 0) {
            const size_t bid = ((size_t)blockIdx.z * gridDim.y + blockIdx.y) *
                               gridDim.x + blockIdx.x;
            partials[2 * bid] = s1[0];
            partials[2 * bid + 1] = s2[0];
        }
    }
}

// ---------------- per-row (max, 1/sum exp) of K [2048 rows x S] bf16 -------
__global__ __launch_bounds__(256)
void row_stats_kernel(const short* __restrict__ K, float2* __restrict__ st)
{
    const short* p = K + (size_t)blockIdx.x * SP;
    __shared__ float sm[4];
    __shared__ float bc;
    const int tid = threadIdx.x, wv = tid >> 6, ln = tid & 63;
    float m = -1e30f;
    for (int c = tid; c < SP / 8; c += 256) {
        bf16x8 v = *(const bf16x8*)(p + c * 8);
#pragma unroll
        for (int j = 0; j < 8; ++j) m = fmaxf(m, bf2f(v[j]));
    }
    for (int o = 32; o; o >>= 1) m = fmaxf(m, __shfl_down(m, o, 64));
    if (ln == 0) sm[wv] = m;
    __syncthreads();
    if (tid == 0) bc = fmaxf(fmaxf(sm[0], sm[1]), fmaxf(sm[2], sm[3]));
    __syncthreads();
    m = bc;
    float sum = 0.f;
    for (int c = tid; c < SP / 8; c += 256) {
        bf16x8 v = *(const bf16x8*)(p + c * 8);
#pragma unroll
        for (int j = 0; j < 8; ++j) sum += __expf(bf2f(v[j]) - m);
    }
    for (int o = 32; o; o >>= 1) sum += __shfl_down(sum, o, 64);
    __syncthreads();
    if (ln == 0) sm[wv] = sum;
    __syncthreads();
    if (tid == 0) {
        float tot = sm[0] + sm[1] + sm[2] + sm[3];
        st[blockIdx.x] = (float2){m, 1.f / tot};
    }
}

// ---------------- ctx = softmax(K) . V^T via MFMA --------------------------
__global__ __launch_bounds__(256)
void ctx_mfma_kernel(const short* __restrict__ Kb, const short* __restrict__ Vb,
                     const float2* __restrict__ stats, float* __restrict__ part)
{
    const int chunk = blockIdx.x, nh = blockIdx.y;
    const short* Kp = Kb + (size_t)nh * 64 * SP;
    const short* Vp = Vb + (size_t)nh * 64 * SP;
    __shared__ short lK[64 * 256];
    __shared__ short lV[64 * 256];
    const int tid = threadIdx.x;
    const int w = tid >> 6, lane = tid & 63;
    const int wr = w >> 1, wc = w & 1;
    f32x4 acc[2][2];
#pragma unroll
    for (int i = 0; i < 2; ++i)
#pragma unroll
        for (int j = 0; j < 2; ++j)
            acc[i][j] = (f32x4){0.f, 0.f, 0.f, 0.f};

    float km8[8], ki8[8];
#pragma unroll
    for (int ps = 0; ps < 8; ++ps) {
        float2 s = stats[nh * 64 + (tid >> 5) + ps * 8];
        km8[ps] = s.x; ki8[ps] = s.y;
    }

    for (int sub = 0; sub < 7; ++sub) {
        const int sOff = chunk * 1792 + sub * 256;
#pragma unroll
        for (int cc = 0; cc < 8; ++cc) {
            const int ch = w * 8 + cc;
            const int row = ch * 2 + (lane >> 5);
            const int sc = lane & 31;
            gload16(Vp + (size_t)row * SP + sOff + ((sc ^ (row & 7)) << 3),
                    &lV[ch * 512]);
        }
#pragma unroll
        for (int ps = 0; ps < 8; ++ps) {
            const int row = (tid >> 5) + ps * 8;
            const int sc = tid & 31;
            bf16x8 kv = *(const bf16x8*)(Kp + (size_t)row * SP + sOff + sc * 8);
            bf16x8 ev;
#pragma unroll
            for (int j = 0; j < 8; ++j)
                ev[j] = f2bf(__expf(bf2f(kv[j]) - km8[ps]) * ki8[ps]);
            *(bf16x8*)&lK[row * 256 + ((sc ^ (row & 7)) << 3)] = ev;
        }
        __syncthreads();
#pragma unroll
        for (int ks = 0; ks < 8; ++ks) {
            const int kb = ks * 4 + (lane >> 4);
            bf16x8 ak[2], bv[2];
#pragma unroll
            for (int i = 0; i < 2; ++i) {
                const int rk = wr * 32 + i * 16 + (lane & 15);
                ak[i] = *(const bf16x8*)&lK[rk * 256 + ((kb ^ (rk & 7)) << 3)];
            }
#pragma unroll
            for (int j = 0; j < 2; ++j) {
                const int rv = wc * 32 + j * 16 + (lane & 15);
                bv[j] = *(const bf16x8*)&lV[rv * 256 + ((kb ^ (rv & 7)) << 3)];
            }
#pragma unroll
            for (int i = 0; i < 2; ++i)
#pragma unroll
                for (int j = 0; j < 2; ++j)
                    acc[i][j] = __builtin_amdgcn_mfma_f32_16x16x32_bf16(
                        ak[i], bv[j], acc[i][j], 0, 0, 0);
        }
        __syncthreads();
    }
    float* op = part + ((size_t)nh * CTX_CHUNKS + chunk) * 4096;
#pragma unroll
    for (int i = 0; i < 2; ++i)
#pragma unroll
        for (int j = 0; j < 2; ++j)
#pragma unroll
            for (int r = 0; r < 4; ++r) {
                const int k = wr * 32 + i * 16 + (lane >> 4) * 4 + r;
                const int v = wc * 32 + j * 16 + (lane & 15);
                op[k * 64 + v] = acc[i][j][r];
            }
}

__global__ __launch_bounds__(256)
void ctx_reduce_kernel(const float* __restrict__ part, float* __restrict__ ctx)
{
    const int nh = blockIdx.x;
    for (int e = threadIdx.x; e < 4096; e += 256) {
        float s = 0.f;
        for (int c = 0; c < CTX_CHUNKS; ++c)
            s += part[((size_t)nh * CTX_CHUNKS + c) * 4096 + e];
        ctx[(size_t)nh * 4096 + e] = s;
    }
}

// ---------------- att = ctx^T . softmaxQ via MFMA --------------------------
__global__ __launch_bounds__(256)
void att_kernel(const float* __restrict__ ctx, const short* __restrict__ Qb,
                short* __restrict__ out)
{
    const int nh = blockIdx.y;
    const int n = nh >> 3, h = nh & 7;
    const int s0 = blockIdx.x * 64;
    const float* cp = ctx + (size_t)nh * 4096;
    __shared__ short lC[64 * 64];
    __shared__ short lQ[64 * 64];
    __shared__ float red[64][4];
    __shared__ short lO[64 * 72];
    const int tid = threadIdx.x;
    const int w = tid >> 6, lane = tid & 63;

#pragma unroll
    for (int u = 0; u < 2; ++u) {
        const int si = (tid >> 6) + u * 4;
        const int v = tid & 63;
        bf16x8 pk;
#pragma unroll
        for (int j = 0; j < 8; ++j) pk[j] = f2bf(cp[(si * 8 + j) * 64 + v]);
        *(bf16x8*)&lC[v * 64 + ((si ^ (v & 7)) << 3)] = pk;
    }
    const int sq = tid >> 2, qpart = tid & 3;
    const short* Qrow = Qb + ((size_t)n * SP + s0 + sq) * 512 + h * 64 + qpart * 16;
    bf16x8 q0 = *(const bf16x8*)(Qrow);
    bf16x8 q1 = *(const bf16x8*)(Qrow + 8);
    float e[16];
    float mx = -1e30f;
#pragma unroll
    for (int j = 0; j < 8; ++j) {
        e[j] = bf2f(q0[j]); e[8 + j] = bf2f(q1[j]);
        mx = fmaxf(mx, fmaxf(e[j], e[8 + j]));
    }
    red[sq][qpart] = mx;
    __syncthreads();
    mx = fmaxf(fmaxf(red[sq][0], red[sq][1]), fmaxf(red[sq][2], red[sq][3]));
    float sum = 0.f;
#pragma unroll
    for (int j = 0; j < 16; ++j) { e[j] = __expf(e[j] - mx); sum += e[j]; }
    __syncthreads();
    red[sq][qpart] = sum;
    __syncthreads();
    const float sinv = 1.f / (red[sq][0] + red[sq][1] + red[sq][2] + red[sq][3]);
    bf16x8 p0, p1;
#pragma unroll
    for (int j = 0; j < 8; ++j) {
        p0[j] = f2bf(e[j] * sinv);
        p1[j] = f2bf(e[8 + j] * sinv);
    }
    *(bf16x8*)&lQ[sq * 64 + (((qpart * 2) ^ (sq & 7)) << 3)] = p0;
    *(bf16x8*)&lQ[sq * 64 + (((qpart * 2 + 1) ^ (sq & 7)) << 3)] = p1;
    __syncthreads();

    f32x4 acc[4];
#pragma unroll
    for (int i = 0; i < 4; ++i) acc[i] = (f32x4){0.f, 0.f, 0.f, 0.f};
    const int srow = w * 16 + (lane & 15);
#pragma unroll
    for (int ks = 0; ks < 2; ++ks) {
        const int kb = ks * 4 + (lane >> 4);
        bf16x8 bq = *(const bf16x8*)&lQ[srow * 64 + ((kb ^ (srow & 7)) << 3)];
#pragma unroll
        for (int i = 0; i < 4; ++i) {
            const int vr = i * 16 + (lane & 15);
            bf16x8 av = *(const bf16x8*)&lC[vr * 64 + ((kb ^ (vr & 7)) << 3)];
            acc[i] = __builtin_amdgcn_mfma_f32_16x16x32_bf16(av, bq, acc[i], 0, 0, 0);
        }
    }
#pragma unroll
    for (int i = 0; i < 4; ++i)
#pragma unroll
        for (int r = 0; r < 4; ++r)
            lO[(i * 16 + (lane >> 4) * 4 + r) * 72 + w * 16 + (lane & 15)] =
                f2bf(acc[i][r]);
    __syncthreads();
    short* op = out + (size_t)nh * 64 * SP;
#pragma unroll
    for (int cc = 0; cc < 2; ++cc) {
        const int idx = tid + cc * 256;
        const int v = idx >> 3, ch = idx & 7;
        bf16x8 t = *(const bf16x8*)&lO[v * 72 + ch * 8];
        *(bf16x8*)&op[(size_t)v * SP + s0 + ch * 8] = t;
    }
}

// ---------------- LN finalize ----------------------------------------------
__global__ __launch_bounds__(256)
void stats_final_kernel(const double* __restrict__ partials, float* __restrict__ mv)
{
    double ls = 0.0, lss = 0.0;
    for (int i = threadIdx.x; i < STATS_PARTS; i += 256) {
        ls += partials[2 * i];
        lss += partials[2 * i + 1];
    }
    __shared__ double s1[256], s2[256];
    const int tid = threadIdx.x;
    s1[tid] = ls; s2[tid] = lss;
    __syncthreads();
    for (int s = 128; s > 0; s >>= 1) {
        if (tid < s) { s1[tid] += s1[tid + s]; s2[tid] += s2[tid + s]; }
        __syncthreads();
    }
    if (tid == 0) {
        double mean = s1[0] / TOTAL_ELEMS;
        double var = s2[0] / TOTAL_ELEMS - mean * mean;
        mv[0] = (float)mean;
        mv[1] = (float)(1.0 / sqrt(var + 1e-5));
    }
}

__global__ __launch_bounds__(256)
void normalize_kernel(float* __restrict__ x, const float* __restrict__ mv)
{
    const float mean = mv[0], inv = mv[1];
    size_t i = ((size_t)blockIdx.x * 256 + threadIdx.x) * 4;
    const size_t tot = (size_t)NB;
    const size_t step = (size_t)gridDim.x * 1024;
    for (; i < tot; i += step) {
        float4 v = *(float4*)&x[i];
        v.x = (v.x - mean) * inv; v.y = (v.y - mean) * inv;
        v.z = (v.z - mean) * inv; v.w = (v.w - mean) * inv;
        *(float4*)&x[i] = v;
    }
}

// ---------------------------------------------------------------------------
extern "C" void kernel_launch(void* const* d_in, const int* in_sizes, int n_in,
                              void* d_out, int out_size, void* d_ws, size_t ws_size,
                              hipStream_t stream)
{
    (void)in_sizes; (void)n_in; (void)out_size; (void)ws_size;
    const float* rgb = (const float*)d_in[0];
    const float* flow = (const float*)d_in[1];
    float* ws = (float*)d_ws;

    short* bufK = (short*)ws;                        // [N,512,S] bf16
    short* bufQ = (short*)(ws + NB / 2);             // [N,S,512] bf16
    short* bufV = (short*)(ws + NB);                 // V/agg [N,512,S] bf16
    short* actK = (short*)(ws + 3 * NB / 2);         // [N,256,S] bf16
    short* actQ = (short*)(ws + 7 * NB / 4);         // [N,256,S] bf16
    short* actV = (short*)(ws + 2 * NB);             // [N,256,S] bf16
    short* wB   = (short*)(ws + 9 * NB / 4);         // 655360 bf16
    float2* rowStats = (float2*)(wB + 655360);       // 2048
    float* ctxBuf = (float*)(rowStats + 2048);       // 32*4096
    double* partials = (double*)(ctxBuf + 32 * 4096);
    float* mv = (float*)(partials + 2 * STATS_PARTS);
    float* ctxPart = ws + 3 * NB / 2;                // alias act region
    short* rpDw = actK;                              // rp dw out [N,512,S] bf16

    const size_t nsA = (size_t)C2 * SP, csA = SP;    // K/V [n][c][s]

    wcvt_kernel<<<2560, 256, 0, stream>>>(
        (const float*)d_in[4], (const float*)d_in[12], (const float*)d_in[16],
        (const float*)d_in[24], (const float*)d_in[8], (const float*)d_in[20],
        (const float*)d_in[28], wB);

    // ---- projections per stream: fused dw3 then 3 pw GEMMs ----
    for (int st = 0; st < 2; ++st) {
        const float* src = st ? flow : rgb;
        const int kI = st ? 14 : 2, qI = st ? 18 : 6, vI = st ? 22 : 10;
        const int choff = st ? 256 : 0;
        dwv_kernel<float, 3><<<dim3(2, C1, NN), 256, 0, stream>>>(
            src,
            (const float*)d_in[kI], (const float*)d_in[kI + 1], actK,
            (const float*)d_in[qI], (const float*)d_in[qI + 1], actQ,
            (const float*)d_in[vI], (const float*)d_in[vI + 1], actV, C1);
        pw_mfma_kernel<0><<<dim3(SP / 128, 2, NN), 256, 0, stream>>>(
            wB + (size_t)(st ? 2 : 0) * 65536, (const float*)d_in[kI + 3], actK,
            bufK, nullptr, nullptr, nullptr, nullptr, C1, nsA, csA, choff);
        pw_mfma_kernel<0><<<dim3(SP / 128, 2, NN), 256, 0, stream>>>(
            wB + (size_t)(st ? 3 : 1) * 65536, (const float*)d_in[vI + 3], actV,
            bufV, nullptr, nullptr, nullptr, nullptr, C1, nsA, csA, choff);
        pw_mfma_kernel<1><<<dim3(SP / 128, 2, NN), 256, 0, stream>>>(
            wB + (size_t)(st ? 5 : 4) * 65536, (const float*)d_in[qI + 3], actQ,
            bufQ, nullptr, nullptr, nullptr, nullptr, C1, 0, 0, choff);
    }

    // ---- attention ----
    row_stats_kernel<<<NN * C2, 256, 0, stream>>>(bufK, rowStats);
    ctx_mfma_kernel<<<dim3(CTX_CHUNKS, NN * HEADS), 256, 0, stream>>>(
        bufK, bufV, rowStats, ctxPart);
    ctx_reduce_kernel<<<NN * HEADS, 256, 0, stream>>>(ctxPart, ctxBuf);
    att_kernel<<<dim3(SP / 64, NN * HEADS), 256, 0, stream>>>(
        ctxBuf, bufQ, bufV);   // bufV becomes aggregated [N,512,S]

    // ---- reprojection: dw(512) -> pw GEMM (+residual +LN stats) ----
    dwv_kernel<short, 1><<<dim3(2, C2, NN), 256, 0, stream>>>(
        bufV, (const float*)d_in[26], (const float*)d_in[27], rpDw,
        nullptr, nullptr, nullptr, nullptr, nullptr, nullptr, C2);
    pw_mfma_kernel<2><<<dim3(SP / 128, 4, NN), 256, 0, stream>>>(
        wB + 6 * 65536, (const float*)d_in[29], rpDw, nullptr,
        (float*)d_out, rgb, flow, partials, C2, 0, 0, 0);

    // ---- LN finalize ----
    stats_final_kernel<<<1, 256, 0, stream>>>(partials, mv);
    normalize_kernel<<<2048, 256, 0, stream>>>((float*)d_out, mv);
}

// Round 10
// 443.680 us; speedup vs baseline: 2.1841x; 1.0378x over previous
//
#include <hip/hip_runtime.h>
#include <math.h>

// ---------------------------------------------------------------------------
// EfficientAttention (dual-stream) — round 10: 2-phase prefetched pw GEMM.
//   pw_mfma: double-buffered LDS (A dma + B reg-stage for tile t+1 issued
//   before MFMA of tile t; scatter after; ONE barrier per K-step). Epilogues,
//   attention, dwv, LN fusion identical to round 9.
// ---------------------------------------------------------------------------

constexpr int NN = 4;
constexpr int C1 = 256;
constexpr int C2 = 512;
constexpr int TT = 16;
constexpr int SP = TT * 28 * 28;                  // 12544
constexpr long long NB = (long long)NN * C2 * SP; // 25,690,112
constexpr int HEADS = 8;
constexpr int CTX_CHUNKS = 7;
constexpr int STATS_PARTS = 98 * 4 * 4;           // rp GEMM grid = 1568
constexpr double TOTAL_ELEMS = (double)NB;

typedef __attribute__((ext_vector_type(8))) short bf16x8;
typedef __attribute__((ext_vector_type(4))) short bf16x4;
typedef __attribute__((ext_vector_type(4))) float f32x4;

__device__ __forceinline__ short f2bf(float f)
{
    unsigned u = __float_as_uint(f);
    unsigned r = u + 0x7FFFu + ((u >> 16) & 1u);
    return (short)(r >> 16);
}
__device__ __forceinline__ float bf2f(short s)
{
    return __uint_as_float(((unsigned)(unsigned short)s) << 16);
}

__device__ __forceinline__ float4 loadvec4(const float* p)
{
    return *(const float4*)p;
}
__device__ __forceinline__ float4 loadvec4(const short* p)
{
    bf16x4 v = *(const bf16x4*)p;
    return (float4){bf2f(v[0]), bf2f(v[1]), bf2f(v[2]), bf2f(v[3])};
}

__device__ __forceinline__ void gload16(const short* g, short* l)
{
    __builtin_amdgcn_global_load_lds(
        (const __attribute__((address_space(1))) unsigned int*)g,
        (__attribute__((address_space(3))) unsigned int*)l,
        16, 0, 0);
}

// ---------------- merged fp32 -> bf16 weight conversion --------------------
__global__ __launch_bounds__(256)
void wcvt_kernel(const float* __restrict__ w0, const float* __restrict__ w1,
                 const float* __restrict__ w2, const float* __restrict__ w3,
                 const float* __restrict__ w4, const float* __restrict__ w5,
                 const float* __restrict__ w6, short* __restrict__ out)
{
    int i = blockIdx.x * 256 + threadIdx.x;
    if (i >= 655360) return;
    const float* src; int off;
    if (i < 393216) {
        int seg = i >> 16; off = i & 65535;
        src = seg == 0 ? w0 : seg == 1 ? w1 : seg == 2 ? w2
            : seg == 3 ? w3 : seg == 4 ? w4 : w5;
    } else { src = w6; off = i - 393216; }
    out[i] = f2bf(src[off]);
}

// ---------------- depthwise 3x3x3 (prefetched, vectorized) -----------------
// grid: (2, Cin, NN), block 256 (196 active in compute).
template<typename IT, int NSET>
__global__ __launch_bounds__(256)
void dwv_kernel(const IT* __restrict__ in,
                const float* __restrict__ w0c, const float* __restrict__ b0c,
                short* __restrict__ o0,
                const float* __restrict__ w1c, const float* __restrict__ b1c,
                short* __restrict__ o1,
                const float* __restrict__ w2c, const float* __restrict__ b2c,
                short* __restrict__ o2, int Cin)
{
    const int split = blockIdx.x, c = blockIdx.y, n = blockIdx.z;
    const int t0 = split * 8, t1 = t0 + 8;
    const int zs = (t0 - 1 > 0) ? t0 - 1 : 0;
    const int ze = (t1 < 15) ? t1 : 15;
    __shared__ float tile[2][900];
    const int tid = threadIdx.x;
    const size_t ibase = ((size_t)(n * Cin + c)) * TT * 784;
    const IT* inp = in + ibase;

    const float* wp[3] = {w0c, w1c, w2c};
    const float* bp[3] = {b0c, b1c, b2c};
    short* op[3] = {o0, o1, o2};
    float w[NSET][27], bv[NSET];
#pragma unroll
    for (int g = 0; g < NSET; ++g) {
#pragma unroll
        for (int i = 0; i < 27; ++i) w[g][i] = wp[g][c * 27 + i];
        bv[g] = bp[g][c];
    }

    for (int i = tid; i < 1800; i += 256) ((float*)tile)[i] = 0.f;

    const bool act = tid < 196;
    const int pos = tid * 4;
    const int hh = pos / 28, ww = pos - hh * 28;
    const int ladr = (hh + 1) * 30 + ww + 1;
    const int rbase = hh * 30 + ww;

    float4 preg = {0.f, 0.f, 0.f, 0.f};
    if (act) preg = loadvec4(inp + (size_t)zs * 784 + pos);

    float a0[NSET][4], a1[NSET][4], a2[NSET][4];
#pragma unroll
    for (int g = 0; g < NSET; ++g)
#pragma unroll
        for (int k = 0; k < 4; ++k) { a0[g][k] = bv[g]; a1[g][k] = bv[g]; a2[g][k] = bv[g]; }

    for (int z = zs; z <= ze; ++z) {
        float* tb = tile[z & 1];
        __syncthreads();
        if (act) {
            tb[ladr] = preg.x; tb[ladr + 1] = preg.y;
            tb[ladr + 2] = preg.z; tb[ladr + 3] = preg.w;
            if (z < ze) preg = loadvec4(inp + (size_t)(z + 1) * 784 + pos);
        }
        __syncthreads();
        if (act) {
            float v[3][6];
#pragma unroll
            for (int r = 0; r < 3; ++r)
#pragma unroll
                for (int j = 0; j < 6; ++j)
                    v[r][j] = tb[rbase + r * 30 + j];
#pragma unroll
            for (int g = 0; g < NSET; ++g)
#pragma unroll
                for (int dh = 0; dh < 3; ++dh)
#pragma unroll
                    for (int dw = 0; dw < 3; ++dw) {
                        const float wa = w[g][18 + dh * 3 + dw];
                        const float wb = w[g][9 + dh * 3 + dw];
                        const float wc2 = w[g][dh * 3 + dw];
#pragma unroll
                        for (int k = 0; k < 4; ++k) {
                            const float val = v[dh][k + dw];
                            a0[g][k] += val * wa;
                            a1[g][k] += val * wb;
                            a2[g][k] += val * wc2;
                        }
                    }
            if (z - 1 >= t0) {
#pragma unroll
                for (int g = 0; g < NSET; ++g) {
                    bf16x4 pk;
#pragma unroll
                    for (int k = 0; k < 4; ++k) pk[k] = f2bf(a0[g][k]);
                    *(bf16x4*)&op[g][ibase + (size_t)(z - 1) * 784 + pos] = pk;
                }
            }
#pragma unroll
            for (int g = 0; g < NSET; ++g)
#pragma unroll
                for (int k = 0; k < 4; ++k) {
                    a0[g][k] = a1[g][k]; a1[g][k] = a2[g][k]; a2[g][k] = bv[g];
                }
        }
    }
    if (act && ze >= t0 && ze < t1) {
#pragma unroll
        for (int g = 0; g < NSET; ++g) {
            bf16x4 pk;
#pragma unroll
            for (int k = 0; k < 4; ++k) pk[k] = f2bf(a0[g][k]);
            *(bf16x4*)&op[g][ibase + (size_t)ze * 784 + pos] = pk;
        }
    }
}

// ---------------- pointwise conv: bf16 MFMA GEMM (2-phase prefetch) --------
// MODE 0: K/V -> bf16 [n][c][s] ; MODE 1: Q -> bf16 [n][s][512] ;
// MODE 2: rp -> f32 x=acc+bias+resid [N,C2,S] + LN partials.
// LDS dbuf: A[2] 128x64, B[2] 128x72 (69632 B). One barrier per K-step;
// next tile's A-dma + B-reg loads issue before current tile's MFMA.
template<int MODE>
__global__ __launch_bounds__(256)
void pw_mfma_kernel(const short* __restrict__ Wb, const float* __restrict__ bias,
                    const short* __restrict__ act, short* __restrict__ outB,
                    float* __restrict__ outF, const float* __restrict__ rgb,
                    const float* __restrict__ flow, double* __restrict__ partials,
                    int Cin, size_t nStride, size_t cStride, int chOff)
{
    __shared__ short smem[34816];     // 69632 B: lA 8192x2 | Bs 9216x2
    const int tid = threadIdx.x;
    const int w = tid >> 6, lane = tid & 63;
    const int s0 = blockIdx.x * 128;
    const int m0 = blockIdx.y * 128;
    const int n = blockIdx.z;
    const short* aSrc = Wb + (size_t)m0 * Cin;
    const short* bSrc = act + (size_t)n * Cin * SP;
    f32x4 acc[4][4];
#pragma unroll
    for (int i = 0; i < 4; ++i)
#pragma unroll
        for (int j = 0; j < 4; ++j)
            acc[i][j] = (f32x4){0.f, 0.f, 0.f, 0.f};
    const int lrow = lane >> 3, lslot = lane & 7;
    const int wr = w >> 1, wc = w & 1;
    const int kg = tid >> 4, scb = tid & 15;   // B staging: 4 k-rows x 8 s
    const int nt = Cin >> 6;

    // ---- prologue: stage tile 0 into buffer 0 ----
    {
        short* nA = smem;
        short* nB = smem + 16384;
#pragma unroll
        for (int cc = 0; cc < 4; ++cc) {
            const int chunk = w * 4 + cc;
            const int row = chunk * 8 + lrow;
            const int ss = lslot ^ (row & 7);
            gload16(aSrc + (size_t)row * Cin + ss * 8, &nA[chunk * 512]);
        }
        bf16x8 breg[4];
#pragma unroll
        for (int r = 0; r < 4; ++r)
            breg[r] = *(const bf16x8*)(bSrc + (size_t)(kg * 4 + r) * SP + s0 + scb * 8);
#pragma unroll
        for (int j = 0; j < 8; ++j) {
            bf16x4 pk;
#pragma unroll
            for (int r = 0; r < 4; ++r) pk[r] = breg[r][j];
            const int srow = scb * 8 + j;
            const int slot = (kg >> 1) ^ (scb & 7);
            *(bf16x4*)&nB[srow * 72 + slot * 8 + (kg & 1) * 4] = pk;
        }
    }
    __syncthreads();

    for (int t = 0; t < nt; ++t) {
        short* cA = smem + (t & 1) * 8192;
        short* cB = smem + 16384 + (t & 1) * 9216;
        short* nA = smem + ((t + 1) & 1) * 8192;
        short* nB = smem + 16384 + ((t + 1) & 1) * 9216;
        const bool more = (t + 1) < nt;
        bf16x8 bnext[4];
        if (more) {
            const int kt = (t + 1) << 6;
#pragma unroll
            for (int cc = 0; cc < 4; ++cc) {
                const int chunk = w * 4 + cc;
                const int row = chunk * 8 + lrow;
                const int ss = lslot ^ (row & 7);
                gload16(aSrc + (size_t)row * Cin + kt + ss * 8, &nA[chunk * 512]);
            }
#pragma unroll
            for (int r = 0; r < 4; ++r)
                bnext[r] = *(const bf16x8*)(bSrc + (size_t)(kt + kg * 4 + r) * SP + s0 + scb * 8);
        }
        // ---- MFMA on current buffers (prefetch latency hides here) ----
#pragma unroll
        for (int kf = 0; kf < 2; ++kf) {
            bf16x8 af[4], bfr[4];
            const int kb = kf * 4 + (lane >> 4);
#pragma unroll
            for (int i = 0; i < 4; ++i) {
                const int row = wr * 64 + i * 16 + (lane & 15);
                af[i] = *(const bf16x8*)&cA[row * 64 + ((kb ^ (row & 7)) << 3)];
            }
#pragma unroll
            for (int j = 0; j < 4; ++j) {
                const int srow = wc * 64 + j * 16 + (lane & 15);
                bfr[j] = *(const bf16x8*)&cB[srow * 72 + ((kb ^ ((srow >> 3) & 7)) << 3)];
            }
#pragma unroll
            for (int i = 0; i < 4; ++i)
#pragma unroll
                for (int j = 0; j < 4; ++j)
                    acc[i][j] = __builtin_amdgcn_mfma_f32_16x16x32_bf16(
                        af[i], bfr[j], acc[i][j], 0, 0, 0);
        }
        if (more) {
#pragma unroll
            for (int j = 0; j < 8; ++j) {
                bf16x4 pk;
#pragma unroll
                for (int r = 0; r < 4; ++r) pk[r] = bnext[r][j];
                const int srow = scb * 8 + j;
                const int slot = (kg >> 1) ^ (scb & 7);
                *(bf16x4*)&nB[srow * 72 + slot * 8 + (kg & 1) * 4] = pk;
            }
        }
        __syncthreads();
    }

    if constexpr (MODE == 0) {
        short* ep = smem;
#pragma unroll
        for (int i = 0; i < 4; ++i) {
            const int mloc = wr * 64 + i * 16 + (lane >> 4) * 4;
#pragma unroll
            for (int j = 0; j < 4; ++j) {
                const int sloc = wc * 64 + j * 16 + (lane & 15);
#pragma unroll
                for (int r = 0; r < 4; ++r)
                    ep[(mloc + r) * 136 + sloc] =
                        f2bf(acc[i][j][r] + bias[m0 + mloc + r]);
            }
        }
        __syncthreads();
        short* op = outB + (size_t)n * nStride;
#pragma unroll
        for (int cc = 0; cc < 8; ++cc) {
            const int idx = tid + cc * 256;
            const int mloc = idx >> 4, ch = idx & 15;
            bf16x8 v = *(const bf16x8*)&ep[mloc * 136 + ch * 8];
            *(bf16x8*)&op[(size_t)(chOff + m0 + mloc) * cStride + s0 + ch * 8] = v;
        }
    } else if constexpr (MODE == 1) {
        short* ep = smem;
#pragma unroll
        for (int i = 0; i < 4; ++i) {
            const int mb = wr * 64 + i * 16 + (lane >> 4) * 4;
#pragma unroll
            for (int j = 0; j < 4; ++j) {
                const int sloc = wc * 64 + j * 16 + (lane & 15);
                bf16x4 pk;
#pragma unroll
                for (int r = 0; r < 4; ++r)
                    pk[r] = f2bf(acc[i][j][r] + bias[m0 + mb + r]);
                *(bf16x4*)&ep[sloc * 136 + mb] = pk;
            }
        }
        __syncthreads();
#pragma unroll
        for (int cc = 0; cc < 8; ++cc) {
            const int idx = tid + cc * 256;
            const int sloc = idx >> 4, ch = idx & 15;
            bf16x8 v = *(const bf16x8*)&ep[sloc * 136 + ch * 8];
            *(bf16x8*)&outB[((size_t)n * SP + s0 + sloc) * 512 + chOff + m0 + ch * 8] = v;
        }
    } else {
        float* ep = (float*)smem;
        float* xp = outF + (size_t)n * C2 * SP;
        const float* rbase = (m0 < 256)
            ? rgb + ((size_t)n * 256 + m0) * SP
            : flow + ((size_t)n * 256 + (m0 - 256)) * SP;
        double ls = 0.0, lss = 0.0;
#pragma unroll
        for (int p = 0; p < 2; ++p) {
            if (p) __syncthreads();
            if (wr == p) {
#pragma unroll
                for (int i = 0; i < 4; ++i) {
                    const int mloc = i * 16 + (lane >> 4) * 4;
#pragma unroll
                    for (int j = 0; j < 4; ++j) {
                        const int sloc = wc * 64 + j * 16 + (lane & 15);
#pragma unroll
                        for (int r = 0; r < 4; ++r)
                            ep[(mloc + r) * 132 + sloc] =
                                acc[i][j][r] + bias[m0 + p * 64 + mloc + r];
                    }
                }
            }
            __syncthreads();
#pragma unroll
            for (int cc = 0; cc < 8; ++cc) {
                const int idx = tid + cc * 256;
                const int row = idx >> 5, ch = idx & 31;
                const int m = m0 + p * 64 + row;
                float4 a = *(const float4*)&ep[row * 132 + ch * 4];
                float4 rs = *(const float4*)&rbase[(size_t)(p * 64 + row) * SP + s0 + ch * 4];
                float4 x;
                x.x = a.x + rs.x; x.y = a.y + rs.y;
                x.z = a.z + rs.z; x.w = a.w + rs.w;
                *(float4*)&xp[(size_t)m * SP + s0 + ch * 4] = x;
                ls += (double)x.x + (double)x.y + (double)x.z + (double)x.w;
                lss += (double)x.x * x.x + (double)x.y * x.y +
                       (double)x.z * x.z + (double)x.w * x.w;
            }
        }
        __shared__ double s1[256], s2[256];
        s1[tid] = ls; s2[tid] = lss;
        __syncthreads();
        for (int st = 128; st > 0; st >>= 1) {
            if (tid < st) { s1[tid] += s1[tid + st]; s2[tid] += s2[tid + st]; }
            __syncthreads();
        }
        if (tid == 0) {
            const size_t bid = ((size_t)blockIdx.z * gridDim.y + blockIdx.y) *
                               gridDim.x + blockIdx.x;
            partials[2 * bid] = s1[0];
            partials[2 * bid + 1] = s2[0];
        }
    }
}

// ---------------- per-row (max, 1/sum exp) of K [2048 rows x S] bf16 -------
__global__ __launch_bounds__(256)
void row_stats_kernel(const short* __restrict__ K, float2* __restrict__ st)
{
    const short* p = K + (size_t)blockIdx.x * SP;
    __shared__ float sm[4];
    __shared__ float bc;
    const int tid = threadIdx.x, wv = tid >> 6, ln = tid & 63;
    float m = -1e30f;
    for (int c = tid; c < SP / 8; c += 256) {
        bf16x8 v = *(const bf16x8*)(p + c * 8);
#pragma unroll
        for (int j = 0; j < 8; ++j) m = fmaxf(m, bf2f(v[j]));
    }
    for (int o = 32; o; o >>= 1) m = fmaxf(m, __shfl_down(m, o, 64));
    if (ln == 0) sm[wv] = m;
    __syncthreads();
    if (tid == 0) bc = fmaxf(fmaxf(sm[0], sm[1]), fmaxf(sm[2], sm[3]));
    __syncthreads();
    m = bc;
    float sum = 0.f;
    for (int c = tid; c < SP / 8; c += 256) {
        bf16x8 v = *(const bf16x8*)(p + c * 8);
#pragma unroll
        for (int j = 0; j < 8; ++j) sum += __expf(bf2f(v[j]) - m);
    }
    for (int o = 32; o; o >>= 1) sum += __shfl_down(sum, o, 64);
    __syncthreads();
    if (ln == 0) sm[wv] = sum;
    __syncthreads();
    if (tid == 0) {
        float tot = sm[0] + sm[1] + sm[2] + sm[3];
        st[blockIdx.x] = (float2){m, 1.f / tot};
    }
}

// ---------------- ctx = softmax(K) . V^T via MFMA --------------------------
__global__ __launch_bounds__(256)
void ctx_mfma_kernel(const short* __restrict__ Kb, const short* __restrict__ Vb,
                     const float2* __restrict__ stats, float* __restrict__ part)
{
    const int chunk = blockIdx.x, nh = blockIdx.y;
    const short* Kp = Kb + (size_t)nh * 64 * SP;
    const short* Vp = Vb + (size_t)nh * 64 * SP;
    __shared__ short lK[64 * 256];
    __shared__ short lV[64 * 256];
    const int tid = threadIdx.x;
    const int w = tid >> 6, lane = tid & 63;
    const int wr = w >> 1, wc = w & 1;
    f32x4 acc[2][2];
#pragma unroll
    for (int i = 0; i < 2; ++i)
#pragma unroll
        for (int j = 0; j < 2; ++j)
            acc[i][j] = (f32x4){0.f, 0.f, 0.f, 0.f};

    float km8[8], ki8[8];
#pragma unroll
    for (int ps = 0; ps < 8; ++ps) {
        float2 s = stats[nh * 64 + (tid >> 5) + ps * 8];
        km8[ps] = s.x; ki8[ps] = s.y;
    }

    for (int sub = 0; sub < 7; ++sub) {
        const int sOff = chunk * 1792 + sub * 256;
#pragma unroll
        for (int cc = 0; cc < 8; ++cc) {
            const int ch = w * 8 + cc;
            const int row = ch * 2 + (lane >> 5);
            const int sc = lane & 31;
            gload16(Vp + (size_t)row * SP + sOff + ((sc ^ (row & 7)) << 3),
                    &lV[ch * 512]);
        }
#pragma unroll
        for (int ps = 0; ps < 8; ++ps) {
            const int row = (tid >> 5) + ps * 8;
            const int sc = tid & 31;
            bf16x8 kv = *(const bf16x8*)(Kp + (size_t)row * SP + sOff + sc * 8);
            bf16x8 ev;
#pragma unroll
            for (int j = 0; j < 8; ++j)
                ev[j] = f2bf(__expf(bf2f(kv[j]) - km8[ps]) * ki8[ps]);
            *(bf16x8*)&lK[row * 256 + ((sc ^ (row & 7)) << 3)] = ev;
        }
        __syncthreads();
#pragma unroll
        for (int ks = 0; ks < 8; ++ks) {
            const int kb = ks * 4 + (lane >> 4);
            bf16x8 ak[2], bv[2];
#pragma unroll
            for (int i = 0; i < 2; ++i) {
                const int rk = wr * 32 + i * 16 + (lane & 15);
                ak[i] = *(const bf16x8*)&lK[rk * 256 + ((kb ^ (rk & 7)) << 3)];
            }
#pragma unroll
            for (int j = 0; j < 2; ++j) {
                const int rv = wc * 32 + j * 16 + (lane & 15);
                bv[j] = *(const bf16x8*)&lV[rv * 256 + ((kb ^ (rv & 7)) << 3)];
            }
#pragma unroll
            for (int i = 0; i < 2; ++i)
#pragma unroll
                for (int j = 0; j < 2; ++j)
                    acc[i][j] = __builtin_amdgcn_mfma_f32_16x16x32_bf16(
                        ak[i], bv[j], acc[i][j], 0, 0, 0);
        }
        __syncthreads();
    }
    float* op = part + ((size_t)nh * CTX_CHUNKS + chunk) * 4096;
#pragma unroll
    for (int i = 0; i < 2; ++i)
#pragma unroll
        for (int j = 0; j < 2; ++j)
#pragma unroll
            for (int r = 0; r < 4; ++r) {
                const int k = wr * 32 + i * 16 + (lane >> 4) * 4 + r;
                const int v = wc * 32 + j * 16 + (lane & 15);
                op[k * 64 + v] = acc[i][j][r];
            }
}

__global__ __launch_bounds__(256)
void ctx_reduce_kernel(const float* __restrict__ part, float* __restrict__ ctx)
{
    const int nh = blockIdx.x;
    for (int e = threadIdx.x; e < 4096; e += 256) {
        float s = 0.f;
        for (int c = 0; c < CTX_CHUNKS; ++c)
            s += part[((size_t)nh * CTX_CHUNKS + c) * 4096 + e];
        ctx[(size_t)nh * 4096 + e] = s;
    }
}

// ---------------- att = ctx^T . softmaxQ via MFMA --------------------------
__global__ __launch_bounds__(256)
void att_kernel(const float* __restrict__ ctx, const short* __restrict__ Qb,
                short* __restrict__ out)
{
    const int nh = blockIdx.y;
    const int n = nh >> 3, h = nh & 7;
    const int s0 = blockIdx.x * 64;
    const float* cp = ctx + (size_t)nh * 4096;
    __shared__ short lC[64 * 64];
    __shared__ short lQ[64 * 64];
    __shared__ float red[64][4];
    __shared__ short lO[64 * 72];
    const int tid = threadIdx.x;
    const int w = tid >> 6, lane = tid & 63;

#pragma unroll
    for (int u = 0; u < 2; ++u) {
        const int si = (tid >> 6) + u * 4;
        const int v = tid & 63;
        bf16x8 pk;
#pragma unroll
        for (int j = 0; j < 8; ++j) pk[j] = f2bf(cp[(si * 8 + j) * 64 + v]);
        *(bf16x8*)&lC[v * 64 + ((si ^ (v & 7)) << 3)] = pk;
    }
    const int sq = tid >> 2, qpart = tid & 3;
    const short* Qrow = Qb + ((size_t)n * SP + s0 + sq) * 512 + h * 64 + qpart * 16;
    bf16x8 q0 = *(const bf16x8*)(Qrow);
    bf16x8 q1 = *(const bf16x8*)(Qrow + 8);
    float e[16];
    float mx = -1e30f;
#pragma unroll
    for (int j = 0; j < 8; ++j) {
        e[j] = bf2f(q0[j]); e[8 + j] = bf2f(q1[j]);
        mx = fmaxf(mx, fmaxf(e[j], e[8 + j]));
    }
    red[sq][qpart] = mx;
    __syncthreads();
    mx = fmaxf(fmaxf(red[sq][0], red[sq][1]), fmaxf(red[sq][2], red[sq][3]));
    float sum = 0.f;
#pragma unroll
    for (int j = 0; j < 16; ++j) { e[j] = __expf(e[j] - mx); sum += e[j]; }
    __syncthreads();
    red[sq][qpart] = sum;
    __syncthreads();
    const float sinv = 1.f / (red[sq][0] + red[sq][1] + red[sq][2] + red[sq][3]);
    bf16x8 p0, p1;
#pragma unroll
    for (int j = 0; j < 8; ++j) {
        p0[j] = f2bf(e[j] * sinv);
        p1[j] = f2bf(e[8 + j] * sinv);
    }
    *(bf16x8*)&lQ[sq * 64 + (((qpart * 2) ^ (sq & 7)) << 3)] = p0;
    *(bf16x8*)&lQ[sq * 64 + (((qpart * 2 + 1) ^ (sq & 7)) << 3)] = p1;
    __syncthreads();

    f32x4 acc[4];
#pragma unroll
    for (int i = 0; i < 4; ++i) acc[i] = (f32x4){0.f, 0.f, 0.f, 0.f};
    const int srow = w * 16 + (lane & 15);
#pragma unroll
    for (int ks = 0; ks < 2; ++ks) {
        const int kb = ks * 4 + (lane >> 4);
        bf16x8 bq = *(const bf16x8*)&lQ[srow * 64 + ((kb ^ (srow & 7)) << 3)];
#pragma unroll
        for (int i = 0; i < 4; ++i) {
            const int vr = i * 16 + (lane & 15);
            bf16x8 av = *(const bf16x8*)&lC[vr * 64 + ((kb ^ (vr & 7)) << 3)];
            acc[i] = __builtin_amdgcn_mfma_f32_16x16x32_bf16(av, bq, acc[i], 0, 0, 0);
        }
    }
#pragma unroll
    for (int i = 0; i < 4; ++i)
#pragma unroll
        for (int r = 0; r < 4; ++r)
            lO[(i * 16 + (lane >> 4) * 4 + r) * 72 + w * 16 + (lane & 15)] =
                f2bf(acc[i][r]);
    __syncthreads();
    short* op = out + (size_t)nh * 64 * SP;
#pragma unroll
    for (int cc = 0; cc < 2; ++cc) {
        const int idx = tid + cc * 256;
        const int v = idx >> 3, ch = idx & 7;
        bf16x8 t = *(const bf16x8*)&lO[v * 72 + ch * 8];
        *(bf16x8*)&op[(size_t)v * SP + s0 + ch * 8] = t;
    }
}

// ---------------- LN finalize ----------------------------------------------
__global__ __launch_bounds__(256)
void stats_final_kernel(const double* __restrict__ partials, float* __restrict__ mv)
{
    double ls = 0.0, lss = 0.0;
    for (int i = threadIdx.x; i < STATS_PARTS; i += 256) {
        ls += partials[2 * i];
        lss += partials[2 * i + 1];
    }
    __shared__ double s1[256], s2[256];
    const int tid = threadIdx.x;
    s1[tid] = ls; s2[tid] = lss;
    __syncthreads();
    for (int s = 128; s > 0; s >>= 1) {
        if (tid < s) { s1[tid] += s1[tid + s]; s2[tid] += s2[tid + s]; }
        __syncthreads();
    }
    if (tid == 0) {
        double mean = s1[0] / TOTAL_ELEMS;
        double var = s2[0] / TOTAL_ELEMS - mean * mean;
        mv[0] = (float)mean;
        mv[1] = (float)(1.0 / sqrt(var + 1e-5));
    }
}

__global__ __launch_bounds__(256)
void normalize_kernel(float* __restrict__ x, const float* __restrict__ mv)
{
    const float mean = mv[0], inv = mv[1];
    size_t i = ((size_t)blockIdx.x * 256 + threadIdx.x) * 4;
    const size_t tot = (size_t)NB;
    const size_t step = (size_t)gridDim.x * 1024;
    for (; i < tot; i += step) {
        float4 v = *(float4*)&x[i];
        v.x = (v.x - mean) * inv; v.y = (v.y - mean) * inv;
        v.z = (v.z - mean) * inv; v.w = (v.w - mean) * inv;
        *(float4*)&x[i] = v;
    }
}

// ---------------------------------------------------------------------------
extern "C" void kernel_launch(void* const* d_in, const int* in_sizes, int n_in,
                              void* d_out, int out_size, void* d_ws, size_t ws_size,
                              hipStream_t stream)
{
    (void)in_sizes; (void)n_in; (void)out_size; (void)ws_size;
    const float* rgb = (const float*)d_in[0];
    const float* flow = (const float*)d_in[1];
    float* ws = (float*)d_ws;

    short* bufK = (short*)ws;                        // [N,512,S] bf16
    short* bufQ = (short*)(ws + NB / 2);             // [N,S,512] bf16
    short* bufV = (short*)(ws + NB);                 // V/agg [N,512,S] bf16
    short* actK = (short*)(ws + 3 * NB / 2);         // [N,256,S] bf16
    short* actQ = (short*)(ws + 7 * NB / 4);         // [N,256,S] bf16
    short* actV = (short*)(ws + 2 * NB);             // [N,256,S] bf16
    short* wB   = (short*)(ws + 9 * NB / 4);         // 655360 bf16
    float2* rowStats = (float2*)(wB + 655360);       // 2048
    float* ctxBuf = (float*)(rowStats + 2048);       // 32*4096
    double* partials = (double*)(ctxBuf + 32 * 4096);
    float* mv = (float*)(partials + 2 * STATS_PARTS);
    float* ctxPart = ws + 3 * NB / 2;                // alias act region
    short* rpDw = actK;                              // rp dw out [N,512,S] bf16

    const size_t nsA = (size_t)C2 * SP, csA = SP;    // K/V [n][c][s]

    wcvt_kernel<<<2560, 256, 0, stream>>>(
        (const float*)d_in[4], (const float*)d_in[12], (const float*)d_in[16],
        (const float*)d_in[24], (const float*)d_in[8], (const float*)d_in[20],
        (const float*)d_in[28], wB);

    // ---- projections per stream: fused dw3 then 3 pw GEMMs ----
    for (int st = 0; st < 2; ++st) {
        const float* src = st ? flow : rgb;
        const int kI = st ? 14 : 2, qI = st ? 18 : 6, vI = st ? 22 : 10;
        const int choff = st ? 256 : 0;
        dwv_kernel<float, 3><<<dim3(2, C1, NN), 256, 0, stream>>>(
            src,
            (const float*)d_in[kI], (const float*)d_in[kI + 1], actK,
            (const float*)d_in[qI], (const float*)d_in[qI + 1], actQ,
            (const float*)d_in[vI], (const float*)d_in[vI + 1], actV, C1);
        pw_mfma_kernel<0><<<dim3(SP / 128, 2, NN), 256, 0, stream>>>(
            wB + (size_t)(st ? 2 : 0) * 65536, (const float*)d_in[kI + 3], actK,
            bufK, nullptr, nullptr, nullptr, nullptr, C1, nsA, csA, choff);
        pw_mfma_kernel<0><<<dim3(SP / 128, 2, NN), 256, 0, stream>>>(
            wB + (size_t)(st ? 3 : 1) * 65536, (const float*)d_in[vI + 3], actV,
            bufV, nullptr, nullptr, nullptr, nullptr, C1, nsA, csA, choff);
        pw_mfma_kernel<1><<<dim3(SP / 128, 2, NN), 256, 0, stream>>>(
            wB + (size_t)(st ? 5 : 4) * 65536, (const float*)d_in[qI + 3], actQ,
            bufQ, nullptr, nullptr, nullptr, nullptr, C1, 0, 0, choff);
    }

    // ---- attention ----
    row_stats_kernel<<<NN * C2, 256, 0, stream>>>(bufK, rowStats);
    ctx_mfma_kernel<<<dim3(CTX_CHUNKS, NN * HEADS), 256, 0, stream>>>(
        bufK, bufV, rowStats, ctxPart);
    ctx_reduce_kernel<<<NN * HEADS, 256, 0, stream>>>(ctxPart, ctxBuf);
    att_kernel<<<dim3(SP / 64, NN * HEADS), 256, 0, stream>>>(
        ctxBuf, bufQ, bufV);   // bufV becomes aggregated [N,512,S]

    // ---- reprojection: dw(512) -> pw GEMM (+residual +LN stats) ----
    dwv_kernel<short, 1><<<dim3(2, C2, NN), 256, 0, stream>>>(
        bufV, (const float*)d_in[26], (const float*)d_in[27], rpDw,
        nullptr, nullptr, nullptr, nullptr, nullptr, nullptr, C2);
    pw_mfma_kernel<2><<<dim3(SP / 128, 4, NN), 256, 0, stream>>>(
        wB + 6 * 65536, (const float*)d_in[29], rpDw, nullptr,
        (float*)d_out, rgb, flow, partials, C2, 0, 0, 0);

    // ---- LN finalize ----
    stats_final_kernel<<<1, 256, 0, stream>>>(partials, mv);
    normalize_kernel<<<2048, 256, 0, stream>>>((float*)d_out, mv);
}

// Round 11
// 419.596 us; speedup vs baseline: 2.3094x; 1.0574x over previous
//
#include <hip/hip_runtime.h>
#include <math.h>

// ---------------------------------------------------------------------------
// EfficientAttention (dual-stream) — round 11: traffic & locality.
//   * rp pw writes x as bf16 (stats on rounded values); normalize bf16->f32.
//   * K softmax row-stats fused into K pw epilogue + tiny online reduce.
//   * rp pw grid: bijective XCD-chunked swizzle (same act s-panel -> same XCD).
//   * K+V projection pw batched into one dispatch per stream.
//   pw inner loop (2-phase dbuf), dwv, ctx/att MFMA kernels: as round 10.
// ---------------------------------------------------------------------------

constexpr int NN = 4;
constexpr int C1 = 256;
constexpr int C2 = 512;
constexpr int TT = 16;
constexpr int SP = TT * 28 * 28;                  // 12544
constexpr long long NB = (long long)NN * C2 * SP; // 25,690,112
constexpr int HEADS = 8;
constexpr int CTX_CHUNKS = 7;
constexpr int SBLKS = 98;                         // SP / 128
constexpr int STATS_PARTS = SBLKS * 4 * 4;        // rp GEMM grid = 1568
constexpr double TOTAL_ELEMS = (double)NB;

typedef __attribute__((ext_vector_type(8))) short bf16x8;
typedef __attribute__((ext_vector_type(4))) short bf16x4;
typedef __attribute__((ext_vector_type(4))) float f32x4;

__device__ __forceinline__ short f2bf(float f)
{
    unsigned u = __float_as_uint(f);
    unsigned r = u + 0x7FFFu + ((u >> 16) & 1u);
    return (short)(r >> 16);
}
__device__ __forceinline__ float bf2f(short s)
{
    return __uint_as_float(((unsigned)(unsigned short)s) << 16);
}

__device__ __forceinline__ float4 loadvec4(const float* p)
{
    return *(const float4*)p;
}
__device__ __forceinline__ float4 loadvec4(const short* p)
{
    bf16x4 v = *(const bf16x4*)p;
    return (float4){bf2f(v[0]), bf2f(v[1]), bf2f(v[2]), bf2f(v[3])};
}

__device__ __forceinline__ void gload16(const short* g, short* l)
{
    __builtin_amdgcn_global_load_lds(
        (const __attribute__((address_space(1))) unsigned int*)g,
        (__attribute__((address_space(3))) unsigned int*)l,
        16, 0, 0);
}

// ---------------- merged fp32 -> bf16 weight conversion --------------------
__global__ __launch_bounds__(256)
void wcvt_kernel(const float* __restrict__ w0, const float* __restrict__ w1,
                 const float* __restrict__ w2, const float* __restrict__ w3,
                 const float* __restrict__ w4, const float* __restrict__ w5,
                 const float* __restrict__ w6, short* __restrict__ out)
{
    int i = blockIdx.x * 256 + threadIdx.x;
    if (i >= 655360) return;
    const float* src; int off;
    if (i < 393216) {
        int seg = i >> 16; off = i & 65535;
        src = seg == 0 ? w0 : seg == 1 ? w1 : seg == 2 ? w2
            : seg == 3 ? w3 : seg == 4 ? w4 : w5;
    } else { src = w6; off = i - 393216; }
    out[i] = f2bf(src[off]);
}

// ---------------- depthwise 3x3x3 (prefetched, vectorized) -----------------
template<typename IT, int NSET>
__global__ __launch_bounds__(256)
void dwv_kernel(const IT* __restrict__ in,
                const float* __restrict__ w0c, const float* __restrict__ b0c,
                short* __restrict__ o0,
                const float* __restrict__ w1c, const float* __restrict__ b1c,
                short* __restrict__ o1,
                const float* __restrict__ w2c, const float* __restrict__ b2c,
                short* __restrict__ o2, int Cin)
{
    const int split = blockIdx.x, c = blockIdx.y, n = blockIdx.z;
    const int t0 = split * 8, t1 = t0 + 8;
    const int zs = (t0 - 1 > 0) ? t0 - 1 : 0;
    const int ze = (t1 < 15) ? t1 : 15;
    __shared__ float tile[2][900];
    const int tid = threadIdx.x;
    const size_t ibase = ((size_t)(n * Cin + c)) * TT * 784;
    const IT* inp = in + ibase;

    const float* wp[3] = {w0c, w1c, w2c};
    const float* bp[3] = {b0c, b1c, b2c};
    short* op[3] = {o0, o1, o2};
    float w[NSET][27], bv[NSET];
#pragma unroll
    for (int g = 0; g < NSET; ++g) {
#pragma unroll
        for (int i = 0; i < 27; ++i) w[g][i] = wp[g][c * 27 + i];
        bv[g] = bp[g][c];
    }

    for (int i = tid; i < 1800; i += 256) ((float*)tile)[i] = 0.f;

    const bool act = tid < 196;
    const int pos = tid * 4;
    const int hh = pos / 28, ww = pos - hh * 28;
    const int ladr = (hh + 1) * 30 + ww + 1;
    const int rbase = hh * 30 + ww;

    float4 preg = {0.f, 0.f, 0.f, 0.f};
    if (act) preg = loadvec4(inp + (size_t)zs * 784 + pos);

    float a0[NSET][4], a1[NSET][4], a2[NSET][4];
#pragma unroll
    for (int g = 0; g < NSET; ++g)
#pragma unroll
        for (int k = 0; k < 4; ++k) { a0[g][k] = bv[g]; a1[g][k] = bv[g]; a2[g][k] = bv[g]; }

    for (int z = zs; z <= ze; ++z) {
        float* tb = tile[z & 1];
        __syncthreads();
        if (act) {
            tb[ladr] = preg.x; tb[ladr + 1] = preg.y;
            tb[ladr + 2] = preg.z; tb[ladr + 3] = preg.w;
            if (z < ze) preg = loadvec4(inp + (size_t)(z + 1) * 784 + pos);
        }
        __syncthreads();
        if (act) {
            float v[3][6];
#pragma unroll
            for (int r = 0; r < 3; ++r)
#pragma unroll
                for (int j = 0; j < 6; ++j)
                    v[r][j] = tb[rbase + r * 30 + j];
#pragma unroll
            for (int g = 0; g < NSET; ++g)
#pragma unroll
                for (int dh = 0; dh < 3; ++dh)
#pragma unroll
                    for (int dw = 0; dw < 3; ++dw) {
                        const float wa = w[g][18 + dh * 3 + dw];
                        const float wb = w[g][9 + dh * 3 + dw];
                        const float wc2 = w[g][dh * 3 + dw];
#pragma unroll
                        for (int k = 0; k < 4; ++k) {
                            const float val = v[dh][k + dw];
                            a0[g][k] += val * wa;
                            a1[g][k] += val * wb;
                            a2[g][k] += val * wc2;
                        }
                    }
            if (z - 1 >= t0) {
#pragma unroll
                for (int g = 0; g < NSET; ++g) {
                    bf16x4 pk;
#pragma unroll
                    for (int k = 0; k < 4; ++k) pk[k] = f2bf(a0[g][k]);
                    *(bf16x4*)&op[g][ibase + (size_t)(z - 1) * 784 + pos] = pk;
                }
            }
#pragma unroll
            for (int g = 0; g < NSET; ++g)
#pragma unroll
                for (int k = 0; k < 4; ++k) {
                    a0[g][k] = a1[g][k]; a1[g][k] = a2[g][k]; a2[g][k] = bv[g];
                }
        }
    }
    if (act && ze >= t0 && ze < t1) {
#pragma unroll
        for (int g = 0; g < NSET; ++g) {
            bf16x4 pk;
#pragma unroll
            for (int k = 0; k < 4; ++k) pk[k] = f2bf(a0[g][k]);
            *(bf16x4*)&op[g][ibase + (size_t)ze * 784 + pos] = pk;
        }
    }
}

// ---------------- pointwise conv: bf16 MFMA GEMM (2-phase prefetch) --------
// MODE 0: batched K(seg0)+V(seg1) -> bf16 [n][c][s]; K also emits per-block
//         row (max, expsum) partials to kpart[row][sBlk].
// MODE 1: Q -> bf16 [n][s][512].
// MODE 2: rp -> x bf16 [n][c][s] (acc+bias+resid, rounded) + LN partials
//         (on rounded values); grid 1D with XCD-chunked swizzle.
template<int MODE>
__global__ __launch_bounds__(256)
void pw_mfma_kernel(const short* __restrict__ WbA, const float* __restrict__ biasA,
                    const short* __restrict__ actA, short* __restrict__ outA,
                    const short* __restrict__ WbV, const float* __restrict__ biasV,
                    const short* __restrict__ actV, short* __restrict__ outV,
                    const float* __restrict__ rgb, const float* __restrict__ flow,
                    double* __restrict__ partials, float2* __restrict__ kpart,
                    int Cin, size_t nStride, size_t cStride, int chOff)
{
    __shared__ short smem[34816];     // 69632 B: lA 8192x2 | Bs 9216x2
    const int tid = threadIdx.x;
    const int w = tid >> 6, lane = tid & 63;
    int s0, m0, n, seg = 0, sBlk;
    if constexpr (MODE == 2) {
        const int b = blockIdx.x;
        const int r = b & 7, t = b >> 3;
        const int mBlk = t & 3, q = t >> 2;
        const int g = q * 8 + r;                  // bijective: 392 groups
        n = g / SBLKS; sBlk = g % SBLKS;
        s0 = sBlk * 128; m0 = mBlk * 128;
    } else {
        sBlk = blockIdx.x; s0 = sBlk * 128; n = blockIdx.z;
        if constexpr (MODE == 0) { seg = blockIdx.y >> 1; m0 = (blockIdx.y & 1) * 128; }
        else m0 = blockIdx.y * 128;
    }
    const short* Wb = (MODE == 0 && seg) ? WbV : WbA;
    const float* bias = (MODE == 0 && seg) ? biasV : biasA;
    const short* actp = (MODE == 0 && seg) ? actV : actA;
    short* outB = (MODE == 0 && seg) ? outV : outA;

    const short* aSrc = Wb + (size_t)m0 * Cin;
    const short* bSrc = actp + (size_t)n * Cin * SP;
    f32x4 acc[4][4];
#pragma unroll
    for (int i = 0; i < 4; ++i)
#pragma unroll
        for (int j = 0; j < 4; ++j)
            acc[i][j] = (f32x4){0.f, 0.f, 0.f, 0.f};
    const int lrow = lane >> 3, lslot = lane & 7;
    const int wr = w >> 1, wc = w & 1;
    const int kg = tid >> 4, scb = tid & 15;   // B staging: 4 k-rows x 8 s
    const int nt = Cin >> 6;

    // ---- prologue: stage tile 0 into buffer 0 ----
    {
        short* nA = smem;
        short* nB = smem + 16384;
#pragma unroll
        for (int cc = 0; cc < 4; ++cc) {
            const int chunk = w * 4 + cc;
            const int row = chunk * 8 + lrow;
            const int ss = lslot ^ (row & 7);
            gload16(aSrc + (size_t)row * Cin + ss * 8, &nA[chunk * 512]);
        }
        bf16x8 breg[4];
#pragma unroll
        for (int r = 0; r < 4; ++r)
            breg[r] = *(const bf16x8*)(bSrc + (size_t)(kg * 4 + r) * SP + s0 + scb * 8);
#pragma unroll
        for (int j = 0; j < 8; ++j) {
            bf16x4 pk;
#pragma unroll
            for (int r = 0; r < 4; ++r) pk[r] = breg[r][j];
            const int srow = scb * 8 + j;
            const int slot = (kg >> 1) ^ (scb & 7);
            *(bf16x4*)&nB[srow * 72 + slot * 8 + (kg & 1) * 4] = pk;
        }
    }
    __syncthreads();

    for (int t = 0; t < nt; ++t) {
        short* cA = smem + (t & 1) * 8192;
        short* cB = smem + 16384 + (t & 1) * 9216;
        short* nA = smem + ((t + 1) & 1) * 8192;
        short* nB = smem + 16384 + ((t + 1) & 1) * 9216;
        const bool more = (t + 1) < nt;
        bf16x8 bnext[4];
        if (more) {
            const int kt = (t + 1) << 6;
#pragma unroll
            for (int cc = 0; cc < 4; ++cc) {
                const int chunk = w * 4 + cc;
                const int row = chunk * 8 + lrow;
                const int ss = lslot ^ (row & 7);
                gload16(aSrc + (size_t)row * Cin + kt + ss * 8, &nA[chunk * 512]);
            }
#pragma unroll
            for (int r = 0; r < 4; ++r)
                bnext[r] = *(const bf16x8*)(bSrc + (size_t)(kt + kg * 4 + r) * SP + s0 + scb * 8);
        }
#pragma unroll
        for (int kf = 0; kf < 2; ++kf) {
            bf16x8 af[4], bfr[4];
            const int kb = kf * 4 + (lane >> 4);
#pragma unroll
            for (int i = 0; i < 4; ++i) {
                const int row = wr * 64 + i * 16 + (lane & 15);
                af[i] = *(const bf16x8*)&cA[row * 64 + ((kb ^ (row & 7)) << 3)];
            }
#pragma unroll
            for (int j = 0; j < 4; ++j) {
                const int srow = wc * 64 + j * 16 + (lane & 15);
                bfr[j] = *(const bf16x8*)&cB[srow * 72 + ((kb ^ ((srow >> 3) & 7)) << 3)];
            }
#pragma unroll
            for (int i = 0; i < 4; ++i)
#pragma unroll
                for (int j = 0; j < 4; ++j)
                    acc[i][j] = __builtin_amdgcn_mfma_f32_16x16x32_bf16(
                        af[i], bfr[j], acc[i][j], 0, 0, 0);
        }
        if (more) {
#pragma unroll
            for (int j = 0; j < 8; ++j) {
                bf16x4 pk;
#pragma unroll
                for (int r = 0; r < 4; ++r) pk[r] = bnext[r][j];
                const int srow = scb * 8 + j;
                const int slot = (kg >> 1) ^ (scb & 7);
                *(bf16x4*)&nB[srow * 72 + slot * 8 + (kg & 1) * 4] = pk;
            }
        }
        __syncthreads();
    }

    if constexpr (MODE == 0) {
        short* ep = smem;                      // [128][136] bf16
#pragma unroll
        for (int i = 0; i < 4; ++i) {
            const int mloc = wr * 64 + i * 16 + (lane >> 4) * 4;
#pragma unroll
            for (int j = 0; j < 4; ++j) {
                const int sloc = wc * 64 + j * 16 + (lane & 15);
#pragma unroll
                for (int r = 0; r < 4; ++r)
                    ep[(mloc + r) * 136 + sloc] =
                        f2bf(acc[i][j][r] + bias[m0 + mloc + r]);
            }
        }
        __syncthreads();
        short* op = outB + (size_t)n * nStride;
#pragma unroll
        for (int cc = 0; cc < 8; ++cc) {
            const int idx = tid + cc * 256;
            const int mloc = idx >> 4, ch = idx & 15;
            bf16x8 v = *(const bf16x8*)&ep[mloc * 136 + ch * 8];
            *(bf16x8*)&op[(size_t)(chOff + m0 + mloc) * cStride + s0 + ch * 8] = v;
        }
        if (seg == 0) {
            // per-row softmax partials over this block's 128 s
            const int row = tid >> 1, half = tid & 1;
            const short* rp = &ep[row * 136 + half * 64];
            float mx = -1e30f;
#pragma unroll 8
            for (int j = 0; j < 64; ++j) mx = fmaxf(mx, bf2f(rp[j]));
            float sum = 0.f;
#pragma unroll 8
            for (int j = 0; j < 64; ++j) sum += __expf(bf2f(rp[j]) - mx);
            const float mo = __shfl_xor(mx, 1, 64);
            const float so = __shfl_xor(sum, 1, 64);
            const float mg = fmaxf(mx, mo);
            const float sg = sum * __expf(mx - mg) + so * __expf(mo - mg);
            if (half == 0)
                kpart[(size_t)(n * 512 + chOff + m0 + row) * SBLKS + sBlk] =
                    (float2){mg, sg};
        }
    } else if constexpr (MODE == 1) {
        short* ep = smem;                      // [128 s][136 m]
#pragma unroll
        for (int i = 0; i < 4; ++i) {
            const int mb = wr * 64 + i * 16 + (lane >> 4) * 4;
#pragma unroll
            for (int j = 0; j < 4; ++j) {
                const int sloc = wc * 64 + j * 16 + (lane & 15);
                bf16x4 pk;
#pragma unroll
                for (int r = 0; r < 4; ++r)
                    pk[r] = f2bf(acc[i][j][r] + bias[m0 + mb + r]);
                *(bf16x4*)&ep[sloc * 136 + mb] = pk;
            }
        }
        __syncthreads();
#pragma unroll
        for (int cc = 0; cc < 8; ++cc) {
            const int idx = tid + cc * 256;
            const int sloc = idx >> 4, ch = idx & 15;
            bf16x8 v = *(const bf16x8*)&ep[sloc * 136 + ch * 8];
            *(bf16x8*)&outA[((size_t)n * SP + s0 + sloc) * 512 + chOff + m0 + ch * 8] = v;
        }
    } else {
        float* ep = (float*)smem;              // [128][132] f32 (67.6 KB)
#pragma unroll
        for (int i = 0; i < 4; ++i) {
            const int mloc = wr * 64 + i * 16 + (lane >> 4) * 4;
#pragma unroll
            for (int j = 0; j < 4; ++j) {
                const int sloc = wc * 64 + j * 16 + (lane & 15);
#pragma unroll
                for (int r = 0; r < 4; ++r)
                    ep[(mloc + r) * 132 + sloc] =
                        acc[i][j][r] + bias[m0 + mloc + r];
            }
        }
        __syncthreads();
        short* xo = outA + (size_t)n * C2 * SP;
        const float* rbase = (m0 < 256)
            ? rgb + ((size_t)n * 256 + m0) * SP
            : flow + ((size_t)n * 256 + (m0 - 256)) * SP;
        double ls = 0.0, lss = 0.0;
#pragma unroll
        for (int cc = 0; cc < 8; ++cc) {
            const int idx = tid + cc * 256;
            const int mloc = idx >> 4, ch = idx & 15;
            float4 a0 = *(const float4*)&ep[mloc * 132 + ch * 8];
            float4 a1 = *(const float4*)&ep[mloc * 132 + ch * 8 + 4];
            float4 r0 = *(const float4*)&rbase[(size_t)mloc * SP + s0 + ch * 8];
            float4 r1 = *(const float4*)&rbase[(size_t)mloc * SP + s0 + ch * 8 + 4];
            bf16x8 pk;
            pk[0] = f2bf(a0.x + r0.x); pk[1] = f2bf(a0.y + r0.y);
            pk[2] = f2bf(a0.z + r0.z); pk[3] = f2bf(a0.w + r0.w);
            pk[4] = f2bf(a1.x + r1.x); pk[5] = f2bf(a1.y + r1.y);
            pk[6] = f2bf(a1.z + r1.z); pk[7] = f2bf(a1.w + r1.w);
            *(bf16x8*)&xo[(size_t)(m0 + mloc) * SP + s0 + ch * 8] = pk;
#pragma unroll
            for (int k = 0; k < 8; ++k) {
                const double xv = (double)bf2f(pk[k]);
                ls += xv; lss += xv * xv;
            }
        }
        __shared__ double s1[256], s2[256];
        s1[tid] = ls; s2[tid] = lss;
        __syncthreads();
        for (int st = 128; st > 0; st >>= 1) {
            if (tid < st) { s1[tid] += s1[tid + st]; s2[tid] += s2[tid + st]; }
            __syncthreads();
        }
        if (tid == 0) {
            partials[2 * blockIdx.x] = s1[0];
            partials[2 * blockIdx.x + 1] = s2[0];
        }
    }
}

// ---------------- K softmax stats: online merge of per-block partials ------
__global__ __launch_bounds__(256)
void kstats_reduce_kernel(const float2* __restrict__ kpart, float2* __restrict__ st)
{
    const int row = blockIdx.x * 256 + threadIdx.x;   // 8 blocks x 256 = 2048
    const float2* p = kpart + (size_t)row * SBLKS;
    float m = -1e30f, s = 0.f;
    for (int b = 0; b < SBLKS; ++b) {
        float2 e = p[b];
        float nm = fmaxf(m, e.x);
        s = s * __expf(m - nm) + e.y * __expf(e.x - nm);
        m = nm;
    }
    st[row] = (float2){m, 1.f / s};
}

// ---------------- ctx = softmax(K) . V^T via MFMA --------------------------
__global__ __launch_bounds__(256)
void ctx_mfma_kernel(const short* __restrict__ Kb, const short* __restrict__ Vb,
                     const float2* __restrict__ stats, float* __restrict__ part)
{
    const int chunk = blockIdx.x, nh = blockIdx.y;
    const short* Kp = Kb + (size_t)nh * 64 * SP;
    const short* Vp = Vb + (size_t)nh * 64 * SP;
    __shared__ short lK[64 * 256];
    __shared__ short lV[64 * 256];
    const int tid = threadIdx.x;
    const int w = tid >> 6, lane = tid & 63;
    const int wr = w >> 1, wc = w & 1;
    f32x4 acc[2][2];
#pragma unroll
    for (int i = 0; i < 2; ++i)
#pragma unroll
        for (int j = 0; j < 2; ++j)
            acc[i][j] = (f32x4){0.f, 0.f, 0.f, 0.f};

    float km8[8], ki8[8];
#pragma unroll
    for (int ps = 0; ps < 8; ++ps) {
        float2 s = stats[nh * 64 + (tid >> 5) + ps * 8];
        km8[ps] = s.x; ki8[ps] = s.y;
    }

    for (int sub = 0; sub < 7; ++sub) {
        const int sOff = chunk * 1792 + sub * 256;
#pragma unroll
        for (int cc = 0; cc < 8; ++cc) {
            const int ch = w * 8 + cc;
            const int row = ch * 2 + (lane >> 5);
            const int sc = lane & 31;
            gload16(Vp + (size_t)row * SP + sOff + ((sc ^ (row & 7)) << 3),
                    &lV[ch * 512]);
        }
#pragma unroll
        for (int ps = 0; ps < 8; ++ps) {
            const int row = (tid >> 5) + ps * 8;
            const int sc = tid & 31;
            bf16x8 kv = *(const bf16x8*)(Kp + (size_t)row * SP + sOff + sc * 8);
            bf16x8 ev;
#pragma unroll
            for (int j = 0; j < 8; ++j)
                ev[j] = f2bf(__expf(bf2f(kv[j]) - km8[ps]) * ki8[ps]);
            *(bf16x8*)&lK[row * 256 + ((sc ^ (row & 7)) << 3)] = ev;
        }
        __syncthreads();
#pragma unroll
        for (int ks = 0; ks < 8; ++ks) {
            const int kb = ks * 4 + (lane >> 4);
            bf16x8 ak[2], bv[2];
#pragma unroll
            for (int i = 0; i < 2; ++i) {
                const int rk = wr * 32 + i * 16 + (lane & 15);
                ak[i] = *(const bf16x8*)&lK[rk * 256 + ((kb ^ (rk & 7)) << 3)];
            }
#pragma unroll
            for (int j = 0; j < 2; ++j) {
                const int rv = wc * 32 + j * 16 + (lane & 15);
                bv[j] = *(const bf16x8*)&lV[rv * 256 + ((kb ^ (rv & 7)) << 3)];
            }
#pragma unroll
            for (int i = 0; i < 2; ++i)
#pragma unroll
                for (int j = 0; j < 2; ++j)
                    acc[i][j] = __builtin_amdgcn_mfma_f32_16x16x32_bf16(
                        ak[i], bv[j], acc[i][j], 0, 0, 0);
        }
        __syncthreads();
    }
    float* op = part + ((size_t)nh * CTX_CHUNKS + chunk) * 4096;
#pragma unroll
    for (int i = 0; i < 2; ++i)
#pragma unroll
        for (int j = 0; j < 2; ++j)
#pragma unroll
            for (int r = 0; r < 4; ++r) {
                const int k = wr * 32 + i * 16 + (lane >> 4) * 4 + r;
                const int v = wc * 32 + j * 16 + (lane & 15);
                op[k * 64 + v] = acc[i][j][r];
            }
}

__global__ __launch_bounds__(256)
void ctx_reduce_kernel(const float* __restrict__ part, float* __restrict__ ctx)
{
    const int nh = blockIdx.x;
    for (int e = threadIdx.x; e < 4096; e += 256) {
        float s = 0.f;
        for (int c = 0; c < CTX_CHUNKS; ++c)
            s += part[((size_t)nh * CTX_CHUNKS + c) * 4096 + e];
        ctx[(size_t)nh * 4096 + e] = s;
    }
}

// ---------------- att = ctx^T . softmaxQ via MFMA --------------------------
__global__ __launch_bounds__(256)
void att_kernel(const float* __restrict__ ctx, const short* __restrict__ Qb,
                short* __restrict__ out)
{
    const int nh = blockIdx.y;
    const int n = nh >> 3, h = nh & 7;
    const int s0 = blockIdx.x * 64;
    const float* cp = ctx + (size_t)nh * 4096;
    __shared__ short lC[64 * 64];
    __shared__ short lQ[64 * 64];
    __shared__ float red[64][4];
    __shared__ short lO[64 * 72];
    const int tid = threadIdx.x;
    const int w = tid >> 6, lane = tid & 63;

#pragma unroll
    for (int u = 0; u < 2; ++u) {
        const int si = (tid >> 6) + u * 4;
        const int v = tid & 63;
        bf16x8 pk;
#pragma unroll
        for (int j = 0; j < 8; ++j) pk[j] = f2bf(cp[(si * 8 + j) * 64 + v]);
        *(bf16x8*)&lC[v * 64 + ((si ^ (v & 7)) << 3)] = pk;
    }
    const int sq = tid >> 2, qpart = tid & 3;
    const short* Qrow = Qb + ((size_t)n * SP + s0 + sq) * 512 + h * 64 + qpart * 16;
    bf16x8 q0 = *(const bf16x8*)(Qrow);
    bf16x8 q1 = *(const bf16x8*)(Qrow + 8);
    float e[16];
    float mx = -1e30f;
#pragma unroll
    for (int j = 0; j < 8; ++j) {
        e[j] = bf2f(q0[j]); e[8 + j] = bf2f(q1[j]);
        mx = fmaxf(mx, fmaxf(e[j], e[8 + j]));
    }
    red[sq][qpart] = mx;
    __syncthreads();
    mx = fmaxf(fmaxf(red[sq][0], red[sq][1]), fmaxf(red[sq][2], red[sq][3]));
    float sum = 0.f;
#pragma unroll
    for (int j = 0; j < 16; ++j) { e[j] = __expf(e[j] - mx); sum += e[j]; }
    __syncthreads();
    red[sq][qpart] = sum;
    __syncthreads();
    const float sinv = 1.f / (red[sq][0] + red[sq][1] + red[sq][2] + red[sq][3]);
    bf16x8 p0, p1;
#pragma unroll
    for (int j = 0; j < 8; ++j) {
        p0[j] = f2bf(e[j] * sinv);
        p1[j] = f2bf(e[8 + j] * sinv);
    }
    *(bf16x8*)&lQ[sq * 64 + (((qpart * 2) ^ (sq & 7)) << 3)] = p0;
    *(bf16x8*)&lQ[sq * 64 + (((qpart * 2 + 1) ^ (sq & 7)) << 3)] = p1;
    __syncthreads();

    f32x4 acc[4];
#pragma unroll
    for (int i = 0; i < 4; ++i) acc[i] = (f32x4){0.f, 0.f, 0.f, 0.f};
    const int srow = w * 16 + (lane & 15);
#pragma unroll
    for (int ks = 0; ks < 2; ++ks) {
        const int kb = ks * 4 + (lane >> 4);
        bf16x8 bq = *(const bf16x8*)&lQ[srow * 64 + ((kb ^ (srow & 7)) << 3)];
#pragma unroll
        for (int i = 0; i < 4; ++i) {
            const int vr = i * 16 + (lane & 15);
            bf16x8 av = *(const bf16x8*)&lC[vr * 64 + ((kb ^ (vr & 7)) << 3)];
            acc[i] = __builtin_amdgcn_mfma_f32_16x16x32_bf16(av, bq, acc[i], 0, 0, 0);
        }
    }
#pragma unroll
    for (int i = 0; i < 4; ++i)
#pragma unroll
        for (int r = 0; r < 4; ++r)
            lO[(i * 16 + (lane >> 4) * 4 + r) * 72 + w * 16 + (lane & 15)] =
                f2bf(acc[i][r]);
    __syncthreads();
    short* op = out + (size_t)nh * 64 * SP;
#pragma unroll
    for (int cc = 0; cc < 2; ++cc) {
        const int idx = tid + cc * 256;
        const int v = idx >> 3, ch = idx & 7;
        bf16x8 t = *(const bf16x8*)&lO[v * 72 + ch * 8];
        *(bf16x8*)&op[(size_t)v * SP + s0 + ch * 8] = t;
    }
}

// ---------------- LN finalize ----------------------------------------------
__global__ __launch_bounds__(256)
void stats_final_kernel(const double* __restrict__ partials, float* __restrict__ mv)
{
    double ls = 0.0, lss = 0.0;
    for (int i = threadIdx.x; i < STATS_PARTS; i += 256) {
        ls += partials[2 * i];
        lss += partials[2 * i + 1];
    }
    __shared__ double s1[256], s2[256];
    const int tid = threadIdx.x;
    s1[tid] = ls; s2[tid] = lss;
    __syncthreads();
    for (int s = 128; s > 0; s >>= 1) {
        if (tid < s) { s1[tid] += s1[tid + s]; s2[tid] += s2[tid + s]; }
        __syncthreads();
    }
    if (tid == 0) {
        double mean = s1[0] / TOTAL_ELEMS;
        double var = s2[0] / TOTAL_ELEMS - mean * mean;
        mv[0] = (float)mean;
        mv[1] = (float)(1.0 / sqrt(var + 1e-5));
    }
}

__global__ __launch_bounds__(256)
void normalize_kernel(const short* __restrict__ xb, float* __restrict__ out,
                      const float* __restrict__ mv)
{
    const float mean = mv[0], inv = mv[1];
    size_t i = ((size_t)blockIdx.x * 256 + threadIdx.x) * 8;
    const size_t tot = (size_t)NB;
    const size_t step = (size_t)gridDim.x * 2048;
    for (; i < tot; i += step) {
        bf16x8 v = *(const bf16x8*)&xb[i];
        float4 a, b;
        a.x = (bf2f(v[0]) - mean) * inv; a.y = (bf2f(v[1]) - mean) * inv;
        a.z = (bf2f(v[2]) - mean) * inv; a.w = (bf2f(v[3]) - mean) * inv;
        b.x = (bf2f(v[4]) - mean) * inv; b.y = (bf2f(v[5]) - mean) * inv;
        b.z = (bf2f(v[6]) - mean) * inv; b.w = (bf2f(v[7]) - mean) * inv;
        *(float4*)&out[i] = a;
        *(float4*)&out[i + 4] = b;
    }
}

// ---------------------------------------------------------------------------
extern "C" void kernel_launch(void* const* d_in, const int* in_sizes, int n_in,
                              void* d_out, int out_size, void* d_ws, size_t ws_size,
                              hipStream_t stream)
{
    (void)in_sizes; (void)n_in; (void)out_size; (void)ws_size;
    const float* rgb = (const float*)d_in[0];
    const float* flow = (const float*)d_in[1];
    float* ws = (float*)d_ws;

    short* bufK = (short*)ws;                        // [N,512,S] bf16
    short* bufQ = (short*)(ws + NB / 2);             // [N,S,512] bf16
    short* bufV = (short*)(ws + NB);                 // V/agg [N,512,S] bf16
    short* actK = (short*)(ws + 3 * NB / 2);         // [N,256,S] bf16
    short* actQ = (short*)(ws + 7 * NB / 4);         // [N,256,S] bf16
    short* actV = (short*)(ws + 2 * NB);             // [N,256,S] bf16
    short* wB   = (short*)(ws + 9 * NB / 4);         // 655360 bf16
    float2* rowStats = (float2*)(wB + 655360);       // 2048
    float* ctxBuf = (float*)(rowStats + 2048);       // 32*4096
    double* partials = (double*)(ctxBuf + 32 * 4096);
    float* mv = (float*)(partials + 2 * STATS_PARTS);
    float2* kpart = (float2*)(mv + 8);               // 2048*98 float2
    float* ctxPart = ws + 3 * NB / 2;                // alias act region
    short* rpDw = actK;                              // rp dw out (spans actK+actQ)
    short* xb = bufK;                                // x bf16 (bufK dead after ctx)

    const size_t nsA = (size_t)C2 * SP, csA = SP;    // K/V [n][c][s]

    wcvt_kernel<<<2560, 256, 0, stream>>>(
        (const float*)d_in[4], (const float*)d_in[12], (const float*)d_in[16],
        (const float*)d_in[24], (const float*)d_in[8], (const float*)d_in[20],
        (const float*)d_in[28], wB);

    // ---- projections per stream: dwv, batched K+V pw, Q pw ----
    for (int st = 0; st < 2; ++st) {
        const float* src = st ? flow : rgb;
        const int kI = st ? 14 : 2, qI = st ? 18 : 6, vI = st ? 22 : 10;
        const int choff = st ? 256 : 0;
        dwv_kernel<float, 3><<<dim3(2, C1, NN), 256, 0, stream>>>(
            src,
            (const float*)d_in[kI], (const float*)d_in[kI + 1], actK,
            (const float*)d_in[qI], (const float*)d_in[qI + 1], actQ,
            (const float*)d_in[vI], (const float*)d_in[vI + 1], actV, C1);
        pw_mfma_kernel<0><<<dim3(SBLKS, 4, NN), 256, 0, stream>>>(
            wB + (size_t)(st ? 2 : 0) * 65536, (const float*)d_in[kI + 3], actK, bufK,
            wB + (size_t)(st ? 3 : 1) * 65536, (const float*)d_in[vI + 3], actV, bufV,
            nullptr, nullptr, nullptr, kpart, C1, nsA, csA, choff);
        pw_mfma_kernel<1><<<dim3(SBLKS, 2, NN), 256, 0, stream>>>(
            wB + (size_t)(st ? 5 : 4) * 65536, (const float*)d_in[qI + 3], actQ, bufQ,
            nullptr, nullptr, nullptr, nullptr,
            nullptr, nullptr, nullptr, nullptr, C1, 0, 0, choff);
    }

    // ---- attention ----
    kstats_reduce_kernel<<<8, 256, 0, stream>>>(kpart, rowStats);
    ctx_mfma_kernel<<<dim3(CTX_CHUNKS, NN * HEADS), 256, 0, stream>>>(
        bufK, bufV, rowStats, ctxPart);
    ctx_reduce_kernel<<<NN * HEADS, 256, 0, stream>>>(ctxPart, ctxBuf);
    att_kernel<<<dim3(SP / 64, NN * HEADS), 256, 0, stream>>>(
        ctxBuf, bufQ, bufV);   // bufV becomes aggregated [N,512,S]

    // ---- reprojection: dw(512) -> pw GEMM (x bf16 + LN partials) ----
    dwv_kernel<short, 1><<<dim3(2, C2, NN), 256, 0, stream>>>(
        bufV, (const float*)d_in[26], (const float*)d_in[27], rpDw,
        nullptr, nullptr, nullptr, nullptr, nullptr, nullptr, C2);
    pw_mfma_kernel<2><<<STATS_PARTS, 256, 0, stream>>>(
        wB + 6 * 65536, (const float*)d_in[29], rpDw, xb,
        nullptr, nullptr, nullptr, nullptr,
        rgb, flow, partials, nullptr, C2, 0, 0, 0);

    // ---- LN finalize ----
    stats_final_kernel<<<1, 256, 0, stream>>>(partials, mv);
    normalize_kernel<<<2048, 256, 0, stream>>>(xb, (float*)d_out, mv);
}